// Round 10
// baseline (815.907 us; speedup 1.0000x reference)
//
#include <hip/hip_runtime.h>
#include <hip/hip_bf16.h>
#include <math.h>

#define N_ 40000
#define E_ 640000
#define CB_ 400   // k_coarse partial blocks
#define CR_ 100   // rows per block (CB_*CR_ == N_)
#define SB_ 256
#define SNB_ 157  // ceil(N_/SB_)

typedef short bf16x8 __attribute__((ext_vector_type(8)));
typedef float floatx4 __attribute__((ext_vector_type(4)));

__device__ __forceinline__ short f2bf(float f) {
    __hip_bfloat16 h = __float2bfloat16(f);
    return *reinterpret_cast<short*>(&h);
}
__device__ __forceinline__ float bf2f(short u) {
    unsigned int x = ((unsigned int)(unsigned short)u) << 16;
    return __int_as_float(x);
}
__device__ __forceinline__ float rdlane(float v, int l) {
    return __int_as_float(__builtin_amdgcn_readlane(__float_as_int(v), l));
}
// unpack 2 bf16 packed in a uint
__device__ __forceinline__ float bflo(unsigned int u) { return __int_as_float(u << 16); }
__device__ __forceinline__ float bfhi(unsigned int u) { return __int_as_float(u & 0xffff0000u); }

// ---------------- CSR build ----------------
__global__ void k_count(const int* __restrict__ dst, int* __restrict__ counts) {
    for (int e = blockIdx.x * blockDim.x + threadIdx.x; e < E_; e += gridDim.x * blockDim.x)
        atomicAdd(&counts[dst[e]], 1);
}

// ---- 3-phase parallel scan ----
__global__ __launch_bounds__(256) void k_scanA(const int* __restrict__ counts,
                                               int* __restrict__ excl,
                                               int* __restrict__ bsum) {
    int t = threadIdx.x;
    int i = blockIdx.x * SB_ + t;
    int v = (i < N_) ? counts[i] : 0;
    int lane = t & 63, wv = t >> 6;
    int x = v;
#pragma unroll
    for (int off = 1; off < 64; off <<= 1) {
        int y = __shfl_up(x, off);
        if (lane >= off) x += y;
    }
    __shared__ int wsum[4];
    __shared__ int woff[4];
    if (lane == 63) wsum[wv] = x;
    __syncthreads();
    if (t == 0) {
        int a = 0;
#pragma unroll
        for (int j = 0; j < 4; j++) { int tv = wsum[j]; woff[j] = a; a += tv; }
        bsum[blockIdx.x] = a;
    }
    __syncthreads();
    if (i < N_) excl[i] = x - v + woff[wv];
}

__global__ __launch_bounds__(256) void k_scanB(int* __restrict__ bsum) {
    int t = threadIdx.x;
    int v = (t < SNB_) ? bsum[t] : 0;
    int lane = t & 63, wv = t >> 6;
    int x = v;
#pragma unroll
    for (int off = 1; off < 64; off <<= 1) {
        int y = __shfl_up(x, off);
        if (lane >= off) x += y;
    }
    __shared__ int wsum[4];
    __shared__ int woff[4];
    if (lane == 63) wsum[wv] = x;
    __syncthreads();
    if (t == 0) {
        int a = 0;
#pragma unroll
        for (int j = 0; j < 4; j++) { int tv = wsum[j]; woff[j] = a; a += tv; }
    }
    __syncthreads();
    if (t < SNB_) bsum[t] = x - v + woff[wv];
}

__global__ __launch_bounds__(256) void k_scanC(const int* __restrict__ excl,
                                               const int* __restrict__ bsum,
                                               int* __restrict__ rowptr,
                                               int* __restrict__ cursor) {
    int i = blockIdx.x * 256 + threadIdx.x;
    if (i < N_) {
        int r = excl[i] + bsum[i / SB_];
        rowptr[i] = r;
        cursor[i] = r;
    }
    if (i == N_) rowptr[N_] = E_;
}

__global__ void k_fill(const int* __restrict__ src, const int* __restrict__ dst,
                       int* __restrict__ cursor, int* __restrict__ srcv,
                       unsigned short* __restrict__ dstv, int* __restrict__ eidv) {
    for (int e = blockIdx.x * blockDim.x + threadIdx.x; e < E_; e += gridDim.x * blockDim.x) {
        int d = dst[e];
        int pos = atomicAdd(&cursor[d], 1);
        srcv[pos] = src[e];
        dstv[pos] = (unsigned short)d;
        eidv[pos] = e;
    }
}

// ---------------- prep: 6x fp32 [k=128][n=128] -> bf16 [n][k] ----------------
__global__ __launch_bounds__(256) void k_prep_all(const float* __restrict__ Wg,
                                                  const float* __restrict__ W3,
                                                  const float* __restrict__ Wm1,
                                                  short* __restrict__ WbT6) {
    int i = blockIdx.x * 256 + threadIdx.x;   // 6*16384 total
    if (i >= 6 * 16384) return;
    int m = i >> 14;
    int r = i & 16383;
    int n = r >> 7, k = r & 127;
    const float* srcp;
    switch (m) {
        case 0: srcp = Wg; break;
        case 1: srcp = Wg + 16384; break;
        case 2: srcp = Wg + 32768; break;
        case 3: srcp = W3; break;
        case 4: srcp = Wm1; break;
        default: srcp = Wm1 + 16384; break;
    }
    WbT6[m * 16384 + n * 128 + k] = f2bf(srcp[k * 128 + n]);
}

// ---------------- prep: fused el/er weight tiles Wel[layer][16][128] ----------------
// el = (A@W)·al = A@(W@Aexp): Wel[n][k] = sum_d W[k][h*16+d]*a[h*16+d], h=n&7,
// a = al (n<8) or ar (n>=8). Layer 3 (H=1): n==0 -> W3·al3, n==1 -> W3·ar3, else 0.
__global__ __launch_bounds__(256) void k_prep_wela(const float* __restrict__ Wg,
                                                   const float* __restrict__ alg,
                                                   const float* __restrict__ arg_,
                                                   const float* __restrict__ W3,
                                                   const float* __restrict__ al3,
                                                   const float* __restrict__ ar3,
                                                   short* __restrict__ WelT) {
    int i = blockIdx.x * 256 + threadIdx.x;   // 4*16*128 = 8192 total
    if (i >= 4 * 2048) return;
    int layer = i >> 11;
    int r = i & 2047;
    int n = r >> 7, k = r & 127;
    float val = 0.f;
    if (layer < 3) {
        const float* W = Wg + layer * 16384;
        const float* a = (n < 8 ? alg : arg_) + layer * 128;
        int h = n & 7;
#pragma unroll
        for (int d = 0; d < 16; d++)
            val += W[k * 128 + h * 16 + d] * a[h * 16 + d];
    } else {
        if (n == 0) { for (int c = 0; c < 128; c++) val += W3[k * 128 + c] * al3[c]; }
        else if (n == 1) { for (int c = 0; c < 128; c++) val += W3[k * 128 + c] * ar3[c]; }
    }
    WelT[layer * 2048 + n * 128 + k] = f2bf(val);
}

// ---------------- prep: hi/lo bf16 splits of W_emb [128,128] and Wa [128,100] ----------------
// outputs transposed [n][k]; Wa zero-padded to n=128
__global__ __launch_bounds__(256) void k_prep_hilo(const float* __restrict__ W_emb,
                                                   const float* __restrict__ Wa,
                                                   short* __restrict__ WembT_hi,
                                                   short* __restrict__ WembT_lo,
                                                   short* __restrict__ WaT_hi,
                                                   short* __restrict__ WaT_lo) {
    int i = blockIdx.x * 256 + threadIdx.x;   // 2*16384 total
    if (i >= 2 * 16384) return;
    int m = i >> 14;
    int r = i & 16383;
    int n = r >> 7, k = r & 127;
    if (m == 0) {
        float w = W_emb[k * 128 + n];
        short h = f2bf(w);
        WembT_hi[n * 128 + k] = h;
        WembT_lo[n * 128 + k] = f2bf(w - bf2f(h));
    } else {
        float w = (n < 100) ? Wa[k * 100 + n] : 0.f;
        short h = f2bf(w);
        WaT_hi[n * 128 + k] = h;
        WaT_lo[n * 128 + k] = f2bf(w - bf2f(h));
    }
}

// ---------------- fp32-accurate MFMA GEMM via 3-term hi/lo split ----------------
__global__ __launch_bounds__(256) void k_mfma_hilo(const float* __restrict__ A,
                                                   const short* __restrict__ BT_hi,
                                                   const short* __restrict__ BT_lo,
                                                   const float* __restrict__ bias,
                                                   float* __restrict__ C, int ncols) {
    __shared__ short sAh[64 * 136];
    __shared__ short sAl[64 * 136];
    __shared__ short sBh[128 * 136];
    int t = threadIdx.x;
    int r0 = blockIdx.x * 64;
    // stage B_hi: each thread copies 64 bf16
    {
        int n = t >> 1;
        int k0 = (t & 1) * 64;
#pragma unroll
        for (int j = 0; j < 8; j++) {
            bf16x8 v = *(const bf16x8*)(BT_hi + n * 128 + k0 + 8 * j);
            *(bf16x8*)(sBh + n * 136 + k0 + 8 * j) = v;
        }
    }
    // stage A hi/lo: each thread converts 32 floats
    {
        int r = t >> 2;
        int k0 = (t & 3) * 32;
        const float* ar = A + (size_t)(r0 + r) * 128 + k0;
#pragma unroll
        for (int j = 0; j < 4; j++) {
            float4 f0 = *(const float4*)(ar + 8 * j);
            float4 f1 = *(const float4*)(ar + 8 * j + 4);
            float x[8] = {f0.x, f0.y, f0.z, f0.w, f1.x, f1.y, f1.z, f1.w};
            bf16x8 vh, vl;
#pragma unroll
            for (int q = 0; q < 8; q++) {
                short hh = f2bf(x[q]);
                vh[q] = hh;
                vl[q] = f2bf(x[q] - bf2f(hh));
            }
            *(bf16x8*)(sAh + r * 136 + k0 + 8 * j) = vh;
            *(bf16x8*)(sAl + r * 136 + k0 + 8 * j) = vl;
        }
    }
    __syncthreads();
    int lane = t & 63, wv = t >> 6;
    int lm = lane & 15, quad = lane >> 4;
    int m0 = wv * 16;
    bf16x8 aH[4], aL[4];
#pragma unroll
    for (int kt = 0; kt < 4; kt++) {
        aH[kt] = *(const bf16x8*)(sAh + (m0 + lm) * 136 + kt * 32 + quad * 8);
        aL[kt] = *(const bf16x8*)(sAl + (m0 + lm) * 136 + kt * 32 + quad * 8);
    }
#pragma unroll
    for (int nt = 0; nt < 8; nt++) {
        const short* blp = BT_lo + (nt * 16 + lm) * 128 + quad * 8;
        floatx4 acc = (floatx4){0.f, 0.f, 0.f, 0.f};
#pragma unroll
        for (int kt = 0; kt < 4; kt++) {
            bf16x8 bH = *(const bf16x8*)(sBh + (nt * 16 + lm) * 136 + kt * 32 + quad * 8);
            bf16x8 bL = *(const bf16x8*)(blp + kt * 32);
            acc = __builtin_amdgcn_mfma_f32_16x16x32_bf16(aH[kt], bH, acc, 0, 0, 0);
            acc = __builtin_amdgcn_mfma_f32_16x16x32_bf16(aL[kt], bH, acc, 0, 0, 0);
            acc = __builtin_amdgcn_mfma_f32_16x16x32_bf16(aH[kt], bL, acc, 0, 0, 0);
        }
        int col = nt * 16 + lm;
        if (col < ncols) {
            float bv = bias ? bias[col] : 0.f;
#pragma unroll
            for (int r = 0; r < 4; r++) {
                int row = r0 + m0 + quad * 4 + r;
                C[(size_t)row * ncols + col] = acc[r] + bv;
            }
        }
    }
}

// ---------------- MFMA GEMM: [N,128](fp32) @ WbT(bf16 [n][k]) -> bf16 out ----------------
// 64 rows/block, full N=128. A converted fp32->bf16 into LDS (+8 pad = 2-way bank, free).
// Optional fused el/er epilogue (replaces k_elr pass — r9, validated).
// Optional fused BN prologue: when bnx!=null, stage A computes
// h = mask(bnh + elu(scale*x+shift)) in place of reading A, writes hout (=h_cur) and
// converts to bf16 LDS in the same pass. Per-column scale/shift precomputed into LDS
// (one rsqrt per column per block). Replaces 3 of 4 k_bn_apply dispatches.
__global__ __launch_bounds__(256) void k_gemm_mfma(const float* __restrict__ A,
                                                   const short* __restrict__ WbT,
                                                   const float* __restrict__ bias,
                                                   short* __restrict__ C,
                                                   const short* __restrict__ WelT,
                                                   float* __restrict__ el,
                                                   float* __restrict__ er,
                                                   int H,
                                                   const float* __restrict__ bnx,
                                                   const float* __restrict__ bnh,
                                                   const float* __restrict__ csum,
                                                   const float* __restrict__ csq,
                                                   const float* __restrict__ bng,
                                                   const float* __restrict__ bnb,
                                                   float* __restrict__ hout,
                                                   int do_mask) {
    __shared__ short sA[64 * 136];
    __shared__ short sB[128 * 136];
    __shared__ float sScale[128];
    __shared__ float sShift[128];
    int t = threadIdx.x;
    int r0 = blockIdx.x * 64;
    if (bnx) {
        if (t < 128) {
            const float invN = 1.f / (float)N_;
            float mu = csum[t] * invN;
            float var = csq[t] * invN - mu * mu;
            float inv = rsqrtf(var + 1e-5f);
            float sc = bng[t] * inv;
            sScale[t] = sc;
            sShift[t] = bnb[t] - mu * sc;
        }
        __syncthreads();
    }
    // stage B: each thread copies 64 bf16
    {
        int n = t >> 1;
        int k0 = (t & 1) * 64;
#pragma unroll
        for (int j = 0; j < 8; j++) {
            bf16x8 v = *(const bf16x8*)(WbT + n * 128 + k0 + 8 * j);
            *(bf16x8*)(sB + n * 136 + k0 + 8 * j) = v;
        }
    }
    // stage A: each thread handles 32 elements of one row-quarter
    {
        int r = t >> 2;
        int k0 = (t & 3) * 32;
        if (bnx) {
            const float* xr = bnx + (size_t)(r0 + r) * 128 + k0;
            const float* hr = bnh + (size_t)(r0 + r) * 128 + k0;
            float* ho = hout + (size_t)(r0 + r) * 128 + k0;
#pragma unroll
            for (int j = 0; j < 4; j++) {
                float4 x0 = *(const float4*)(xr + 8 * j);
                float4 x1 = *(const float4*)(xr + 8 * j + 4);
                float4 h0 = *(const float4*)(hr + 8 * j);
                float4 h1 = *(const float4*)(hr + 8 * j + 4);
                float xs[8] = {x0.x, x0.y, x0.z, x0.w, x1.x, x1.y, x1.z, x1.w};
                float hs[8] = {h0.x, h0.y, h0.z, h0.w, h1.x, h1.y, h1.z, h1.w};
                float ov[8];
                bf16x8 v;
#pragma unroll
                for (int q = 0; q < 8; q++) {
                    int c = k0 + 8 * j + q;
                    float y = sScale[c] * xs[q] + sShift[c];
                    y = y > 0.f ? y : (__expf(y) - 1.f);
                    float hv = hs[q] + y;
                    if (do_mask && isinf(hv)) hv = 1e9f;
                    ov[q] = hv;
                    v[q] = f2bf(hv);
                }
                *(float4*)(ho + 8 * j) = make_float4(ov[0], ov[1], ov[2], ov[3]);
                *(float4*)(ho + 8 * j + 4) = make_float4(ov[4], ov[5], ov[6], ov[7]);
                *(bf16x8*)(sA + r * 136 + k0 + 8 * j) = v;
            }
        } else {
            const float* ar = A + (size_t)(r0 + r) * 128 + k0;
#pragma unroll
            for (int j = 0; j < 4; j++) {
                float4 f0 = *(const float4*)(ar + 8 * j);
                float4 f1 = *(const float4*)(ar + 8 * j + 4);
                bf16x8 v;
                v[0] = f2bf(f0.x); v[1] = f2bf(f0.y); v[2] = f2bf(f0.z); v[3] = f2bf(f0.w);
                v[4] = f2bf(f1.x); v[5] = f2bf(f1.y); v[6] = f2bf(f1.z); v[7] = f2bf(f1.w);
                *(bf16x8*)(sA + r * 136 + k0 + 8 * j) = v;
            }
        }
    }
    __syncthreads();
    int lane = t & 63, wv = t >> 6;
    int lm = lane & 15, quad = lane >> 4;
    int m0 = wv * 16;
    bf16x8 aF[4];
#pragma unroll
    for (int kt = 0; kt < 4; kt++)
        aF[kt] = *(const bf16x8*)(sA + (m0 + lm) * 136 + kt * 32 + quad * 8);
#pragma unroll
    for (int nt = 0; nt < 8; nt++) {
        floatx4 acc = (floatx4){0.f, 0.f, 0.f, 0.f};
#pragma unroll
        for (int kt = 0; kt < 4; kt++) {
            bf16x8 bF = *(const bf16x8*)(sB + (nt * 16 + lm) * 136 + kt * 32 + quad * 8);
            acc = __builtin_amdgcn_mfma_f32_16x16x32_bf16(aF[kt], bF, acc, 0, 0, 0);
        }
        int col = nt * 16 + lm;
        float bv = bias ? bias[col] : 0.f;
#pragma unroll
        for (int r = 0; r < 4; r++) {
            int row = r0 + m0 + quad * 4 + r;
            C[(size_t)row * 128 + col] = f2bf(acc[r] + bv);
        }
    }
    // fused el/er tile: cols 0..7 = el heads, 8..15 = er heads (H=1: col0=el, col1=er)
    if (WelT) {
        floatx4 acc = (floatx4){0.f, 0.f, 0.f, 0.f};
#pragma unroll
        for (int kt = 0; kt < 4; kt++) {
            bf16x8 wF = *(const bf16x8*)(WelT + lm * 128 + kt * 32 + quad * 8);
            acc = __builtin_amdgcn_mfma_f32_16x16x32_bf16(aF[kt], wF, acc, 0, 0, 0);
        }
        if (H == 8) {
#pragma unroll
            for (int r = 0; r < 4; r++) {
                int row = r0 + m0 + quad * 4 + r;
                if (lm < 8) el[(size_t)row * 8 + lm] = acc[r];
                else        er[(size_t)row * 8 + (lm - 8)] = acc[r];
            }
        } else {
#pragma unroll
            for (int r = 0; r < 4; r++) {
                int row = r0 + m0 + quad * 4 + r;
                if (lm == 0) el[row] = acc[r];
                if (lm == 1) er[row] = acc[r];
            }
        }
    }
}

// ---------------- softmax over 100 logits, wave per node, barrier-free ----------------
__global__ __launch_bounds__(256) void k_smax100(const float* __restrict__ logits,
                                                 float* __restrict__ s) {
    int lane = threadIdx.x & 63;
    int n = blockIdx.x * 4 + (threadIdx.x >> 6);
    if (n >= N_) return;
    bool act = lane < 50;
    float2 v = make_float2(-INFINITY, -INFINITY);
    if (act) v = *(const float2*)(logits + (size_t)n * 100 + 2 * lane);
    float mx = fmaxf(v.x, v.y);
#pragma unroll
    for (int off = 1; off < 64; off <<= 1) mx = fmaxf(mx, __shfl_xor(mx, off));
    float e0 = act ? __expf(v.x - mx) : 0.f;
    float e1 = act ? __expf(v.y - mx) : 0.f;
    float sm = e0 + e1;
#pragma unroll
    for (int off = 1; off < 64; off <<= 1) sm += __shfl_xor(sm, off);
    float inv = 1.f / sm;
    if (act) *(float2*)(s + (size_t)n * 100 + 2 * lane) = make_float2(e0 * inv, e1 * inv);
}

// ---------------- GAT edge-softmax + aggregate (wave per dst node, bf16 feat) ----------------
// v4 (proven config). Do not re-fuse stats (atomic-burst, r7) and do not
// rewrite pass 1 (compiler pipelining, r7).
template <int H>
__global__ __launch_bounds__(256) void k_gat_agg(const short* __restrict__ feat,
                                                 const float* __restrict__ el,
                                                 const float* __restrict__ er,
                                                 const int* __restrict__ rowptr,
                                                 const int* __restrict__ srcv,
                                                 const float* __restrict__ bias,
                                                 float* __restrict__ xout) {
    int lane = threadIdx.x & 63;
    int gw = (blockIdx.x * blockDim.x + threadIdx.x) >> 6;
    int nw = (gridDim.x * blockDim.x) >> 6;
    constexpr int LH = (H == 8) ? 3 : 0;
    int h = lane & (H - 1);
    int f0 = 2 * lane;
    int hf = (H == 8) ? (lane >> 3) : 0;   // head owning this lane's feature slice

    for (int n = gw; n < N_; n += nw) {
        int beg = rowptr[n], end = rowptr[n + 1];
        if (beg == end) {
            *(float2*)(xout + (size_t)n * 128 + f0) = *(const float2*)(bias + f0);
            continue;
        }
        float ern = er[(size_t)n * H + h];
        // ---- pass 1: online softmax stats ----
        float m = -INFINITY, ss = 0.f;
        for (int e = beg + (lane >> LH); e < end; e += (64 >> LH)) {
            int sI = srcv[e];
            float x = el[(size_t)sI * H + h] + ern;
            float lr = x > 0.f ? x : 0.2f * x;
            if (lr > m) { ss = ss * __expf(m - lr) + 1.f; m = lr; }
            else ss += __expf(lr - m);
        }
#pragma unroll
        for (int off = H; off < 64; off <<= 1) {
            float om = __shfl_xor(m, off);
            float os = __shfl_xor(ss, off);
            float nm = fmaxf(m, om);
            float p1 = (m == -INFINITY) ? 0.f : ss * __expf(m - nm);
            float p2 = (om == -INFINITY) ? 0.f : os * __expf(om - nm);
            m = nm; ss = p1 + p2;
        }
        // after butterfly each lane holds (m, ss) for its own head h = lane&(H-1)
        float inv_d = 1.f / ss;
        // ---- pass 2: 2x interleaved chunked aggregation ----
        int endm1 = end - 1;
        float accx = 0.f, accy = 0.f;
        for (int e0 = beg; e0 < end; e0 += 16) {
            int le = lane >> 3;
            int eLA = e0 + le, eLB = e0 + 8 + le;
            int eCA = eLA <= endm1 ? eLA : endm1;
            int eCB = eLB <= endm1 ? eLB : endm1;
            int sLA = srcv[eCA];
            int sLB = srcv[eCB];
            float xA = el[(size_t)sLA * H + h] + ern;
            float xB = el[(size_t)sLB * H + h] + ern;
            float lrA = xA > 0.f ? xA : 0.2f * xA;
            float lrB = xB > 0.f ? xB : 0.2f * xB;
            float wA = __expf(lrA - m) * inv_d;
            float wB = __expf(lrB - m) * inv_d;
            if (eLA > endm1) wA = 0.f;
            if (eLB > endm1) wB = 0.f;
            bool haveB = (e0 + 8) < end;    // wave-uniform
            unsigned int uuA[8], uuB[8];
#pragma unroll
            for (int j = 0; j < 8; j++) {
                int sj = __builtin_amdgcn_readlane(sLA, j * 8);
                uuA[j] = *(const unsigned int*)(feat + (size_t)sj * 128 + f0);
            }
            if (haveB) {
#pragma unroll
                for (int j = 0; j < 8; j++) {
                    int sj = __builtin_amdgcn_readlane(sLB, j * 8);
                    uuB[j] = *(const unsigned int*)(feat + (size_t)sj * 128 + f0);
                }
            }
#pragma unroll
            for (int j = 0; j < 8; j++) {
                float aj;
                if (H == 8) aj = __shfl(wA, j * 8 + hf);
                else        aj = rdlane(wA, j * 8);
                accx += aj * bflo(uuA[j]);
                accy += aj * bfhi(uuA[j]);
            }
            if (haveB) {
#pragma unroll
                for (int j = 0; j < 8; j++) {
                    float aj;
                    if (H == 8) aj = __shfl(wB, j * 8 + hf);
                    else        aj = rdlane(wB, j * 8);
                    accx += aj * bflo(uuB[j]);
                    accy += aj * bfhi(uuB[j]);
                }
            }
        }
        float2 b2 = *(const float2*)(bias + f0);
        *(float2*)(xout + (size_t)n * 128 + f0) = make_float2(accx + b2.x, accy + b2.y);
    }
}

// ---------------- BN stats ----------------
__global__ __launch_bounds__(256) void k_bn_stats(const float* __restrict__ x,
                                                  float* __restrict__ sum,
                                                  float* __restrict__ sumsq) {
    __shared__ float ls[256], lq[256];
    int t = threadIdx.x;
    int col = t & 127, half = t >> 7;
    float s = 0.f, q = 0.f;
    for (int r = blockIdx.x * 2 + half; r < N_; r += gridDim.x * 2) {
        float v = x[(size_t)r * 128 + col];
        s += v; q += v * v;
    }
    ls[t] = s; lq[t] = q;
    __syncthreads();
    if (t < 128) {
        atomicAdd(&sum[col], ls[t] + ls[t + 128]);
        atomicAdd(&sumsq[col], lq[t] + lq[t + 128]);
    }
}

// ---------------- BN apply + ELU + residual (+mask) — layer-1 only ----------------
__global__ __launch_bounds__(256) void k_bn_apply(const float* __restrict__ x,
                                                  const float* __restrict__ hprev,
                                                  const float* __restrict__ sum,
                                                  const float* __restrict__ sumsq,
                                                  const float* __restrict__ g,
                                                  const float* __restrict__ b,
                                                  float* __restrict__ out, int do_mask) {
    int i = blockIdx.x * blockDim.x + threadIdx.x;
    if (i >= N_ * 128) return;
    int c = i & 127;
    const float invN = 1.f / (float)N_;
    float mu = sum[c] * invN;
    float var = sumsq[c] * invN - mu * mu;
    float inv = rsqrtf(var + 1e-5f);
    float y = g[c] * (x[i] - mu) * inv + b[c];
    y = y > 0.f ? y : (__expf(y) - 1.f);
    float hv = hprev[i] + y;
    if (do_mask && isinf(hv)) hv = 1e9f;
    out[i] = hv;
}

// ---------------- h_coarse partials ----------------
__global__ __launch_bounds__(512) void k_coarse_part(const float* __restrict__ s,
                                                     const float* __restrict__ hf,
                                                     float* __restrict__ part) {
    int t = threadIdx.x;
    int c = t & 127;
    int g = t >> 7;        // 0..3
    int lane = t & 63;
    float acc[25];
#pragma unroll
    for (int a = 0; a < 25; a++) acc[a] = 0.f;
    int n0 = blockIdx.x * CR_;
    for (int n = n0; n < n0 + CR_; n += 2) {
        float hv0 = hf[(size_t)n * 128 + c];
        float hv1 = hf[(size_t)(n + 1) * 128 + c];
        float sv0 = 0.f, sv1 = 0.f;
        if (lane < 25) {
            sv0 = s[(size_t)n * 100 + 25 * g + lane];
            sv1 = s[(size_t)(n + 1) * 100 + 25 * g + lane];
        }
#pragma unroll
        for (int a = 0; a < 25; ++a) {
            float a0 = rdlane(sv0, a);
            float a1 = rdlane(sv1, a);
            acc[a] += a0 * hv0 + a1 * hv1;
        }
    }
    float* dstp = part + (size_t)blockIdx.x * 12800 + (size_t)(25 * g) * 128 + c;
#pragma unroll
    for (int a = 0; a < 25; a++) dstp[a * 128] = acc[a];
}

// ---------------- reduce partials -> hc[100][128] ----------------
__global__ __launch_bounds__(256) void k_coarse_reduce(const float* __restrict__ part,
                                                       float* __restrict__ hc) {
    int i = blockIdx.x * blockDim.x + threadIdx.x;  // 12800 total
    if (i >= 12800) return;
    float s0 = 0.f, s1 = 0.f, s2 = 0.f, s3 = 0.f;
    for (int b = 0; b < CB_; b += 4) {
        s0 += part[(size_t)(b + 0) * 12800 + i];
        s1 += part[(size_t)(b + 1) * 12800 + i];
        s2 += part[(size_t)(b + 2) * 12800 + i];
        s3 += part[(size_t)(b + 3) * 12800 + i];
    }
    hc[i] = (s0 + s1) + (s2 + s3);
}

// ---------------- h = mask(0.5*h_fine + 0.5*(s@h_coarse)) ----------------
__global__ __launch_bounds__(256) void k_combine(const float* __restrict__ s,
                                                 const float* __restrict__ hc,
                                                 const float* __restrict__ hfine,
                                                 float* __restrict__ hout) {
    __shared__ float ssh[16 * 100];
    int t = threadIdx.x;
    int n0 = blockIdx.x * 16;
    for (int u = t; u < 1600; u += 256) ssh[u] = s[(size_t)n0 * 100 + u];
    __syncthreads();
    int c = t & 127, g = t >> 7;
    float acc[8];
#pragma unroll
    for (int r = 0; r < 8; r++) acc[r] = 0.f;
    const float* hcp = hc + c;
    for (int a = 0; a < 100; a += 4) {
        float h0 = hcp[(a + 0) * 128];
        float h1 = hcp[(a + 1) * 128];
        float h2 = hcp[(a + 2) * 128];
        float h3 = hcp[(a + 3) * 128];
#pragma unroll
        for (int r = 0; r < 8; r++) {
            float4 sv = *(const float4*)(ssh + (g * 8 + r) * 100 + a);
            acc[r] += sv.x * h0 + sv.y * h1 + sv.z * h2 + sv.w * h3;
        }
    }
#pragma unroll
    for (int r = 0; r < 8; r++) {
        int row = n0 + g * 8 + r;
        float v = 0.5f * hfine[(size_t)row * 128 + c] + 0.5f * acc[r];
        if (isinf(v)) v = 1e9f;
        hout[(size_t)row * 128 + c] = v;
    }
}

// ---------------- prep: Wm2 [128][64] fp32 -> Wm2T bf16 [64][128] ----------------
__global__ __launch_bounds__(256) void k_prep_w(const float* __restrict__ Wm2,
                                                short* __restrict__ Wm2T) {
    int i = blockIdx.x * blockDim.x + threadIdx.x;  // 8192 total
    if (i >= 64 * 128) return;
    int n = i & 63, k = i >> 6;
    Wm2T[n * 128 + k] = f2bf(Wm2[k * 64 + n]);
}

// ---------------- edge MLP readout: dst-sorted order, barrier-free persistent MFMA ----------------
// v2 — LOCAL OPTIMUM at ~54us, VGPR 84. Do not register-diet (v3: spills, 3x dur).
// Do not 2-tile (v4: compiler serializes the B-tile loads, occupancy drops, +6us).
__global__ __launch_bounds__(256) void k_edge_mlp3(const short* __restrict__ Pb,
                                                   const short* __restrict__ Qb,
                                                   const int* __restrict__ srcv,
                                                   const unsigned short* __restrict__ dstv,
                                                   const int* __restrict__ eidv,
                                                   const short* __restrict__ Wm2T,
                                                   const float* __restrict__ bm2,
                                                   const float* __restrict__ Wm3,
                                                   const float* __restrict__ bm3,
                                                   float* __restrict__ zout) {
    __shared__ short sW[64 * 128];  // 16 KiB
    int t = threadIdx.x;
    // stage Wm2T -> LDS with 16B-unit XOR swizzle: phys_unit = n*16 + (k16 ^ (n&15))
    for (int u = t; u < 1024; u += 256) {
        int n = u >> 4, k16 = u & 15;
        int phys = (n << 4) | (k16 ^ (n & 15));
        *(bf16x8*)(sW + phys * 8) = *(const bf16x8*)(Wm2T + n * 128 + k16 * 8);
    }
    int lane = t & 63;
    int lm = lane & 15, quad = lane >> 4;
    float bv[4], w30[4], w31[4];
#pragma unroll
    for (int nt = 0; nt < 4; nt++) {
        int n = nt * 16 + lm;
        bv[nt] = bm2[n]; w30[nt] = Wm3[2 * n]; w31[nt] = Wm3[2 * n + 1];
    }
    float b30 = bm3[0], b31 = bm3[1];
    __syncthreads();

    int gw = (blockIdx.x * blockDim.x + t) >> 6;
    int nw = (gridDim.x * blockDim.x) >> 6;

    for (int tile = gw; tile < E_ / 16; tile += nw) {
        int p0 = tile * 16;
        int sI = srcv[p0 + lm];
        int dI = (int)dstv[p0 + lm];
        const short* pr = Pb + (size_t)sI * 128 + quad * 8;
        const short* qr = Qb + (size_t)dI * 128 + quad * 8;
        // issue all 8 gathers up-front (latency hidden within wave)
        uint4 pu[4], qu[4];
#pragma unroll
        for (int kt = 0; kt < 4; kt++) {
            pu[kt] = *(const uint4*)(pr + kt * 32);
            qu[kt] = *(const uint4*)(qr + kt * 32);
        }
        bf16x8 aF[4];
#pragma unroll
        for (int kt = 0; kt < 4; kt++) {
            unsigned int pv[4] = {pu[kt].x, pu[kt].y, pu[kt].z, pu[kt].w};
            unsigned int qv[4] = {qu[kt].x, qu[kt].y, qu[kt].z, qu[kt].w};
            union { uint4 u; bf16x8 v; } cv;
            unsigned int rr[4];
#pragma unroll
            for (int j = 0; j < 4; j++) {
                float fl = fmaxf(bflo(pv[j]) + bflo(qv[j]), 0.f);
                float fh = fmaxf(bfhi(pv[j]) + bfhi(qv[j]), 0.f);
                rr[j] = (unsigned int)(unsigned short)f2bf(fl) |
                        ((unsigned int)(unsigned short)f2bf(fh) << 16);
            }
            cv.u.x = rr[0]; cv.u.y = rr[1]; cv.u.z = rr[2]; cv.u.w = rr[3];
            aF[kt] = cv.v;
        }
        float pz0[4] = {0.f, 0.f, 0.f, 0.f};
        float pz1[4] = {0.f, 0.f, 0.f, 0.f};
#pragma unroll
        for (int nt = 0; nt < 4; nt++) {
            floatx4 acc = (floatx4){0.f, 0.f, 0.f, 0.f};
#pragma unroll
            for (int kt = 0; kt < 4; kt++) {
                int phys = ((nt * 16 + lm) << 4) | (((kt << 2) | quad) ^ lm);
                bf16x8 bF = *(const bf16x8*)(sW + phys * 8);
                acc = __builtin_amdgcn_mfma_f32_16x16x32_bf16(aF[kt], bF, acc, 0, 0, 0);
            }
#pragma unroll
            for (int r = 0; r < 4; r++) {
                float u = fmaxf(acc[r] + bv[nt], 0.f);
                pz0[r] += u * w30[nt];
                pz1[r] += u * w31[nt];
            }
        }
#pragma unroll
        for (int off = 1; off < 16; off <<= 1) {
#pragma unroll
            for (int r = 0; r < 4; r++) {
                pz0[r] += __shfl_xor(pz0[r], off);
                pz1[r] += __shfl_xor(pz1[r], off);
            }
        }
        if (lm < 4) {
            int eid = eidv[p0 + quad * 4 + lm];
            float z0 = pz0[lm] + b30;
            float z1 = pz1[lm] + b31;
            if (isinf(z0)) z0 = 1e9f;
            if (isinf(z1)) z1 = 1e9f;
            *(float2*)(zout + (size_t)eid * 2) = make_float2(z0, z1);
        }
    }
}

extern "C" void kernel_launch(void* const* d_in, const int* in_sizes, int n_in,
                              void* d_out, int out_size, void* d_ws, size_t ws_size,
                              hipStream_t stream) {
    const float* h_in  = (const float*)d_in[0];
    const int*   src   = (const int*)d_in[2];
    const int*   dst   = (const int*)d_in[3];
    const float* W_emb = (const float*)d_in[4];
    const float* b_emb = (const float*)d_in[5];
    const float* Wg    = (const float*)d_in[6];
    const float* alg   = (const float*)d_in[7];
    const float* arg_  = (const float*)d_in[8];
    const float* bg    = (const float*)d_in[9];
    const float* gam   = (const float*)d_in[10];
    const float* bet   = (const float*)d_in[11];
    const float* W3    = (const float*)d_in[12];
    const float* al3   = (const float*)d_in[13];
    const float* ar3   = (const float*)d_in[14];
    const float* b3    = (const float*)d_in[15];
    const float* gam3  = (const float*)d_in[16];
    const float* bet3  = (const float*)d_in[17];
    const float* Wa    = (const float*)d_in[18];
    const float* ba    = (const float*)d_in[19];
    const float* Wm1   = (const float*)d_in[20];
    const float* bm1   = (const float*)d_in[21];
    const float* Wm2   = (const float*)d_in[22];
    const float* bm2   = (const float*)d_in[23];
    const float* Wm3   = (const float*)d_in[24];
    const float* bm3   = (const float*)d_in[25];

    float* zout = (float*)d_out;
    float* sout = zout + (size_t)E_ * 2;

    float* ws = (float*)d_ws;
    size_t o = 0;
    float* h_cur = ws + o; o += (size_t)N_ * 128;
    float* xbuf  = ws + o; o += (size_t)N_ * 128;
    float* featb = ws + o; o += (size_t)N_ * 128;   // reused: bf16 feat, coarse partials, bf16 P/Q
    float* el    = ws + o; o += (size_t)N_ * 8;
    float* er    = ws + o; o += (size_t)N_ * 8;
    float* colsum = ws + o; o += 128;
    float* colsq  = ws + o; o += 128;
    float* hc     = ws + o; o += 100 * 128;
    short* Wm2T = (short*)(ws + o); o += (64 * 128) / 2;
    short* WbT6 = (short*)(ws + o); o += (6 * 16384) / 2;
    short* WelT = (short*)(ws + o); o += (4 * 2048) / 2;
    short* WembT_hi = (short*)(ws + o); o += 16384 / 2;
    short* WembT_lo = (short*)(ws + o); o += 16384 / 2;
    short* WaT_hi   = (short*)(ws + o); o += 16384 / 2;
    short* WaT_lo   = (short*)(ws + o); o += 16384 / 2;
    int* counts = (int*)(ws + o); o += N_;
    int* rowptr = (int*)(ws + o); o += N_ + 4;
    int* cursor = (int*)(ws + o); o += N_;
    int* srcv   = (int*)(ws + o); o += E_;
    unsigned short* dstv = (unsigned short*)(ws + o); o += E_ / 2;
    int* eidv   = (int*)(ws + o); o += E_;
    int* bsum   = (int*)(ws + o); o += SNB_ + 4;

    short* featw = (short*)featb;  // bf16 per-layer projection

    // ---- CSR build (parallel scan; excl scratch reuses eidv pre-fill) ----
    hipMemsetAsync(counts, 0, N_ * sizeof(int), stream);
    k_count<<<1024, 256, 0, stream>>>(dst, counts);
    k_scanA<<<SNB_, 256, 0, stream>>>(counts, eidv, bsum);
    k_scanB<<<1, 256, 0, stream>>>(bsum);
    k_scanC<<<SNB_ + 1, 256, 0, stream>>>(eidv, bsum, rowptr, cursor);
    k_fill<<<1024, 256, 0, stream>>>(src, dst, cursor, srcv, dstv, eidv);
    k_prep_w<<<32, 256, 0, stream>>>(Wm2, Wm2T);
    k_prep_all<<<384, 256, 0, stream>>>(Wg, W3, Wm1, WbT6);
    k_prep_wela<<<32, 256, 0, stream>>>(Wg, alg, arg_, W3, al3, ar3, WelT);
    k_prep_hilo<<<128, 256, 0, stream>>>(W_emb, Wa, WembT_hi, WembT_lo, WaT_hi, WaT_lo);

    // ---- embedding (fp32-accurate via hi/lo MFMA) ----
    k_mfma_hilo<<<N_ / 64, 256, 0, stream>>>(h_in, WembT_hi, WembT_lo, b_emb, h_cur, 128);

    // ---- layer 0 (H=8) ----
    k_gemm_mfma<<<N_ / 64, 256, 0, stream>>>(h_cur, WbT6 + 0 * 16384, nullptr, featw,
                                             WelT + 0 * 2048, el, er, 8,
                                             nullptr, nullptr, nullptr, nullptr,
                                             nullptr, nullptr, nullptr, 0);
    k_gat_agg<8><<<2048, 256, 0, stream>>>(featw, el, er, rowptr, srcv, bg + 0 * 128, xbuf);
    hipMemsetAsync(colsum, 0, 256 * sizeof(float), stream);
    k_bn_stats<<<512, 256, 0, stream>>>(xbuf, colsum, colsq);

    // ---- layer 1 (biGAT, H=8): gemm fused with layer-0 BN (writes h_cur) ----
    k_gemm_mfma<<<N_ / 64, 256, 0, stream>>>(nullptr, WbT6 + 1 * 16384, nullptr, featw,
                                             WelT + 1 * 2048, el, er, 8,
                                             xbuf, h_cur, colsum, colsq,
                                             gam + 0 * 128, bet + 0 * 128, h_cur, 1);
    k_mfma_hilo<<<N_ / 64, 256, 0, stream>>>(h_cur, WaT_hi, WaT_lo, ba, xbuf, 100);
    k_smax100<<<N_ / 4, 256, 0, stream>>>(xbuf, sout);
    k_gat_agg<8><<<2048, 256, 0, stream>>>(featw, el, er, rowptr, srcv, bg + 1 * 128, xbuf);
    hipMemsetAsync(colsum, 0, 256 * sizeof(float), stream);
    k_bn_stats<<<512, 256, 0, stream>>>(xbuf, colsum, colsq);
    k_bn_apply<<<(N_ * 128) / 256, 256, 0, stream>>>(xbuf, h_cur, colsum, colsq,
                                                     gam + 1 * 128, bet + 1 * 128, xbuf, 0);
    k_coarse_part<<<CB_, 512, 0, stream>>>(sout, xbuf, featb);
    k_coarse_reduce<<<50, 256, 0, stream>>>(featb, hc);
    k_combine<<<N_ / 16, 256, 0, stream>>>(sout, hc, xbuf, h_cur);

    // ---- layer 2 (H=8) ----
    k_gemm_mfma<<<N_ / 64, 256, 0, stream>>>(h_cur, WbT6 + 2 * 16384, nullptr, featw,
                                             WelT + 2 * 2048, el, er, 8,
                                             nullptr, nullptr, nullptr, nullptr,
                                             nullptr, nullptr, nullptr, 0);
    k_gat_agg<8><<<2048, 256, 0, stream>>>(featw, el, er, rowptr, srcv, bg + 2 * 128, xbuf);
    hipMemsetAsync(colsum, 0, 256 * sizeof(float), stream);
    k_bn_stats<<<512, 256, 0, stream>>>(xbuf, colsum, colsq);

    // ---- layer 3 (H=1): gemm fused with layer-2 BN (writes h_cur) ----
    k_gemm_mfma<<<N_ / 64, 256, 0, stream>>>(nullptr, WbT6 + 3 * 16384, nullptr, featw,
                                             WelT + 3 * 2048, el, er, 1,
                                             xbuf, h_cur, colsum, colsq,
                                             gam + 2 * 128, bet + 2 * 128, h_cur, 1);
    k_gat_agg<1><<<2048, 256, 0, stream>>>(featw, el, er, rowptr, srcv, b3, xbuf);
    hipMemsetAsync(colsum, 0, 256 * sizeof(float), stream);
    k_bn_stats<<<512, 256, 0, stream>>>(xbuf, colsum, colsq);

    // ---- edge MLP readout: Pb gemm fused with layer-3 BN (writes h_cur) ----
    short* Pb = (short*)featb;
    short* Qb = Pb + (size_t)N_ * 128;
    k_gemm_mfma<<<N_ / 64, 256, 0, stream>>>(nullptr, WbT6 + 4 * 16384, bm1, Pb,
                                             nullptr, nullptr, nullptr, 0,
                                             xbuf, h_cur, colsum, colsq,
                                             gam3, bet3, h_cur, 1);
    k_gemm_mfma<<<N_ / 64, 256, 0, stream>>>(h_cur, WbT6 + 5 * 16384, nullptr, Qb,
                                             nullptr, nullptr, nullptr, 0,
                                             nullptr, nullptr, nullptr, nullptr,
                                             nullptr, nullptr, nullptr, 0);
    k_edge_mlp3<<<2048, 256, 0, stream>>>(Pb, Qb, srcv, dstv, eidv, Wm2T, bm2, Wm3, bm3, zout);
}

// Round 12
// 754.685 us; speedup vs baseline: 1.0811x; 1.0811x over previous
//
#include <hip/hip_runtime.h>
#include <hip/hip_bf16.h>
#include <math.h>

#define N_ 40000
#define E_ 640000
#define CB_ 400   // k_coarse partial blocks
#define CR_ 100   // rows per block (CB_*CR_ == N_)
#define SB_ 256
#define SNB_ 157  // ceil(N_/SB_)
#define AGGB_ 2048  // k_gat_agg grid (blocks); psum/psq sized to this

typedef short bf16x8 __attribute__((ext_vector_type(8)));
typedef float floatx4 __attribute__((ext_vector_type(4)));

__device__ __forceinline__ short f2bf(float f) {
    __hip_bfloat16 h = __float2bfloat16(f);
    return *reinterpret_cast<short*>(&h);
}
__device__ __forceinline__ float bf2f(short u) {
    unsigned int x = ((unsigned int)(unsigned short)u) << 16;
    return __int_as_float(x);
}
__device__ __forceinline__ float rdlane(float v, int l) {
    return __int_as_float(__builtin_amdgcn_readlane(__float_as_int(v), l));
}
// unpack 2 bf16 packed in a uint
__device__ __forceinline__ float bflo(unsigned int u) { return __int_as_float(u << 16); }
__device__ __forceinline__ float bfhi(unsigned int u) { return __int_as_float(u & 0xffff0000u); }

// ---------------- CSR build ----------------
__global__ void k_count(const int* __restrict__ dst, int* __restrict__ counts) {
    for (int e = blockIdx.x * blockDim.x + threadIdx.x; e < E_; e += gridDim.x * blockDim.x)
        atomicAdd(&counts[dst[e]], 1);
}

// ---- 3-phase parallel scan ----
__global__ __launch_bounds__(256) void k_scanA(const int* __restrict__ counts,
                                               int* __restrict__ excl,
                                               int* __restrict__ bsum) {
    int t = threadIdx.x;
    int i = blockIdx.x * SB_ + t;
    int v = (i < N_) ? counts[i] : 0;
    int lane = t & 63, wv = t >> 6;
    int x = v;
#pragma unroll
    for (int off = 1; off < 64; off <<= 1) {
        int y = __shfl_up(x, off);
        if (lane >= off) x += y;
    }
    __shared__ int wsum[4];
    __shared__ int woff[4];
    if (lane == 63) wsum[wv] = x;
    __syncthreads();
    if (t == 0) {
        int a = 0;
#pragma unroll
        for (int j = 0; j < 4; j++) { int tv = wsum[j]; woff[j] = a; a += tv; }
        bsum[blockIdx.x] = a;
    }
    __syncthreads();
    if (i < N_) excl[i] = x - v + woff[wv];
}

__global__ __launch_bounds__(256) void k_scanB(int* __restrict__ bsum) {
    int t = threadIdx.x;
    int v = (t < SNB_) ? bsum[t] : 0;
    int lane = t & 63, wv = t >> 6;
    int x = v;
#pragma unroll
    for (int off = 1; off < 64; off <<= 1) {
        int y = __shfl_up(x, off);
        if (lane >= off) x += y;
    }
    __shared__ int wsum[4];
    __shared__ int woff[4];
    if (lane == 63) wsum[wv] = x;
    __syncthreads();
    if (t == 0) {
        int a = 0;
#pragma unroll
        for (int j = 0; j < 4; j++) { int tv = wsum[j]; woff[j] = a; a += tv; }
    }
    __syncthreads();
    if (t < SNB_) bsum[t] = x - v + woff[wv];
}

__global__ __launch_bounds__(256) void k_scanC(const int* __restrict__ excl,
                                               const int* __restrict__ bsum,
                                               int* __restrict__ rowptr,
                                               int* __restrict__ cursor) {
    int i = blockIdx.x * 256 + threadIdx.x;
    if (i < N_) {
        int r = excl[i] + bsum[i / SB_];
        rowptr[i] = r;
        cursor[i] = r;
    }
    if (i == N_) rowptr[N_] = E_;
}

__global__ void k_fill(const int* __restrict__ src, const int* __restrict__ dst,
                       int* __restrict__ cursor, int* __restrict__ srcv,
                       unsigned short* __restrict__ dstv, int* __restrict__ eidv) {
    for (int e = blockIdx.x * blockDim.x + threadIdx.x; e < E_; e += gridDim.x * blockDim.x) {
        int d = dst[e];
        int pos = atomicAdd(&cursor[d], 1);
        srcv[pos] = src[e];
        dstv[pos] = (unsigned short)d;
        eidv[pos] = e;
    }
}

// ---------------- prep: 6x fp32 [k=128][n=128] -> bf16 [n][k] ----------------
__global__ __launch_bounds__(256) void k_prep_all(const float* __restrict__ Wg,
                                                  const float* __restrict__ W3,
                                                  const float* __restrict__ Wm1,
                                                  short* __restrict__ WbT6) {
    int i = blockIdx.x * 256 + threadIdx.x;   // 6*16384 total
    if (i >= 6 * 16384) return;
    int m = i >> 14;
    int r = i & 16383;
    int n = r >> 7, k = r & 127;
    const float* srcp;
    switch (m) {
        case 0: srcp = Wg; break;
        case 1: srcp = Wg + 16384; break;
        case 2: srcp = Wg + 32768; break;
        case 3: srcp = W3; break;
        case 4: srcp = Wm1; break;
        default: srcp = Wm1 + 16384; break;
    }
    WbT6[m * 16384 + n * 128 + k] = f2bf(srcp[k * 128 + n]);
}

// ---------------- prep: fused el/er weight tiles Wel[layer][16][128] ----------------
// el = (A@W)·al = A@(W@Aexp): Wel[n][k] = sum_d W[k][h*16+d]*a[h*16+d], h=n&7,
// a = al (n<8) or ar (n>=8). Layer 3 (H=1): n==0 -> W3·al3, n==1 -> W3·ar3, else 0.
__global__ __launch_bounds__(256) void k_prep_wela(const float* __restrict__ Wg,
                                                   const float* __restrict__ alg,
                                                   const float* __restrict__ arg_,
                                                   const float* __restrict__ W3,
                                                   const float* __restrict__ al3,
                                                   const float* __restrict__ ar3,
                                                   short* __restrict__ WelT) {
    int i = blockIdx.x * 256 + threadIdx.x;   // 4*16*128 = 8192 total
    if (i >= 4 * 2048) return;
    int layer = i >> 11;
    int r = i & 2047;
    int n = r >> 7, k = r & 127;
    float val = 0.f;
    if (layer < 3) {
        const float* W = Wg + layer * 16384;
        const float* a = (n < 8 ? alg : arg_) + layer * 128;
        int h = n & 7;
#pragma unroll
        for (int d = 0; d < 16; d++)
            val += W[k * 128 + h * 16 + d] * a[h * 16 + d];
    } else {
        if (n == 0) { for (int c = 0; c < 128; c++) val += W3[k * 128 + c] * al3[c]; }
        else if (n == 1) { for (int c = 0; c < 128; c++) val += W3[k * 128 + c] * ar3[c]; }
    }
    WelT[layer * 2048 + n * 128 + k] = f2bf(val);
}

// ---------------- prep: hi/lo bf16 splits of W_emb [128,128] and Wa [128,100] ----------------
// outputs transposed [n][k]; Wa zero-padded to n=128
__global__ __launch_bounds__(256) void k_prep_hilo(const float* __restrict__ W_emb,
                                                   const float* __restrict__ Wa,
                                                   short* __restrict__ WembT_hi,
                                                   short* __restrict__ WembT_lo,
                                                   short* __restrict__ WaT_hi,
                                                   short* __restrict__ WaT_lo) {
    int i = blockIdx.x * 256 + threadIdx.x;   // 2*16384 total
    if (i >= 2 * 16384) return;
    int m = i >> 14;
    int r = i & 16383;
    int n = r >> 7, k = r & 127;
    if (m == 0) {
        float w = W_emb[k * 128 + n];
        short h = f2bf(w);
        WembT_hi[n * 128 + k] = h;
        WembT_lo[n * 128 + k] = f2bf(w - bf2f(h));
    } else {
        float w = (n < 100) ? Wa[k * 100 + n] : 0.f;
        short h = f2bf(w);
        WaT_hi[n * 128 + k] = h;
        WaT_lo[n * 128 + k] = f2bf(w - bf2f(h));
    }
}

// ---------------- fp32-accurate MFMA GEMM via 3-term hi/lo split ----------------
__global__ __launch_bounds__(256) void k_mfma_hilo(const float* __restrict__ A,
                                                   const short* __restrict__ BT_hi,
                                                   const short* __restrict__ BT_lo,
                                                   const float* __restrict__ bias,
                                                   float* __restrict__ C, int ncols) {
    __shared__ short sAh[64 * 136];
    __shared__ short sAl[64 * 136];
    __shared__ short sBh[128 * 136];
    int t = threadIdx.x;
    int r0 = blockIdx.x * 64;
    // stage B_hi: each thread copies 64 bf16
    {
        int n = t >> 1;
        int k0 = (t & 1) * 64;
#pragma unroll
        for (int j = 0; j < 8; j++) {
            bf16x8 v = *(const bf16x8*)(BT_hi + n * 128 + k0 + 8 * j);
            *(bf16x8*)(sBh + n * 136 + k0 + 8 * j) = v;
        }
    }
    // stage A hi/lo: each thread converts 32 floats
    {
        int r = t >> 2;
        int k0 = (t & 3) * 32;
        const float* ar = A + (size_t)(r0 + r) * 128 + k0;
#pragma unroll
        for (int j = 0; j < 4; j++) {
            float4 f0 = *(const float4*)(ar + 8 * j);
            float4 f1 = *(const float4*)(ar + 8 * j + 4);
            float x[8] = {f0.x, f0.y, f0.z, f0.w, f1.x, f1.y, f1.z, f1.w};
            bf16x8 vh, vl;
#pragma unroll
            for (int q = 0; q < 8; q++) {
                short hh = f2bf(x[q]);
                vh[q] = hh;
                vl[q] = f2bf(x[q] - bf2f(hh));
            }
            *(bf16x8*)(sAh + r * 136 + k0 + 8 * j) = vh;
            *(bf16x8*)(sAl + r * 136 + k0 + 8 * j) = vl;
        }
    }
    __syncthreads();
    int lane = t & 63, wv = t >> 6;
    int lm = lane & 15, quad = lane >> 4;
    int m0 = wv * 16;
    bf16x8 aH[4], aL[4];
#pragma unroll
    for (int kt = 0; kt < 4; kt++) {
        aH[kt] = *(const bf16x8*)(sAh + (m0 + lm) * 136 + kt * 32 + quad * 8);
        aL[kt] = *(const bf16x8*)(sAl + (m0 + lm) * 136 + kt * 32 + quad * 8);
    }
#pragma unroll
    for (int nt = 0; nt < 8; nt++) {
        const short* blp = BT_lo + (nt * 16 + lm) * 128 + quad * 8;
        floatx4 acc = (floatx4){0.f, 0.f, 0.f, 0.f};
#pragma unroll
        for (int kt = 0; kt < 4; kt++) {
            bf16x8 bH = *(const bf16x8*)(sBh + (nt * 16 + lm) * 136 + kt * 32 + quad * 8);
            bf16x8 bL = *(const bf16x8*)(blp + kt * 32);
            acc = __builtin_amdgcn_mfma_f32_16x16x32_bf16(aH[kt], bH, acc, 0, 0, 0);
            acc = __builtin_amdgcn_mfma_f32_16x16x32_bf16(aL[kt], bH, acc, 0, 0, 0);
            acc = __builtin_amdgcn_mfma_f32_16x16x32_bf16(aH[kt], bL, acc, 0, 0, 0);
        }
        int col = nt * 16 + lm;
        if (col < ncols) {
            float bv = bias ? bias[col] : 0.f;
#pragma unroll
            for (int r = 0; r < 4; r++) {
                int row = r0 + m0 + quad * 4 + r;
                C[(size_t)row * ncols + col] = acc[r] + bv;
            }
        }
    }
}

// ---------------- MFMA GEMM: [N,128](fp32) @ WbT(bf16 [n][k]) -> bf16 out ----------------
// 64 rows/block, full N=128. A converted fp32->bf16 into LDS (+8 pad = 2-way bank, free).
// Optional fused el/er epilogue (replaces k_elr pass — r9, validated).
// Optional fused BN prologue (r10, neutral-kept): h = mask(bnh + elu(scale*x+shift)).
__global__ __launch_bounds__(256) void k_gemm_mfma(const float* __restrict__ A,
                                                   const short* __restrict__ WbT,
                                                   const float* __restrict__ bias,
                                                   short* __restrict__ C,
                                                   const short* __restrict__ WelT,
                                                   float* __restrict__ el,
                                                   float* __restrict__ er,
                                                   int H,
                                                   const float* __restrict__ bnx,
                                                   const float* __restrict__ bnh,
                                                   const float* __restrict__ csum,
                                                   const float* __restrict__ csq,
                                                   const float* __restrict__ bng,
                                                   const float* __restrict__ bnb,
                                                   float* __restrict__ hout,
                                                   int do_mask) {
    __shared__ short sA[64 * 136];
    __shared__ short sB[128 * 136];
    __shared__ float sScale[128];
    __shared__ float sShift[128];
    int t = threadIdx.x;
    int r0 = blockIdx.x * 64;
    if (bnx) {
        if (t < 128) {
            const float invN = 1.f / (float)N_;
            float mu = csum[t] * invN;
            float var = csq[t] * invN - mu * mu;
            float inv = rsqrtf(var + 1e-5f);
            float sc = bng[t] * inv;
            sScale[t] = sc;
            sShift[t] = bnb[t] - mu * sc;
        }
        __syncthreads();
    }
    // stage B: each thread copies 64 bf16
    {
        int n = t >> 1;
        int k0 = (t & 1) * 64;
#pragma unroll
        for (int j = 0; j < 8; j++) {
            bf16x8 v = *(const bf16x8*)(WbT + n * 128 + k0 + 8 * j);
            *(bf16x8*)(sB + n * 136 + k0 + 8 * j) = v;
        }
    }
    // stage A: each thread handles 32 elements of one row-quarter
    {
        int r = t >> 2;
        int k0 = (t & 3) * 32;
        if (bnx) {
            const float* xr = bnx + (size_t)(r0 + r) * 128 + k0;
            const float* hr = bnh + (size_t)(r0 + r) * 128 + k0;
            float* ho = hout + (size_t)(r0 + r) * 128 + k0;
#pragma unroll
            for (int j = 0; j < 4; j++) {
                float4 x0 = *(const float4*)(xr + 8 * j);
                float4 x1 = *(const float4*)(xr + 8 * j + 4);
                float4 h0 = *(const float4*)(hr + 8 * j);
                float4 h1 = *(const float4*)(hr + 8 * j + 4);
                float xs[8] = {x0.x, x0.y, x0.z, x0.w, x1.x, x1.y, x1.z, x1.w};
                float hs[8] = {h0.x, h0.y, h0.z, h0.w, h1.x, h1.y, h1.z, h1.w};
                float ov[8];
                bf16x8 v;
#pragma unroll
                for (int q = 0; q < 8; q++) {
                    int c = k0 + 8 * j + q;
                    float y = sScale[c] * xs[q] + sShift[c];
                    y = y > 0.f ? y : (__expf(y) - 1.f);
                    float hv = hs[q] + y;
                    if (do_mask && isinf(hv)) hv = 1e9f;
                    ov[q] = hv;
                    v[q] = f2bf(hv);
                }
                *(float4*)(ho + 8 * j) = make_float4(ov[0], ov[1], ov[2], ov[3]);
                *(float4*)(ho + 8 * j + 4) = make_float4(ov[4], ov[5], ov[6], ov[7]);
                *(bf16x8*)(sA + r * 136 + k0 + 8 * j) = v;
            }
        } else {
            const float* ar = A + (size_t)(r0 + r) * 128 + k0;
#pragma unroll
            for (int j = 0; j < 4; j++) {
                float4 f0 = *(const float4*)(ar + 8 * j);
                float4 f1 = *(const float4*)(ar + 8 * j + 4);
                bf16x8 v;
                v[0] = f2bf(f0.x); v[1] = f2bf(f0.y); v[2] = f2bf(f0.z); v[3] = f2bf(f0.w);
                v[4] = f2bf(f1.x); v[5] = f2bf(f1.y); v[6] = f2bf(f1.z); v[7] = f2bf(f1.w);
                *(bf16x8*)(sA + r * 136 + k0 + 8 * j) = v;
            }
        }
    }
    __syncthreads();
    int lane = t & 63, wv = t >> 6;
    int lm = lane & 15, quad = lane >> 4;
    int m0 = wv * 16;
    bf16x8 aF[4];
#pragma unroll
    for (int kt = 0; kt < 4; kt++)
        aF[kt] = *(const bf16x8*)(sA + (m0 + lm) * 136 + kt * 32 + quad * 8);
#pragma unroll
    for (int nt = 0; nt < 8; nt++) {
        floatx4 acc = (floatx4){0.f, 0.f, 0.f, 0.f};
#pragma unroll
        for (int kt = 0; kt < 4; kt++) {
            bf16x8 bF = *(const bf16x8*)(sB + (nt * 16 + lm) * 136 + kt * 32 + quad * 8);
            acc = __builtin_amdgcn_mfma_f32_16x16x32_bf16(aF[kt], bF, acc, 0, 0, 0);
        }
        int col = nt * 16 + lm;
        float bv = bias ? bias[col] : 0.f;
#pragma unroll
        for (int r = 0; r < 4; r++) {
            int row = r0 + m0 + quad * 4 + r;
            C[(size_t)row * 128 + col] = f2bf(acc[r] + bv);
        }
    }
    // fused el/er tile: cols 0..7 = el heads, 8..15 = er heads (H=1: col0=el, col1=er)
    if (WelT) {
        floatx4 acc = (floatx4){0.f, 0.f, 0.f, 0.f};
#pragma unroll
        for (int kt = 0; kt < 4; kt++) {
            bf16x8 wF = *(const bf16x8*)(WelT + lm * 128 + kt * 32 + quad * 8);
            acc = __builtin_amdgcn_mfma_f32_16x16x32_bf16(aF[kt], wF, acc, 0, 0, 0);
        }
        if (H == 8) {
#pragma unroll
            for (int r = 0; r < 4; r++) {
                int row = r0 + m0 + quad * 4 + r;
                if (lm < 8) el[(size_t)row * 8 + lm] = acc[r];
                else        er[(size_t)row * 8 + (lm - 8)] = acc[r];
            }
        } else {
#pragma unroll
            for (int r = 0; r < 4; r++) {
                int row = r0 + m0 + quad * 4 + r;
                if (lm == 0) el[row] = acc[r];
                if (lm == 1) er[row] = acc[r];
            }
        }
    }
}

// ---------------- softmax over 100 logits, wave per node, barrier-free ----------------
__global__ __launch_bounds__(256) void k_smax100(const float* __restrict__ logits,
                                                 float* __restrict__ s) {
    int lane = threadIdx.x & 63;
    int n = blockIdx.x * 4 + (threadIdx.x >> 6);
    if (n >= N_) return;
    bool act = lane < 50;
    float2 v = make_float2(-INFINITY, -INFINITY);
    if (act) v = *(const float2*)(logits + (size_t)n * 100 + 2 * lane);
    float mx = fmaxf(v.x, v.y);
#pragma unroll
    for (int off = 1; off < 64; off <<= 1) mx = fmaxf(mx, __shfl_xor(mx, off));
    float e0 = act ? __expf(v.x - mx) : 0.f;
    float e1 = act ? __expf(v.y - mx) : 0.f;
    float sm = e0 + e1;
#pragma unroll
    for (int off = 1; off < 64; off <<= 1) sm += __shfl_xor(sm, off);
    float inv = 1.f / sm;
    if (act) *(float2*)(s + (size_t)n * 100 + 2 * lane) = make_float2(e0 * inv, e1 * inv);
}

// ---------------- GAT edge-softmax + aggregate (wave per dst node, bf16 feat) ----------------
// v6: pass 1 / pass 2 byte-identical to proven v4. NEW: BN column stats accumulated
// per-thread over owned cols (f0,f0+1), block LDS-reduced, written as PLAIN COALESCED
// per-block partials to psum/psq[block][128] — no atomics (r7's fused-stats failure
// was the 2048-way atomic burst; this isolates that variable). k_stats_reduce (4MB)
// replaces k_bn_stats (20MB re-read).
template <int H>
__global__ __launch_bounds__(256) void k_gat_agg(const short* __restrict__ feat,
                                                 const float* __restrict__ el,
                                                 const float* __restrict__ er,
                                                 const int* __restrict__ rowptr,
                                                 const int* __restrict__ srcv,
                                                 const float* __restrict__ bias,
                                                 float* __restrict__ xout,
                                                 float* __restrict__ psum,
                                                 float* __restrict__ psq) {
    int t = threadIdx.x;
    int lane = t & 63;
    int gw = (blockIdx.x * blockDim.x + t) >> 6;
    int nw = (gridDim.x * blockDim.x) >> 6;
    constexpr int LH = (H == 8) ? 3 : 0;
    int h = lane & (H - 1);
    int f0 = 2 * lane;
    int hf = (H == 8) ? (lane >> 3) : 0;   // head owning this lane's feature slice

    float stx = 0.f, sty = 0.f, qtx = 0.f, qty = 0.f;  // fused BN stats

    for (int n = gw; n < N_; n += nw) {
        int beg = rowptr[n], end = rowptr[n + 1];
        if (beg == end) {
            float2 b2 = *(const float2*)(bias + f0);
            *(float2*)(xout + (size_t)n * 128 + f0) = b2;
            stx += b2.x; sty += b2.y;
            qtx += b2.x * b2.x; qty += b2.y * b2.y;
            continue;
        }
        float ern = er[(size_t)n * H + h];
        // ---- pass 1: online softmax stats ----
        float m = -INFINITY, ss = 0.f;
        for (int e = beg + (lane >> LH); e < end; e += (64 >> LH)) {
            int sI = srcv[e];
            float x = el[(size_t)sI * H + h] + ern;
            float lr = x > 0.f ? x : 0.2f * x;
            if (lr > m) { ss = ss * __expf(m - lr) + 1.f; m = lr; }
            else ss += __expf(lr - m);
        }
#pragma unroll
        for (int off = H; off < 64; off <<= 1) {
            float om = __shfl_xor(m, off);
            float os = __shfl_xor(ss, off);
            float nm = fmaxf(m, om);
            float p1 = (m == -INFINITY) ? 0.f : ss * __expf(m - nm);
            float p2 = (om == -INFINITY) ? 0.f : os * __expf(om - nm);
            m = nm; ss = p1 + p2;
        }
        // after butterfly each lane holds (m, ss) for its own head h = lane&(H-1)
        float inv_d = 1.f / ss;
        // ---- pass 2: 2x interleaved chunked aggregation ----
        int endm1 = end - 1;
        float accx = 0.f, accy = 0.f;
        for (int e0 = beg; e0 < end; e0 += 16) {
            int le = lane >> 3;
            int eLA = e0 + le, eLB = e0 + 8 + le;
            int eCA = eLA <= endm1 ? eLA : endm1;
            int eCB = eLB <= endm1 ? eLB : endm1;
            int sLA = srcv[eCA];
            int sLB = srcv[eCB];
            float xA = el[(size_t)sLA * H + h] + ern;
            float xB = el[(size_t)sLB * H + h] + ern;
            float lrA = xA > 0.f ? xA : 0.2f * xA;
            float lrB = xB > 0.f ? xB : 0.2f * xB;
            float wA = __expf(lrA - m) * inv_d;
            float wB = __expf(lrB - m) * inv_d;
            if (eLA > endm1) wA = 0.f;
            if (eLB > endm1) wB = 0.f;
            bool haveB = (e0 + 8) < end;    // wave-uniform
            unsigned int uuA[8], uuB[8];
#pragma unroll
            for (int j = 0; j < 8; j++) {
                int sj = __builtin_amdgcn_readlane(sLA, j * 8);
                uuA[j] = *(const unsigned int*)(feat + (size_t)sj * 128 + f0);
            }
            if (haveB) {
#pragma unroll
                for (int j = 0; j < 8; j++) {
                    int sj = __builtin_amdgcn_readlane(sLB, j * 8);
                    uuB[j] = *(const unsigned int*)(feat + (size_t)sj * 128 + f0);
                }
            }
#pragma unroll
            for (int j = 0; j < 8; j++) {
                float aj;
                if (H == 8) aj = __shfl(wA, j * 8 + hf);
                else        aj = rdlane(wA, j * 8);
                accx += aj * bflo(uuA[j]);
                accy += aj * bfhi(uuA[j]);
            }
            if (haveB) {
#pragma unroll
                for (int j = 0; j < 8; j++) {
                    float aj;
                    if (H == 8) aj = __shfl(wB, j * 8 + hf);
                    else        aj = rdlane(wB, j * 8);
                    accx += aj * bflo(uuB[j]);
                    accy += aj * bfhi(uuB[j]);
                }
            }
        }
        float2 b2 = *(const float2*)(bias + f0);
        float ox = accx + b2.x, oy = accy + b2.y;
        *(float2*)(xout + (size_t)n * 128 + f0) = make_float2(ox, oy);
        stx += ox; sty += oy;
        qtx += ox * ox; qty += oy * oy;
    }

    // ---- per-block partial stats: LDS reduce across 4 waves, coalesced plain store ----
    __shared__ float red[4][256];
    red[0][t] = stx; red[1][t] = sty; red[2][t] = qtx; red[3][t] = qty;
    __syncthreads();
    if (t < 64) {
        float a0 = red[0][t] + red[0][t + 64] + red[0][t + 128] + red[0][t + 192];
        float a1 = red[1][t] + red[1][t + 64] + red[1][t + 128] + red[1][t + 192];
        float q0 = red[2][t] + red[2][t + 64] + red[2][t + 128] + red[2][t + 192];
        float q1 = red[3][t] + red[3][t + 64] + red[3][t + 128] + red[3][t + 192];
        *(float2*)(psum + (size_t)blockIdx.x * 128 + 2 * t) = make_float2(a0, a1);
        *(float2*)(psq + (size_t)blockIdx.x * 128 + 2 * t) = make_float2(q0, q1);
    }
}

// ---------------- reduce per-block stats partials -> colsum/colsq ----------------
__global__ __launch_bounds__(256) void k_stats_reduce(const float* __restrict__ psum,
                                                      const float* __restrict__ psq,
                                                      float* __restrict__ colsum,
                                                      float* __restrict__ colsq) {
    __shared__ float ls[256], lq[256];
    int t = threadIdx.x;
    int col = t & 127, half = t >> 7;
    float s = 0.f, q = 0.f;
    for (int b = blockIdx.x * 2 + half; b < AGGB_; b += gridDim.x * 2) {
        s += psum[(size_t)b * 128 + col];
        q += psq[(size_t)b * 128 + col];
    }
    ls[t] = s; lq[t] = q;
    __syncthreads();
    if (t < 128) {
        atomicAdd(&colsum[col], ls[t] + ls[t + 128]);
        atomicAdd(&colsq[col], lq[t] + lq[t + 128]);
    }
}

// ---------------- BN apply + ELU + residual (+mask) — layer-1 only ----------------
__global__ __launch_bounds__(256) void k_bn_apply(const float* __restrict__ x,
                                                  const float* __restrict__ hprev,
                                                  const float* __restrict__ sum,
                                                  const float* __restrict__ sumsq,
                                                  const float* __restrict__ g,
                                                  const float* __restrict__ b,
                                                  float* __restrict__ out, int do_mask) {
    int i = blockIdx.x * blockDim.x + threadIdx.x;
    if (i >= N_ * 128) return;
    int c = i & 127;
    const float invN = 1.f / (float)N_;
    float mu = sum[c] * invN;
    float var = sumsq[c] * invN - mu * mu;
    float inv = rsqrtf(var + 1e-5f);
    float y = g[c] * (x[i] - mu) * inv + b[c];
    y = y > 0.f ? y : (__expf(y) - 1.f);
    float hv = hprev[i] + y;
    if (do_mask && isinf(hv)) hv = 1e9f;
    out[i] = hv;
}

// ---------------- h_coarse partials ----------------
__global__ __launch_bounds__(512) void k_coarse_part(const float* __restrict__ s,
                                                     const float* __restrict__ hf,
                                                     float* __restrict__ part) {
    int t = threadIdx.x;
    int c = t & 127;
    int g = t >> 7;        // 0..3
    int lane = t & 63;
    float acc[25];
#pragma unroll
    for (int a = 0; a < 25; a++) acc[a] = 0.f;
    int n0 = blockIdx.x * CR_;
    for (int n = n0; n < n0 + CR_; n += 2) {
        float hv0 = hf[(size_t)n * 128 + c];
        float hv1 = hf[(size_t)(n + 1) * 128 + c];
        float sv0 = 0.f, sv1 = 0.f;
        if (lane < 25) {
            sv0 = s[(size_t)n * 100 + 25 * g + lane];
            sv1 = s[(size_t)(n + 1) * 100 + 25 * g + lane];
        }
#pragma unroll
        for (int a = 0; a < 25; ++a) {
            float a0 = rdlane(sv0, a);
            float a1 = rdlane(sv1, a);
            acc[a] += a0 * hv0 + a1 * hv1;
        }
    }
    float* dstp = part + (size_t)blockIdx.x * 12800 + (size_t)(25 * g) * 128 + c;
#pragma unroll
    for (int a = 0; a < 25; a++) dstp[a * 128] = acc[a];
}

// ---------------- reduce partials -> hc[100][128] ----------------
__global__ __launch_bounds__(256) void k_coarse_reduce(const float* __restrict__ part,
                                                       float* __restrict__ hc) {
    int i = blockIdx.x * blockDim.x + threadIdx.x;  // 12800 total
    if (i >= 12800) return;
    float s0 = 0.f, s1 = 0.f, s2 = 0.f, s3 = 0.f;
    for (int b = 0; b < CB_; b += 4) {
        s0 += part[(size_t)(b + 0) * 12800 + i];
        s1 += part[(size_t)(b + 1) * 12800 + i];
        s2 += part[(size_t)(b + 2) * 12800 + i];
        s3 += part[(size_t)(b + 3) * 12800 + i];
    }
    hc[i] = (s0 + s1) + (s2 + s3);
}

// ---------------- h = mask(0.5*h_fine + 0.5*(s@h_coarse)) ----------------
__global__ __launch_bounds__(256) void k_combine(const float* __restrict__ s,
                                                 const float* __restrict__ hc,
                                                 const float* __restrict__ hfine,
                                                 float* __restrict__ hout) {
    __shared__ float ssh[16 * 100];
    int t = threadIdx.x;
    int n0 = blockIdx.x * 16;
    for (int u = t; u < 1600; u += 256) ssh[u] = s[(size_t)n0 * 100 + u];
    __syncthreads();
    int c = t & 127, g = t >> 7;
    float acc[8];
#pragma unroll
    for (int r = 0; r < 8; r++) acc[r] = 0.f;
    const float* hcp = hc + c;
    for (int a = 0; a < 100; a += 4) {
        float h0 = hcp[(a + 0) * 128];
        float h1 = hcp[(a + 1) * 128];
        float h2 = hcp[(a + 2) * 128];
        float h3 = hcp[(a + 3) * 128];
#pragma unroll
        for (int r = 0; r < 8; r++) {
            float4 sv = *(const float4*)(ssh + (g * 8 + r) * 100 + a);
            acc[r] += sv.x * h0 + sv.y * h1 + sv.z * h2 + sv.w * h3;
        }
    }
#pragma unroll
    for (int r = 0; r < 8; r++) {
        int row = n0 + g * 8 + r;
        float v = 0.5f * hfine[(size_t)row * 128 + c] + 0.5f * acc[r];
        if (isinf(v)) v = 1e9f;
        hout[(size_t)row * 128 + c] = v;
    }
}

// ---------------- prep: Wm2 [128][64] fp32 -> Wm2T bf16 [64][128] ----------------
__global__ __launch_bounds__(256) void k_prep_w(const float* __restrict__ Wm2,
                                                short* __restrict__ Wm2T) {
    int i = blockIdx.x * blockDim.x + threadIdx.x;  // 8192 total
    if (i >= 64 * 128) return;
    int n = i & 63, k = i >> 6;
    Wm2T[n * 128 + k] = f2bf(Wm2[k * 64 + n]);
}

// ---------------- edge MLP readout: dst-sorted order, barrier-free persistent MFMA ----------------
// v2 — LOCAL OPTIMUM at ~54us, VGPR 84. Do not register-diet (v3: spills, 3x dur).
// Do not 2-tile (v4: compiler serializes the B-tile loads, occupancy drops, +6us).
__global__ __launch_bounds__(256) void k_edge_mlp3(const short* __restrict__ Pb,
                                                   const short* __restrict__ Qb,
                                                   const int* __restrict__ srcv,
                                                   const unsigned short* __restrict__ dstv,
                                                   const int* __restrict__ eidv,
                                                   const short* __restrict__ Wm2T,
                                                   const float* __restrict__ bm2,
                                                   const float* __restrict__ Wm3,
                                                   const float* __restrict__ bm3,
                                                   float* __restrict__ zout) {
    __shared__ short sW[64 * 128];  // 16 KiB
    int t = threadIdx.x;
    // stage Wm2T -> LDS with 16B-unit XOR swizzle: phys_unit = n*16 + (k16 ^ (n&15))
    for (int u = t; u < 1024; u += 256) {
        int n = u >> 4, k16 = u & 15;
        int phys = (n << 4) | (k16 ^ (n & 15));
        *(bf16x8*)(sW + phys * 8) = *(const bf16x8*)(Wm2T + n * 128 + k16 * 8);
    }
    int lane = t & 63;
    int lm = lane & 15, quad = lane >> 4;
    float bv[4], w30[4], w31[4];
#pragma unroll
    for (int nt = 0; nt < 4; nt++) {
        int n = nt * 16 + lm;
        bv[nt] = bm2[n]; w30[nt] = Wm3[2 * n]; w31[nt] = Wm3[2 * n + 1];
    }
    float b30 = bm3[0], b31 = bm3[1];
    __syncthreads();

    int gw = (blockIdx.x * blockDim.x + t) >> 6;
    int nw = (gridDim.x * blockDim.x) >> 6;

    for (int tile = gw; tile < E_ / 16; tile += nw) {
        int p0 = tile * 16;
        int sI = srcv[p0 + lm];
        int dI = (int)dstv[p0 + lm];
        const short* pr = Pb + (size_t)sI * 128 + quad * 8;
        const short* qr = Qb + (size_t)dI * 128 + quad * 8;
        // issue all 8 gathers up-front (latency hidden within wave)
        uint4 pu[4], qu[4];
#pragma unroll
        for (int kt = 0; kt < 4; kt++) {
            pu[kt] = *(const uint4*)(pr + kt * 32);
            qu[kt] = *(const uint4*)(qr + kt * 32);
        }
        bf16x8 aF[4];
#pragma unroll
        for (int kt = 0; kt < 4; kt++) {
            unsigned int pv[4] = {pu[kt].x, pu[kt].y, pu[kt].z, pu[kt].w};
            unsigned int qv[4] = {qu[kt].x, qu[kt].y, qu[kt].z, qu[kt].w};
            union { uint4 u; bf16x8 v; } cv;
            unsigned int rr[4];
#pragma unroll
            for (int j = 0; j < 4; j++) {
                float fl = fmaxf(bflo(pv[j]) + bflo(qv[j]), 0.f);
                float fh = fmaxf(bfhi(pv[j]) + bfhi(qv[j]), 0.f);
                rr[j] = (unsigned int)(unsigned short)f2bf(fl) |
                        ((unsigned int)(unsigned short)f2bf(fh) << 16);
            }
            cv.u.x = rr[0]; cv.u.y = rr[1]; cv.u.z = rr[2]; cv.u.w = rr[3];
            aF[kt] = cv.v;
        }
        float pz0[4] = {0.f, 0.f, 0.f, 0.f};
        float pz1[4] = {0.f, 0.f, 0.f, 0.f};
#pragma unroll
        for (int nt = 0; nt < 4; nt++) {
            floatx4 acc = (floatx4){0.f, 0.f, 0.f, 0.f};
#pragma unroll
            for (int kt = 0; kt < 4; kt++) {
                int phys = ((nt * 16 + lm) << 4) | (((kt << 2) | quad) ^ lm);
                bf16x8 bF = *(const bf16x8*)(sW + phys * 8);
                acc = __builtin_amdgcn_mfma_f32_16x16x32_bf16(aF[kt], bF, acc, 0, 0, 0);
            }
#pragma unroll
            for (int r = 0; r < 4; r++) {
                float u = fmaxf(acc[r] + bv[nt], 0.f);
                pz0[r] += u * w30[nt];
                pz1[r] += u * w31[nt];
            }
        }
#pragma unroll
        for (int off = 1; off < 16; off <<= 1) {
#pragma unroll
            for (int r = 0; r < 4; r++) {
                pz0[r] += __shfl_xor(pz0[r], off);
                pz1[r] += __shfl_xor(pz1[r], off);
            }
        }
        if (lm < 4) {
            int eid = eidv[p0 + quad * 4 + lm];
            float z0 = pz0[lm] + b30;
            float z1 = pz1[lm] + b31;
            if (isinf(z0)) z0 = 1e9f;
            if (isinf(z1)) z1 = 1e9f;
            *(float2*)(zout + (size_t)eid * 2) = make_float2(z0, z1);
        }
    }
}

extern "C" void kernel_launch(void* const* d_in, const int* in_sizes, int n_in,
                              void* d_out, int out_size, void* d_ws, size_t ws_size,
                              hipStream_t stream) {
    const float* h_in  = (const float*)d_in[0];
    const int*   src   = (const int*)d_in[2];
    const int*   dst   = (const int*)d_in[3];
    const float* W_emb = (const float*)d_in[4];
    const float* b_emb = (const float*)d_in[5];
    const float* Wg    = (const float*)d_in[6];
    const float* alg   = (const float*)d_in[7];
    const float* arg_  = (const float*)d_in[8];
    const float* bg    = (const float*)d_in[9];
    const float* gam   = (const float*)d_in[10];
    const float* bet   = (const float*)d_in[11];
    const float* W3    = (const float*)d_in[12];
    const float* al3   = (const float*)d_in[13];
    const float* ar3   = (const float*)d_in[14];
    const float* b3    = (const float*)d_in[15];
    const float* gam3  = (const float*)d_in[16];
    const float* bet3  = (const float*)d_in[17];
    const float* Wa    = (const float*)d_in[18];
    const float* ba    = (const float*)d_in[19];
    const float* Wm1   = (const float*)d_in[20];
    const float* bm1   = (const float*)d_in[21];
    const float* Wm2   = (const float*)d_in[22];
    const float* bm2   = (const float*)d_in[23];
    const float* Wm3   = (const float*)d_in[24];
    const float* bm3   = (const float*)d_in[25];

    float* zout = (float*)d_out;
    float* sout = zout + (size_t)E_ * 2;

    float* ws = (float*)d_ws;
    size_t o = 0;
    float* h_cur = ws + o; o += (size_t)N_ * 128;
    float* xbuf  = ws + o; o += (size_t)N_ * 128;
    float* featb = ws + o; o += (size_t)N_ * 128;   // reused: bf16 feat, coarse partials, bf16 P/Q
    float* el    = ws + o; o += (size_t)N_ * 8;
    float* er    = ws + o; o += (size_t)N_ * 8;
    float* colsum = ws + o; o += 128;
    float* colsq  = ws + o; o += 128;
    float* hc     = ws + o; o += 100 * 128;
    float* psum   = ws + o; o += (size_t)AGGB_ * 128;
    float* psq    = ws + o; o += (size_t)AGGB_ * 128;
    short* Wm2T = (short*)(ws + o); o += (64 * 128) / 2;
    short* WbT6 = (short*)(ws + o); o += (6 * 16384) / 2;
    short* WelT = (short*)(ws + o); o += (4 * 2048) / 2;
    short* WembT_hi = (short*)(ws + o); o += 16384 / 2;
    short* WembT_lo = (short*)(ws + o); o += 16384 / 2;
    short* WaT_hi   = (short*)(ws + o); o += 16384 / 2;
    short* WaT_lo   = (short*)(ws + o); o += 16384 / 2;
    int* counts = (int*)(ws + o); o += N_;
    int* rowptr = (int*)(ws + o); o += N_ + 4;
    int* cursor = (int*)(ws + o); o += N_;
    int* srcv   = (int*)(ws + o); o += E_;
    unsigned short* dstv = (unsigned short*)(ws + o); o += E_ / 2;
    int* eidv   = (int*)(ws + o); o += E_;
    int* bsum   = (int*)(ws + o); o += SNB_ + 4;

    short* featw = (short*)featb;  // bf16 per-layer projection

    // ---- CSR build (parallel scan; excl scratch reuses eidv pre-fill) ----
    hipMemsetAsync(counts, 0, N_ * sizeof(int), stream);
    k_count<<<1024, 256, 0, stream>>>(dst, counts);
    k_scanA<<<SNB_, 256, 0, stream>>>(counts, eidv, bsum);
    k_scanB<<<1, 256, 0, stream>>>(bsum);
    k_scanC<<<SNB_ + 1, 256, 0, stream>>>(eidv, bsum, rowptr, cursor);
    k_fill<<<1024, 256, 0, stream>>>(src, dst, cursor, srcv, dstv, eidv);
    k_prep_w<<<32, 256, 0, stream>>>(Wm2, Wm2T);
    k_prep_all<<<384, 256, 0, stream>>>(Wg, W3, Wm1, WbT6);
    k_prep_wela<<<32, 256, 0, stream>>>(Wg, alg, arg_, W3, al3, ar3, WelT);
    k_prep_hilo<<<128, 256, 0, stream>>>(W_emb, Wa, WembT_hi, WembT_lo, WaT_hi, WaT_lo);

    // ---- embedding (fp32-accurate via hi/lo MFMA) ----
    k_mfma_hilo<<<N_ / 64, 256, 0, stream>>>(h_in, WembT_hi, WembT_lo, b_emb, h_cur, 128);

    // ---- layer 0 (H=8) ----
    k_gemm_mfma<<<N_ / 64, 256, 0, stream>>>(h_cur, WbT6 + 0 * 16384, nullptr, featw,
                                             WelT + 0 * 2048, el, er, 8,
                                             nullptr, nullptr, nullptr, nullptr,
                                             nullptr, nullptr, nullptr, 0);
    hipMemsetAsync(colsum, 0, 256 * sizeof(float), stream);
    k_gat_agg<8><<<AGGB_, 256, 0, stream>>>(featw, el, er, rowptr, srcv, bg + 0 * 128, xbuf,
                                            psum, psq);
    k_stats_reduce<<<64, 256, 0, stream>>>(psum, psq, colsum, colsq);

    // ---- layer 1 (biGAT, H=8): gemm fused with layer-0 BN (writes h_cur) ----
    k_gemm_mfma<<<N_ / 64, 256, 0, stream>>>(nullptr, WbT6 + 1 * 16384, nullptr, featw,
                                             WelT + 1 * 2048, el, er, 8,
                                             xbuf, h_cur, colsum, colsq,
                                             gam + 0 * 128, bet + 0 * 128, h_cur, 1);
    k_mfma_hilo<<<N_ / 64, 256, 0, stream>>>(h_cur, WaT_hi, WaT_lo, ba, xbuf, 100);
    k_smax100<<<N_ / 4, 256, 0, stream>>>(xbuf, sout);
    hipMemsetAsync(colsum, 0, 256 * sizeof(float), stream);
    k_gat_agg<8><<<AGGB_, 256, 0, stream>>>(featw, el, er, rowptr, srcv, bg + 1 * 128, xbuf,
                                            psum, psq);
    k_stats_reduce<<<64, 256, 0, stream>>>(psum, psq, colsum, colsq);
    k_bn_apply<<<(N_ * 128) / 256, 256, 0, stream>>>(xbuf, h_cur, colsum, colsq,
                                                     gam + 1 * 128, bet + 1 * 128, xbuf, 0);
    k_coarse_part<<<CB_, 512, 0, stream>>>(sout, xbuf, featb);
    k_coarse_reduce<<<50, 256, 0, stream>>>(featb, hc);
    k_combine<<<N_ / 16, 256, 0, stream>>>(sout, hc, xbuf, h_cur);

    // ---- layer 2 (H=8) ----
    k_gemm_mfma<<<N_ / 64, 256, 0, stream>>>(h_cur, WbT6 + 2 * 16384, nullptr, featw,
                                             WelT + 2 * 2048, el, er, 8,
                                             nullptr, nullptr, nullptr, nullptr,
                                             nullptr, nullptr, nullptr, 0);
    hipMemsetAsync(colsum, 0, 256 * sizeof(float), stream);
    k_gat_agg<8><<<AGGB_, 256, 0, stream>>>(featw, el, er, rowptr, srcv, bg + 2 * 128, xbuf,
                                            psum, psq);
    k_stats_reduce<<<64, 256, 0, stream>>>(psum, psq, colsum, colsq);

    // ---- layer 3 (H=1): gemm fused with layer-2 BN (writes h_cur) ----
    k_gemm_mfma<<<N_ / 64, 256, 0, stream>>>(nullptr, WbT6 + 3 * 16384, nullptr, featw,
                                             WelT + 3 * 2048, el, er, 1,
                                             xbuf, h_cur, colsum, colsq,
                                             gam + 2 * 128, bet + 2 * 128, h_cur, 1);
    hipMemsetAsync(colsum, 0, 256 * sizeof(float), stream);
    k_gat_agg<1><<<AGGB_, 256, 0, stream>>>(featw, el, er, rowptr, srcv, b3, xbuf,
                                            psum, psq);
    k_stats_reduce<<<64, 256, 0, stream>>>(psum, psq, colsum, colsq);

    // ---- edge MLP readout: Pb gemm fused with layer-3 BN (writes h_cur) ----
    short* Pb = (short*)featb;
    short* Qb = Pb + (size_t)N_ * 128;
    k_gemm_mfma<<<N_ / 64, 256, 0, stream>>>(nullptr, WbT6 + 4 * 16384, bm1, Pb,
                                             nullptr, nullptr, nullptr, 0,
                                             xbuf, h_cur, colsum, colsq,
                                             gam3, bet3, h_cur, 1);
    k_gemm_mfma<<<N_ / 64, 256, 0, stream>>>(h_cur, WbT6 + 5 * 16384, nullptr, Qb,
                                             nullptr, nullptr, nullptr, 0,
                                             nullptr, nullptr, nullptr, nullptr,
                                             nullptr, nullptr, nullptr, 0);
    k_edge_mlp3<<<2048, 256, 0, stream>>>(Pb, Qb, srcv, dstv, eidv, Wm2T, bm2, Wm3, bm3, zout);
}

// Round 13
// 751.031 us; speedup vs baseline: 1.0864x; 1.0049x over previous
//
#include <hip/hip_runtime.h>
#include <hip/hip_bf16.h>
#include <math.h>

#define N_ 40000
#define E_ 640000
#define CB_ 400   // k_coarse partial blocks
#define CR_ 100   // rows per block (CB_*CR_ == N_)
#define SB_ 256
#define SNB_ 157  // ceil(N_/SB_)
#define AGGB_ 2048  // k_gat_agg grid (blocks); psum/psq sized to this

typedef short bf16x8 __attribute__((ext_vector_type(8)));
typedef float floatx4 __attribute__((ext_vector_type(4)));

__device__ __forceinline__ short f2bf(float f) {
    __hip_bfloat16 h = __float2bfloat16(f);
    return *reinterpret_cast<short*>(&h);
}
__device__ __forceinline__ float bf2f(short u) {
    unsigned int x = ((unsigned int)(unsigned short)u) << 16;
    return __int_as_float(x);
}
__device__ __forceinline__ float rdlane(float v, int l) {
    return __int_as_float(__builtin_amdgcn_readlane(__float_as_int(v), l));
}
// unpack 2 bf16 packed in a uint
__device__ __forceinline__ float bflo(unsigned int u) { return __int_as_float(u << 16); }
__device__ __forceinline__ float bfhi(unsigned int u) { return __int_as_float(u & 0xffff0000u); }

// ---------------- CSR build ----------------
__global__ void k_count(const int* __restrict__ dst, int* __restrict__ counts) {
    for (int e = blockIdx.x * blockDim.x + threadIdx.x; e < E_; e += gridDim.x * blockDim.x)
        atomicAdd(&counts[dst[e]], 1);
}

// ---- 3-phase parallel scan ----
__global__ __launch_bounds__(256) void k_scanA(const int* __restrict__ counts,
                                               int* __restrict__ excl,
                                               int* __restrict__ bsum) {
    int t = threadIdx.x;
    int i = blockIdx.x * SB_ + t;
    int v = (i < N_) ? counts[i] : 0;
    int lane = t & 63, wv = t >> 6;
    int x = v;
#pragma unroll
    for (int off = 1; off < 64; off <<= 1) {
        int y = __shfl_up(x, off);
        if (lane >= off) x += y;
    }
    __shared__ int wsum[4];
    __shared__ int woff[4];
    if (lane == 63) wsum[wv] = x;
    __syncthreads();
    if (t == 0) {
        int a = 0;
#pragma unroll
        for (int j = 0; j < 4; j++) { int tv = wsum[j]; woff[j] = a; a += tv; }
        bsum[blockIdx.x] = a;
    }
    __syncthreads();
    if (i < N_) excl[i] = x - v + woff[wv];
}

__global__ __launch_bounds__(256) void k_scanB(int* __restrict__ bsum) {
    int t = threadIdx.x;
    int v = (t < SNB_) ? bsum[t] : 0;
    int lane = t & 63, wv = t >> 6;
    int x = v;
#pragma unroll
    for (int off = 1; off < 64; off <<= 1) {
        int y = __shfl_up(x, off);
        if (lane >= off) x += y;
    }
    __shared__ int wsum[4];
    __shared__ int woff[4];
    if (lane == 63) wsum[wv] = x;
    __syncthreads();
    if (t == 0) {
        int a = 0;
#pragma unroll
        for (int j = 0; j < 4; j++) { int tv = wsum[j]; woff[j] = a; a += tv; }
    }
    __syncthreads();
    if (t < SNB_) bsum[t] = x - v + woff[wv];
}

__global__ __launch_bounds__(256) void k_scanC(const int* __restrict__ excl,
                                               const int* __restrict__ bsum,
                                               int* __restrict__ rowptr,
                                               int* __restrict__ cursor) {
    int i = blockIdx.x * 256 + threadIdx.x;
    if (i < N_) {
        int r = excl[i] + bsum[i / SB_];
        rowptr[i] = r;
        cursor[i] = r;
    }
    if (i == N_) rowptr[N_] = E_;
}

__global__ void k_fill(const int* __restrict__ src, const int* __restrict__ dst,
                       int* __restrict__ cursor, int* __restrict__ srcv,
                       unsigned short* __restrict__ dstv, int* __restrict__ eidv) {
    for (int e = blockIdx.x * blockDim.x + threadIdx.x; e < E_; e += gridDim.x * blockDim.x) {
        int d = dst[e];
        int pos = atomicAdd(&cursor[d], 1);
        srcv[pos] = src[e];
        dstv[pos] = (unsigned short)d;
        eidv[pos] = e;
    }
}

// ---------------- prep: 6x fp32 [k=128][n=128] -> bf16 [n][k] ----------------
__global__ __launch_bounds__(256) void k_prep_all(const float* __restrict__ Wg,
                                                  const float* __restrict__ W3,
                                                  const float* __restrict__ Wm1,
                                                  short* __restrict__ WbT6) {
    int i = blockIdx.x * 256 + threadIdx.x;   // 6*16384 total
    if (i >= 6 * 16384) return;
    int m = i >> 14;
    int r = i & 16383;
    int n = r >> 7, k = r & 127;
    const float* srcp;
    switch (m) {
        case 0: srcp = Wg; break;
        case 1: srcp = Wg + 16384; break;
        case 2: srcp = Wg + 32768; break;
        case 3: srcp = W3; break;
        case 4: srcp = Wm1; break;
        default: srcp = Wm1 + 16384; break;
    }
    WbT6[m * 16384 + n * 128 + k] = f2bf(srcp[k * 128 + n]);
}

// ---------------- prep: fused el/er weight tiles Wel[layer][16][128] ----------------
// el = (A@W)·al = A@(W@Aexp): Wel[n][k] = sum_d W[k][h*16+d]*a[h*16+d], h=n&7,
// a = al (n<8) or ar (n>=8). Layer 3 (H=1): n==0 -> W3·al3, n==1 -> W3·ar3, else 0.
__global__ __launch_bounds__(256) void k_prep_wela(const float* __restrict__ Wg,
                                                   const float* __restrict__ alg,
                                                   const float* __restrict__ arg_,
                                                   const float* __restrict__ W3,
                                                   const float* __restrict__ al3,
                                                   const float* __restrict__ ar3,
                                                   short* __restrict__ WelT) {
    int i = blockIdx.x * 256 + threadIdx.x;   // 4*16*128 = 8192 total
    if (i >= 4 * 2048) return;
    int layer = i >> 11;
    int r = i & 2047;
    int n = r >> 7, k = r & 127;
    float val = 0.f;
    if (layer < 3) {
        const float* W = Wg + layer * 16384;
        const float* a = (n < 8 ? alg : arg_) + layer * 128;
        int h = n & 7;
#pragma unroll
        for (int d = 0; d < 16; d++)
            val += W[k * 128 + h * 16 + d] * a[h * 16 + d];
    } else {
        if (n == 0) { for (int c = 0; c < 128; c++) val += W3[k * 128 + c] * al3[c]; }
        else if (n == 1) { for (int c = 0; c < 128; c++) val += W3[k * 128 + c] * ar3[c]; }
    }
    WelT[layer * 2048 + n * 128 + k] = f2bf(val);
}

// ---------------- prep: hi/lo bf16 splits of W_emb [128,128] and Wa [128,100] ----------------
// outputs transposed [n][k]; Wa zero-padded to n=128
__global__ __launch_bounds__(256) void k_prep_hilo(const float* __restrict__ W_emb,
                                                   const float* __restrict__ Wa,
                                                   short* __restrict__ WembT_hi,
                                                   short* __restrict__ WembT_lo,
                                                   short* __restrict__ WaT_hi,
                                                   short* __restrict__ WaT_lo) {
    int i = blockIdx.x * 256 + threadIdx.x;   // 2*16384 total
    if (i >= 2 * 16384) return;
    int m = i >> 14;
    int r = i & 16383;
    int n = r >> 7, k = r & 127;
    if (m == 0) {
        float w = W_emb[k * 128 + n];
        short h = f2bf(w);
        WembT_hi[n * 128 + k] = h;
        WembT_lo[n * 128 + k] = f2bf(w - bf2f(h));
    } else {
        float w = (n < 100) ? Wa[k * 100 + n] : 0.f;
        short h = f2bf(w);
        WaT_hi[n * 128 + k] = h;
        WaT_lo[n * 128 + k] = f2bf(w - bf2f(h));
    }
}

// ---------------- fp32-accurate MFMA GEMM via 3-term hi/lo split ----------------
__global__ __launch_bounds__(256) void k_mfma_hilo(const float* __restrict__ A,
                                                   const short* __restrict__ BT_hi,
                                                   const short* __restrict__ BT_lo,
                                                   const float* __restrict__ bias,
                                                   float* __restrict__ C, int ncols) {
    __shared__ short sAh[64 * 136];
    __shared__ short sAl[64 * 136];
    __shared__ short sBh[128 * 136];
    int t = threadIdx.x;
    int r0 = blockIdx.x * 64;
    // stage B_hi: each thread copies 64 bf16
    {
        int n = t >> 1;
        int k0 = (t & 1) * 64;
#pragma unroll
        for (int j = 0; j < 8; j++) {
            bf16x8 v = *(const bf16x8*)(BT_hi + n * 128 + k0 + 8 * j);
            *(bf16x8*)(sBh + n * 136 + k0 + 8 * j) = v;
        }
    }
    // stage A hi/lo: each thread converts 32 floats
    {
        int r = t >> 2;
        int k0 = (t & 3) * 32;
        const float* ar = A + (size_t)(r0 + r) * 128 + k0;
#pragma unroll
        for (int j = 0; j < 4; j++) {
            float4 f0 = *(const float4*)(ar + 8 * j);
            float4 f1 = *(const float4*)(ar + 8 * j + 4);
            float x[8] = {f0.x, f0.y, f0.z, f0.w, f1.x, f1.y, f1.z, f1.w};
            bf16x8 vh, vl;
#pragma unroll
            for (int q = 0; q < 8; q++) {
                short hh = f2bf(x[q]);
                vh[q] = hh;
                vl[q] = f2bf(x[q] - bf2f(hh));
            }
            *(bf16x8*)(sAh + r * 136 + k0 + 8 * j) = vh;
            *(bf16x8*)(sAl + r * 136 + k0 + 8 * j) = vl;
        }
    }
    __syncthreads();
    int lane = t & 63, wv = t >> 6;
    int lm = lane & 15, quad = lane >> 4;
    int m0 = wv * 16;
    bf16x8 aH[4], aL[4];
#pragma unroll
    for (int kt = 0; kt < 4; kt++) {
        aH[kt] = *(const bf16x8*)(sAh + (m0 + lm) * 136 + kt * 32 + quad * 8);
        aL[kt] = *(const bf16x8*)(sAl + (m0 + lm) * 136 + kt * 32 + quad * 8);
    }
#pragma unroll
    for (int nt = 0; nt < 8; nt++) {
        const short* blp = BT_lo + (nt * 16 + lm) * 128 + quad * 8;
        floatx4 acc = (floatx4){0.f, 0.f, 0.f, 0.f};
#pragma unroll
        for (int kt = 0; kt < 4; kt++) {
            bf16x8 bH = *(const bf16x8*)(sBh + (nt * 16 + lm) * 136 + kt * 32 + quad * 8);
            bf16x8 bL = *(const bf16x8*)(blp + kt * 32);
            acc = __builtin_amdgcn_mfma_f32_16x16x32_bf16(aH[kt], bH, acc, 0, 0, 0);
            acc = __builtin_amdgcn_mfma_f32_16x16x32_bf16(aL[kt], bH, acc, 0, 0, 0);
            acc = __builtin_amdgcn_mfma_f32_16x16x32_bf16(aH[kt], bL, acc, 0, 0, 0);
        }
        int col = nt * 16 + lm;
        if (col < ncols) {
            float bv = bias ? bias[col] : 0.f;
#pragma unroll
            for (int r = 0; r < 4; r++) {
                int row = r0 + m0 + quad * 4 + r;
                C[(size_t)row * ncols + col] = acc[r] + bv;
            }
        }
    }
}

// ---------------- MFMA GEMM: [N,128](fp32) @ WbT(bf16 [n][k]) -> bf16 out ----------------
// 64 rows/block, full N=128. A converted fp32->bf16 into LDS (+8 pad = 2-way bank, free).
// Optional fused el/er epilogue (replaces k_elr pass — r9, validated).
// Optional fused BN prologue (r10): h = mask(bnh + elu(scale*x+shift)).
// Optional SECOND output (r13): when WbT2!=null, re-stage sB from WbT2 after a barrier
// and compute C2 reusing the in-register aF fragments — merges the Pb/Qb pair, deleting
// one dispatch and a redundant 20MB A-read+conversion.
__global__ __launch_bounds__(256) void k_gemm_mfma(const float* __restrict__ A,
                                                   const short* __restrict__ WbT,
                                                   const float* __restrict__ bias,
                                                   short* __restrict__ C,
                                                   const short* __restrict__ WelT,
                                                   float* __restrict__ el,
                                                   float* __restrict__ er,
                                                   int H,
                                                   const float* __restrict__ bnx,
                                                   const float* __restrict__ bnh,
                                                   const float* __restrict__ csum,
                                                   const float* __restrict__ csq,
                                                   const float* __restrict__ bng,
                                                   const float* __restrict__ bnb,
                                                   float* __restrict__ hout,
                                                   int do_mask,
                                                   const short* __restrict__ WbT2,
                                                   short* __restrict__ C2) {
    __shared__ short sA[64 * 136];
    __shared__ short sB[128 * 136];
    __shared__ float sScale[128];
    __shared__ float sShift[128];
    int t = threadIdx.x;
    int r0 = blockIdx.x * 64;
    if (bnx) {
        if (t < 128) {
            const float invN = 1.f / (float)N_;
            float mu = csum[t] * invN;
            float var = csq[t] * invN - mu * mu;
            float inv = rsqrtf(var + 1e-5f);
            float sc = bng[t] * inv;
            sScale[t] = sc;
            sShift[t] = bnb[t] - mu * sc;
        }
        __syncthreads();
    }
    // stage B: each thread copies 64 bf16
    {
        int n = t >> 1;
        int k0 = (t & 1) * 64;
#pragma unroll
        for (int j = 0; j < 8; j++) {
            bf16x8 v = *(const bf16x8*)(WbT + n * 128 + k0 + 8 * j);
            *(bf16x8*)(sB + n * 136 + k0 + 8 * j) = v;
        }
    }
    // stage A: each thread handles 32 elements of one row-quarter
    {
        int r = t >> 2;
        int k0 = (t & 3) * 32;
        if (bnx) {
            const float* xr = bnx + (size_t)(r0 + r) * 128 + k0;
            const float* hr = bnh + (size_t)(r0 + r) * 128 + k0;
            float* ho = hout + (size_t)(r0 + r) * 128 + k0;
#pragma unroll
            for (int j = 0; j < 4; j++) {
                float4 x0 = *(const float4*)(xr + 8 * j);
                float4 x1 = *(const float4*)(xr + 8 * j + 4);
                float4 h0 = *(const float4*)(hr + 8 * j);
                float4 h1 = *(const float4*)(hr + 8 * j + 4);
                float xs[8] = {x0.x, x0.y, x0.z, x0.w, x1.x, x1.y, x1.z, x1.w};
                float hs[8] = {h0.x, h0.y, h0.z, h0.w, h1.x, h1.y, h1.z, h1.w};
                float ov[8];
                bf16x8 v;
#pragma unroll
                for (int q = 0; q < 8; q++) {
                    int c = k0 + 8 * j + q;
                    float y = sScale[c] * xs[q] + sShift[c];
                    y = y > 0.f ? y : (__expf(y) - 1.f);
                    float hv = hs[q] + y;
                    if (do_mask && isinf(hv)) hv = 1e9f;
                    ov[q] = hv;
                    v[q] = f2bf(hv);
                }
                *(float4*)(ho + 8 * j) = make_float4(ov[0], ov[1], ov[2], ov[3]);
                *(float4*)(ho + 8 * j + 4) = make_float4(ov[4], ov[5], ov[6], ov[7]);
                *(bf16x8*)(sA + r * 136 + k0 + 8 * j) = v;
            }
        } else {
            const float* ar = A + (size_t)(r0 + r) * 128 + k0;
#pragma unroll
            for (int j = 0; j < 4; j++) {
                float4 f0 = *(const float4*)(ar + 8 * j);
                float4 f1 = *(const float4*)(ar + 8 * j + 4);
                bf16x8 v;
                v[0] = f2bf(f0.x); v[1] = f2bf(f0.y); v[2] = f2bf(f0.z); v[3] = f2bf(f0.w);
                v[4] = f2bf(f1.x); v[5] = f2bf(f1.y); v[6] = f2bf(f1.z); v[7] = f2bf(f1.w);
                *(bf16x8*)(sA + r * 136 + k0 + 8 * j) = v;
            }
        }
    }
    __syncthreads();
    int lane = t & 63, wv = t >> 6;
    int lm = lane & 15, quad = lane >> 4;
    int m0 = wv * 16;
    bf16x8 aF[4];
#pragma unroll
    for (int kt = 0; kt < 4; kt++)
        aF[kt] = *(const bf16x8*)(sA + (m0 + lm) * 136 + kt * 32 + quad * 8);
#pragma unroll
    for (int nt = 0; nt < 8; nt++) {
        floatx4 acc = (floatx4){0.f, 0.f, 0.f, 0.f};
#pragma unroll
        for (int kt = 0; kt < 4; kt++) {
            bf16x8 bF = *(const bf16x8*)(sB + (nt * 16 + lm) * 136 + kt * 32 + quad * 8);
            acc = __builtin_amdgcn_mfma_f32_16x16x32_bf16(aF[kt], bF, acc, 0, 0, 0);
        }
        int col = nt * 16 + lm;
        float bv = bias ? bias[col] : 0.f;
#pragma unroll
        for (int r = 0; r < 4; r++) {
            int row = r0 + m0 + quad * 4 + r;
            C[(size_t)row * 128 + col] = f2bf(acc[r] + bv);
        }
    }
    // fused el/er tile: cols 0..7 = el heads, 8..15 = er heads (H=1: col0=el, col1=er)
    if (WelT) {
        floatx4 acc = (floatx4){0.f, 0.f, 0.f, 0.f};
#pragma unroll
        for (int kt = 0; kt < 4; kt++) {
            bf16x8 wF = *(const bf16x8*)(WelT + lm * 128 + kt * 32 + quad * 8);
            acc = __builtin_amdgcn_mfma_f32_16x16x32_bf16(aF[kt], wF, acc, 0, 0, 0);
        }
        if (H == 8) {
#pragma unroll
            for (int r = 0; r < 4; r++) {
                int row = r0 + m0 + quad * 4 + r;
                if (lm < 8) el[(size_t)row * 8 + lm] = acc[r];
                else        er[(size_t)row * 8 + (lm - 8)] = acc[r];
            }
        } else {
#pragma unroll
            for (int r = 0; r < 4; r++) {
                int row = r0 + m0 + quad * 4 + r;
                if (lm == 0) el[row] = acc[r];
                if (lm == 1) er[row] = acc[r];
            }
        }
    }
    // second output: re-stage sB, recompute with same aF (Pb/Qb merge)
    if (WbT2) {
        __syncthreads();   // all compute reads of sB complete
        {
            int n = t >> 1;
            int k0 = (t & 1) * 64;
#pragma unroll
            for (int j = 0; j < 8; j++) {
                bf16x8 v = *(const bf16x8*)(WbT2 + n * 128 + k0 + 8 * j);
                *(bf16x8*)(sB + n * 136 + k0 + 8 * j) = v;
            }
        }
        __syncthreads();
#pragma unroll
        for (int nt = 0; nt < 8; nt++) {
            floatx4 acc = (floatx4){0.f, 0.f, 0.f, 0.f};
#pragma unroll
            for (int kt = 0; kt < 4; kt++) {
                bf16x8 bF = *(const bf16x8*)(sB + (nt * 16 + lm) * 136 + kt * 32 + quad * 8);
                acc = __builtin_amdgcn_mfma_f32_16x16x32_bf16(aF[kt], bF, acc, 0, 0, 0);
            }
            int col = nt * 16 + lm;
#pragma unroll
            for (int r = 0; r < 4; r++) {
                int row = r0 + m0 + quad * 4 + r;
                C2[(size_t)row * 128 + col] = f2bf(acc[r]);
            }
        }
    }
}

// ---------------- softmax over 100 logits, wave per node, barrier-free ----------------
__global__ __launch_bounds__(256) void k_smax100(const float* __restrict__ logits,
                                                 float* __restrict__ s) {
    int lane = threadIdx.x & 63;
    int n = blockIdx.x * 4 + (threadIdx.x >> 6);
    if (n >= N_) return;
    bool act = lane < 50;
    float2 v = make_float2(-INFINITY, -INFINITY);
    if (act) v = *(const float2*)(logits + (size_t)n * 100 + 2 * lane);
    float mx = fmaxf(v.x, v.y);
#pragma unroll
    for (int off = 1; off < 64; off <<= 1) mx = fmaxf(mx, __shfl_xor(mx, off));
    float e0 = act ? __expf(v.x - mx) : 0.f;
    float e1 = act ? __expf(v.y - mx) : 0.f;
    float sm = e0 + e1;
#pragma unroll
    for (int off = 1; off < 64; off <<= 1) sm += __shfl_xor(sm, off);
    float inv = 1.f / sm;
    if (act) *(float2*)(s + (size_t)n * 100 + 2 * lane) = make_float2(e0 * inv, e1 * inv);
}

// ---------------- GAT edge-softmax + aggregate (wave per dst node, bf16 feat) ----------------
// v6 (r12, VALIDATED 755us): pass 1/2 identical to v4; BN stats via per-block coalesced
// partials + k_stats_reduce — NO global atomics (r7's failure was the atomic burst).
template <int H>
__global__ __launch_bounds__(256) void k_gat_agg(const short* __restrict__ feat,
                                                 const float* __restrict__ el,
                                                 const float* __restrict__ er,
                                                 const int* __restrict__ rowptr,
                                                 const int* __restrict__ srcv,
                                                 const float* __restrict__ bias,
                                                 float* __restrict__ xout,
                                                 float* __restrict__ psum,
                                                 float* __restrict__ psq) {
    int t = threadIdx.x;
    int lane = t & 63;
    int gw = (blockIdx.x * blockDim.x + t) >> 6;
    int nw = (gridDim.x * blockDim.x) >> 6;
    constexpr int LH = (H == 8) ? 3 : 0;
    int h = lane & (H - 1);
    int f0 = 2 * lane;
    int hf = (H == 8) ? (lane >> 3) : 0;   // head owning this lane's feature slice

    float stx = 0.f, sty = 0.f, qtx = 0.f, qty = 0.f;  // fused BN stats

    for (int n = gw; n < N_; n += nw) {
        int beg = rowptr[n], end = rowptr[n + 1];
        if (beg == end) {
            float2 b2 = *(const float2*)(bias + f0);
            *(float2*)(xout + (size_t)n * 128 + f0) = b2;
            stx += b2.x; sty += b2.y;
            qtx += b2.x * b2.x; qty += b2.y * b2.y;
            continue;
        }
        float ern = er[(size_t)n * H + h];
        // ---- pass 1: online softmax stats ----
        float m = -INFINITY, ss = 0.f;
        for (int e = beg + (lane >> LH); e < end; e += (64 >> LH)) {
            int sI = srcv[e];
            float x = el[(size_t)sI * H + h] + ern;
            float lr = x > 0.f ? x : 0.2f * x;
            if (lr > m) { ss = ss * __expf(m - lr) + 1.f; m = lr; }
            else ss += __expf(lr - m);
        }
#pragma unroll
        for (int off = H; off < 64; off <<= 1) {
            float om = __shfl_xor(m, off);
            float os = __shfl_xor(ss, off);
            float nm = fmaxf(m, om);
            float p1 = (m == -INFINITY) ? 0.f : ss * __expf(m - nm);
            float p2 = (om == -INFINITY) ? 0.f : os * __expf(om - nm);
            m = nm; ss = p1 + p2;
        }
        // after butterfly each lane holds (m, ss) for its own head h = lane&(H-1)
        float inv_d = 1.f / ss;
        // ---- pass 2: 2x interleaved chunked aggregation ----
        int endm1 = end - 1;
        float accx = 0.f, accy = 0.f;
        for (int e0 = beg; e0 < end; e0 += 16) {
            int le = lane >> 3;
            int eLA = e0 + le, eLB = e0 + 8 + le;
            int eCA = eLA <= endm1 ? eLA : endm1;
            int eCB = eLB <= endm1 ? eLB : endm1;
            int sLA = srcv[eCA];
            int sLB = srcv[eCB];
            float xA = el[(size_t)sLA * H + h] + ern;
            float xB = el[(size_t)sLB * H + h] + ern;
            float lrA = xA > 0.f ? xA : 0.2f * xA;
            float lrB = xB > 0.f ? xB : 0.2f * xB;
            float wA = __expf(lrA - m) * inv_d;
            float wB = __expf(lrB - m) * inv_d;
            if (eLA > endm1) wA = 0.f;
            if (eLB > endm1) wB = 0.f;
            bool haveB = (e0 + 8) < end;    // wave-uniform
            unsigned int uuA[8], uuB[8];
#pragma unroll
            for (int j = 0; j < 8; j++) {
                int sj = __builtin_amdgcn_readlane(sLA, j * 8);
                uuA[j] = *(const unsigned int*)(feat + (size_t)sj * 128 + f0);
            }
            if (haveB) {
#pragma unroll
                for (int j = 0; j < 8; j++) {
                    int sj = __builtin_amdgcn_readlane(sLB, j * 8);
                    uuB[j] = *(const unsigned int*)(feat + (size_t)sj * 128 + f0);
                }
            }
#pragma unroll
            for (int j = 0; j < 8; j++) {
                float aj;
                if (H == 8) aj = __shfl(wA, j * 8 + hf);
                else        aj = rdlane(wA, j * 8);
                accx += aj * bflo(uuA[j]);
                accy += aj * bfhi(uuA[j]);
            }
            if (haveB) {
#pragma unroll
                for (int j = 0; j < 8; j++) {
                    float aj;
                    if (H == 8) aj = __shfl(wB, j * 8 + hf);
                    else        aj = rdlane(wB, j * 8);
                    accx += aj * bflo(uuB[j]);
                    accy += aj * bfhi(uuB[j]);
                }
            }
        }
        float2 b2 = *(const float2*)(bias + f0);
        float ox = accx + b2.x, oy = accy + b2.y;
        *(float2*)(xout + (size_t)n * 128 + f0) = make_float2(ox, oy);
        stx += ox; sty += oy;
        qtx += ox * ox; qty += oy * oy;
    }

    // ---- per-block partial stats: LDS reduce across 4 waves, coalesced plain store ----
    __shared__ float red[4][256];
    red[0][t] = stx; red[1][t] = sty; red[2][t] = qtx; red[3][t] = qty;
    __syncthreads();
    if (t < 64) {
        float a0 = red[0][t] + red[0][t + 64] + red[0][t + 128] + red[0][t + 192];
        float a1 = red[1][t] + red[1][t + 64] + red[1][t + 128] + red[1][t + 192];
        float q0 = red[2][t] + red[2][t + 64] + red[2][t + 128] + red[2][t + 192];
        float q1 = red[3][t] + red[3][t + 64] + red[3][t + 128] + red[3][t + 192];
        *(float2*)(psum + (size_t)blockIdx.x * 128 + 2 * t) = make_float2(a0, a1);
        *(float2*)(psq + (size_t)blockIdx.x * 128 + 2 * t) = make_float2(q0, q1);
    }
}

// ---------------- reduce per-block stats partials -> colsum/colsq ----------------
__global__ __launch_bounds__(256) void k_stats_reduce(const float* __restrict__ psum,
                                                      const float* __restrict__ psq,
                                                      float* __restrict__ colsum,
                                                      float* __restrict__ colsq) {
    __shared__ float ls[256], lq[256];
    int t = threadIdx.x;
    int col = t & 127, half = t >> 7;
    float s = 0.f, q = 0.f;
    for (int b = blockIdx.x * 2 + half; b < AGGB_; b += gridDim.x * 2) {
        s += psum[(size_t)b * 128 + col];
        q += psq[(size_t)b * 128 + col];
    }
    ls[t] = s; lq[t] = q;
    __syncthreads();
    if (t < 128) {
        atomicAdd(&colsum[col], ls[t] + ls[t + 128]);
        atomicAdd(&colsq[col], lq[t] + lq[t + 128]);
    }
}

// ---------------- BN apply + ELU + residual (+mask) — layer-1 only ----------------
__global__ __launch_bounds__(256) void k_bn_apply(const float* __restrict__ x,
                                                  const float* __restrict__ hprev,
                                                  const float* __restrict__ sum,
                                                  const float* __restrict__ sumsq,
                                                  const float* __restrict__ g,
                                                  const float* __restrict__ b,
                                                  float* __restrict__ out, int do_mask) {
    int i = blockIdx.x * blockDim.x + threadIdx.x;
    if (i >= N_ * 128) return;
    int c = i & 127;
    const float invN = 1.f / (float)N_;
    float mu = sum[c] * invN;
    float var = sumsq[c] * invN - mu * mu;
    float inv = rsqrtf(var + 1e-5f);
    float y = g[c] * (x[i] - mu) * inv + b[c];
    y = y > 0.f ? y : (__expf(y) - 1.f);
    float hv = hprev[i] + y;
    if (do_mask && isinf(hv)) hv = 1e9f;
    out[i] = hv;
}

// ---------------- h_coarse partials ----------------
__global__ __launch_bounds__(512) void k_coarse_part(const float* __restrict__ s,
                                                     const float* __restrict__ hf,
                                                     float* __restrict__ part) {
    int t = threadIdx.x;
    int c = t & 127;
    int g = t >> 7;        // 0..3
    int lane = t & 63;
    float acc[25];
#pragma unroll
    for (int a = 0; a < 25; a++) acc[a] = 0.f;
    int n0 = blockIdx.x * CR_;
    for (int n = n0; n < n0 + CR_; n += 2) {
        float hv0 = hf[(size_t)n * 128 + c];
        float hv1 = hf[(size_t)(n + 1) * 128 + c];
        float sv0 = 0.f, sv1 = 0.f;
        if (lane < 25) {
            sv0 = s[(size_t)n * 100 + 25 * g + lane];
            sv1 = s[(size_t)(n + 1) * 100 + 25 * g + lane];
        }
#pragma unroll
        for (int a = 0; a < 25; ++a) {
            float a0 = rdlane(sv0, a);
            float a1 = rdlane(sv1, a);
            acc[a] += a0 * hv0 + a1 * hv1;
        }
    }
    float* dstp = part + (size_t)blockIdx.x * 12800 + (size_t)(25 * g) * 128 + c;
#pragma unroll
    for (int a = 0; a < 25; a++) dstp[a * 128] = acc[a];
}

// ---------------- reduce partials -> hc[100][128] ----------------
__global__ __launch_bounds__(256) void k_coarse_reduce(const float* __restrict__ part,
                                                       float* __restrict__ hc) {
    int i = blockIdx.x * blockDim.x + threadIdx.x;  // 12800 total
    if (i >= 12800) return;
    float s0 = 0.f, s1 = 0.f, s2 = 0.f, s3 = 0.f;
    for (int b = 0; b < CB_; b += 4) {
        s0 += part[(size_t)(b + 0) * 12800 + i];
        s1 += part[(size_t)(b + 1) * 12800 + i];
        s2 += part[(size_t)(b + 2) * 12800 + i];
        s3 += part[(size_t)(b + 3) * 12800 + i];
    }
    hc[i] = (s0 + s1) + (s2 + s3);
}

// ---------------- h = mask(0.5*h_fine + 0.5*(s@h_coarse)) ----------------
__global__ __launch_bounds__(256) void k_combine(const float* __restrict__ s,
                                                 const float* __restrict__ hc,
                                                 const float* __restrict__ hfine,
                                                 float* __restrict__ hout) {
    __shared__ float ssh[16 * 100];
    int t = threadIdx.x;
    int n0 = blockIdx.x * 16;
    for (int u = t; u < 1600; u += 256) ssh[u] = s[(size_t)n0 * 100 + u];
    __syncthreads();
    int c = t & 127, g = t >> 7;
    float acc[8];
#pragma unroll
    for (int r = 0; r < 8; r++) acc[r] = 0.f;
    const float* hcp = hc + c;
    for (int a = 0; a < 100; a += 4) {
        float h0 = hcp[(a + 0) * 128];
        float h1 = hcp[(a + 1) * 128];
        float h2 = hcp[(a + 2) * 128];
        float h3 = hcp[(a + 3) * 128];
#pragma unroll
        for (int r = 0; r < 8; r++) {
            float4 sv = *(const float4*)(ssh + (g * 8 + r) * 100 + a);
            acc[r] += sv.x * h0 + sv.y * h1 + sv.z * h2 + sv.w * h3;
        }
    }
#pragma unroll
    for (int r = 0; r < 8; r++) {
        int row = n0 + g * 8 + r;
        float v = 0.5f * hfine[(size_t)row * 128 + c] + 0.5f * acc[r];
        if (isinf(v)) v = 1e9f;
        hout[(size_t)row * 128 + c] = v;
    }
}

// ---------------- prep: Wm2 [128][64] fp32 -> Wm2T bf16 [64][128] ----------------
__global__ __launch_bounds__(256) void k_prep_w(const float* __restrict__ Wm2,
                                                short* __restrict__ Wm2T) {
    int i = blockIdx.x * blockDim.x + threadIdx.x;  // 8192 total
    if (i >= 64 * 128) return;
    int n = i & 63, k = i >> 6;
    Wm2T[n * 128 + k] = f2bf(Wm2[k * 64 + n]);
}

// ---------------- edge MLP readout: dst-sorted order, barrier-free persistent MFMA ----------------
// v2 — LOCAL OPTIMUM at ~54us, VGPR 84. Do not register-diet (v3: spills, 3x dur).
// Do not 2-tile (v4: compiler serializes the B-tile loads, occupancy drops, +6us).
__global__ __launch_bounds__(256) void k_edge_mlp3(const short* __restrict__ Pb,
                                                   const short* __restrict__ Qb,
                                                   const int* __restrict__ srcv,
                                                   const unsigned short* __restrict__ dstv,
                                                   const int* __restrict__ eidv,
                                                   const short* __restrict__ Wm2T,
                                                   const float* __restrict__ bm2,
                                                   const float* __restrict__ Wm3,
                                                   const float* __restrict__ bm3,
                                                   float* __restrict__ zout) {
    __shared__ short sW[64 * 128];  // 16 KiB
    int t = threadIdx.x;
    // stage Wm2T -> LDS with 16B-unit XOR swizzle: phys_unit = n*16 + (k16 ^ (n&15))
    for (int u = t; u < 1024; u += 256) {
        int n = u >> 4, k16 = u & 15;
        int phys = (n << 4) | (k16 ^ (n & 15));
        *(bf16x8*)(sW + phys * 8) = *(const bf16x8*)(Wm2T + n * 128 + k16 * 8);
    }
    int lane = t & 63;
    int lm = lane & 15, quad = lane >> 4;
    float bv[4], w30[4], w31[4];
#pragma unroll
    for (int nt = 0; nt < 4; nt++) {
        int n = nt * 16 + lm;
        bv[nt] = bm2[n]; w30[nt] = Wm3[2 * n]; w31[nt] = Wm3[2 * n + 1];
    }
    float b30 = bm3[0], b31 = bm3[1];
    __syncthreads();

    int gw = (blockIdx.x * blockDim.x + t) >> 6;
    int nw = (gridDim.x * blockDim.x) >> 6;

    for (int tile = gw; tile < E_ / 16; tile += nw) {
        int p0 = tile * 16;
        int sI = srcv[p0 + lm];
        int dI = (int)dstv[p0 + lm];
        const short* pr = Pb + (size_t)sI * 128 + quad * 8;
        const short* qr = Qb + (size_t)dI * 128 + quad * 8;
        // issue all 8 gathers up-front (latency hidden within wave)
        uint4 pu[4], qu[4];
#pragma unroll
        for (int kt = 0; kt < 4; kt++) {
            pu[kt] = *(const uint4*)(pr + kt * 32);
            qu[kt] = *(const uint4*)(qr + kt * 32);
        }
        bf16x8 aF[4];
#pragma unroll
        for (int kt = 0; kt < 4; kt++) {
            unsigned int pv[4] = {pu[kt].x, pu[kt].y, pu[kt].z, pu[kt].w};
            unsigned int qv[4] = {qu[kt].x, qu[kt].y, qu[kt].z, qu[kt].w};
            union { uint4 u; bf16x8 v; } cv;
            unsigned int rr[4];
#pragma unroll
            for (int j = 0; j < 4; j++) {
                float fl = fmaxf(bflo(pv[j]) + bflo(qv[j]), 0.f);
                float fh = fmaxf(bfhi(pv[j]) + bfhi(qv[j]), 0.f);
                rr[j] = (unsigned int)(unsigned short)f2bf(fl) |
                        ((unsigned int)(unsigned short)f2bf(fh) << 16);
            }
            cv.u.x = rr[0]; cv.u.y = rr[1]; cv.u.z = rr[2]; cv.u.w = rr[3];
            aF[kt] = cv.v;
        }
        float pz0[4] = {0.f, 0.f, 0.f, 0.f};
        float pz1[4] = {0.f, 0.f, 0.f, 0.f};
#pragma unroll
        for (int nt = 0; nt < 4; nt++) {
            floatx4 acc = (floatx4){0.f, 0.f, 0.f, 0.f};
#pragma unroll
            for (int kt = 0; kt < 4; kt++) {
                int phys = ((nt * 16 + lm) << 4) | (((kt << 2) | quad) ^ lm);
                bf16x8 bF = *(const bf16x8*)(sW + phys * 8);
                acc = __builtin_amdgcn_mfma_f32_16x16x32_bf16(aF[kt], bF, acc, 0, 0, 0);
            }
#pragma unroll
            for (int r = 0; r < 4; r++) {
                float u = fmaxf(acc[r] + bv[nt], 0.f);
                pz0[r] += u * w30[nt];
                pz1[r] += u * w31[nt];
            }
        }
#pragma unroll
        for (int off = 1; off < 16; off <<= 1) {
#pragma unroll
            for (int r = 0; r < 4; r++) {
                pz0[r] += __shfl_xor(pz0[r], off);
                pz1[r] += __shfl_xor(pz1[r], off);
            }
        }
        if (lm < 4) {
            int eid = eidv[p0 + quad * 4 + lm];
            float z0 = pz0[lm] + b30;
            float z1 = pz1[lm] + b31;
            if (isinf(z0)) z0 = 1e9f;
            if (isinf(z1)) z1 = 1e9f;
            *(float2*)(zout + (size_t)eid * 2) = make_float2(z0, z1);
        }
    }
}

extern "C" void kernel_launch(void* const* d_in, const int* in_sizes, int n_in,
                              void* d_out, int out_size, void* d_ws, size_t ws_size,
                              hipStream_t stream) {
    const float* h_in  = (const float*)d_in[0];
    const int*   src   = (const int*)d_in[2];
    const int*   dst   = (const int*)d_in[3];
    const float* W_emb = (const float*)d_in[4];
    const float* b_emb = (const float*)d_in[5];
    const float* Wg    = (const float*)d_in[6];
    const float* alg   = (const float*)d_in[7];
    const float* arg_  = (const float*)d_in[8];
    const float* bg    = (const float*)d_in[9];
    const float* gam   = (const float*)d_in[10];
    const float* bet   = (const float*)d_in[11];
    const float* W3    = (const float*)d_in[12];
    const float* al3   = (const float*)d_in[13];
    const float* ar3   = (const float*)d_in[14];
    const float* b3    = (const float*)d_in[15];
    const float* gam3  = (const float*)d_in[16];
    const float* bet3  = (const float*)d_in[17];
    const float* Wa    = (const float*)d_in[18];
    const float* ba    = (const float*)d_in[19];
    const float* Wm1   = (const float*)d_in[20];
    const float* bm1   = (const float*)d_in[21];
    const float* Wm2   = (const float*)d_in[22];
    const float* bm2   = (const float*)d_in[23];
    const float* Wm3   = (const float*)d_in[24];
    const float* bm3   = (const float*)d_in[25];

    float* zout = (float*)d_out;
    float* sout = zout + (size_t)E_ * 2;

    float* ws = (float*)d_ws;
    size_t o = 0;
    float* h_cur = ws + o; o += (size_t)N_ * 128;
    float* xbuf  = ws + o; o += (size_t)N_ * 128;
    float* featb = ws + o; o += (size_t)N_ * 128;   // reused: bf16 feat, coarse partials, bf16 P/Q
    float* el    = ws + o; o += (size_t)N_ * 8;
    float* er    = ws + o; o += (size_t)N_ * 8;
    float* colsum = ws + o; o += 128;
    float* colsq  = ws + o; o += 128;
    float* hc     = ws + o; o += 100 * 128;
    float* psum   = ws + o; o += (size_t)AGGB_ * 128;
    float* psq    = ws + o; o += (size_t)AGGB_ * 128;
    short* Wm2T = (short*)(ws + o); o += (64 * 128) / 2;
    short* WbT6 = (short*)(ws + o); o += (6 * 16384) / 2;
    short* WelT = (short*)(ws + o); o += (4 * 2048) / 2;
    short* WembT_hi = (short*)(ws + o); o += 16384 / 2;
    short* WembT_lo = (short*)(ws + o); o += 16384 / 2;
    short* WaT_hi   = (short*)(ws + o); o += 16384 / 2;
    short* WaT_lo   = (short*)(ws + o); o += 16384 / 2;
    int* counts = (int*)(ws + o); o += N_;
    int* rowptr = (int*)(ws + o); o += N_ + 4;
    int* cursor = (int*)(ws + o); o += N_;
    int* srcv   = (int*)(ws + o); o += E_;
    unsigned short* dstv = (unsigned short*)(ws + o); o += E_ / 2;
    int* eidv   = (int*)(ws + o); o += E_;
    int* bsum   = (int*)(ws + o); o += SNB_ + 4;

    short* featw = (short*)featb;  // bf16 per-layer projection

    // ---- CSR build (parallel scan; excl scratch reuses eidv pre-fill) ----
    hipMemsetAsync(counts, 0, N_ * sizeof(int), stream);
    k_count<<<1024, 256, 0, stream>>>(dst, counts);
    k_scanA<<<SNB_, 256, 0, stream>>>(counts, eidv, bsum);
    k_scanB<<<1, 256, 0, stream>>>(bsum);
    k_scanC<<<SNB_ + 1, 256, 0, stream>>>(eidv, bsum, rowptr, cursor);
    k_fill<<<1024, 256, 0, stream>>>(src, dst, cursor, srcv, dstv, eidv);
    k_prep_w<<<32, 256, 0, stream>>>(Wm2, Wm2T);
    k_prep_all<<<384, 256, 0, stream>>>(Wg, W3, Wm1, WbT6);
    k_prep_wela<<<32, 256, 0, stream>>>(Wg, alg, arg_, W3, al3, ar3, WelT);
    k_prep_hilo<<<128, 256, 0, stream>>>(W_emb, Wa, WembT_hi, WembT_lo, WaT_hi, WaT_lo);

    // ---- embedding (fp32-accurate via hi/lo MFMA) ----
    k_mfma_hilo<<<N_ / 64, 256, 0, stream>>>(h_in, WembT_hi, WembT_lo, b_emb, h_cur, 128);

    // ---- layer 0 (H=8) ----
    k_gemm_mfma<<<N_ / 64, 256, 0, stream>>>(h_cur, WbT6 + 0 * 16384, nullptr, featw,
                                             WelT + 0 * 2048, el, er, 8,
                                             nullptr, nullptr, nullptr, nullptr,
                                             nullptr, nullptr, nullptr, 0,
                                             nullptr, nullptr);
    hipMemsetAsync(colsum, 0, 256 * sizeof(float), stream);
    k_gat_agg<8><<<AGGB_, 256, 0, stream>>>(featw, el, er, rowptr, srcv, bg + 0 * 128, xbuf,
                                            psum, psq);
    k_stats_reduce<<<64, 256, 0, stream>>>(psum, psq, colsum, colsq);

    // ---- layer 1 (biGAT, H=8): gemm fused with layer-0 BN (writes h_cur) ----
    k_gemm_mfma<<<N_ / 64, 256, 0, stream>>>(nullptr, WbT6 + 1 * 16384, nullptr, featw,
                                             WelT + 1 * 2048, el, er, 8,
                                             xbuf, h_cur, colsum, colsq,
                                             gam + 0 * 128, bet + 0 * 128, h_cur, 1,
                                             nullptr, nullptr);
    k_mfma_hilo<<<N_ / 64, 256, 0, stream>>>(h_cur, WaT_hi, WaT_lo, ba, xbuf, 100);
    k_smax100<<<N_ / 4, 256, 0, stream>>>(xbuf, sout);
    hipMemsetAsync(colsum, 0, 256 * sizeof(float), stream);
    k_gat_agg<8><<<AGGB_, 256, 0, stream>>>(featw, el, er, rowptr, srcv, bg + 1 * 128, xbuf,
                                            psum, psq);
    k_stats_reduce<<<64, 256, 0, stream>>>(psum, psq, colsum, colsq);
    k_bn_apply<<<(N_ * 128) / 256, 256, 0, stream>>>(xbuf, h_cur, colsum, colsq,
                                                     gam + 1 * 128, bet + 1 * 128, xbuf, 0);
    k_coarse_part<<<CB_, 512, 0, stream>>>(sout, xbuf, featb);
    k_coarse_reduce<<<50, 256, 0, stream>>>(featb, hc);
    k_combine<<<N_ / 16, 256, 0, stream>>>(sout, hc, xbuf, h_cur);

    // ---- layer 2 (H=8) ----
    k_gemm_mfma<<<N_ / 64, 256, 0, stream>>>(h_cur, WbT6 + 2 * 16384, nullptr, featw,
                                             WelT + 2 * 2048, el, er, 8,
                                             nullptr, nullptr, nullptr, nullptr,
                                             nullptr, nullptr, nullptr, 0,
                                             nullptr, nullptr);
    hipMemsetAsync(colsum, 0, 256 * sizeof(float), stream);
    k_gat_agg<8><<<AGGB_, 256, 0, stream>>>(featw, el, er, rowptr, srcv, bg + 2 * 128, xbuf,
                                            psum, psq);
    k_stats_reduce<<<64, 256, 0, stream>>>(psum, psq, colsum, colsq);

    // ---- layer 3 (H=1): gemm fused with layer-2 BN (writes h_cur) ----
    k_gemm_mfma<<<N_ / 64, 256, 0, stream>>>(nullptr, WbT6 + 3 * 16384, nullptr, featw,
                                             WelT + 3 * 2048, el, er, 1,
                                             xbuf, h_cur, colsum, colsq,
                                             gam + 2 * 128, bet + 2 * 128, h_cur, 1,
                                             nullptr, nullptr);
    hipMemsetAsync(colsum, 0, 256 * sizeof(float), stream);
    k_gat_agg<1><<<AGGB_, 256, 0, stream>>>(featw, el, er, rowptr, srcv, b3, xbuf,
                                            psum, psq);
    k_stats_reduce<<<64, 256, 0, stream>>>(psum, psq, colsum, colsq);

    // ---- edge MLP readout: ONE gemm (layer-3 BN fused) producing BOTH Pb and Qb ----
    short* Pb = (short*)featb;
    short* Qb = Pb + (size_t)N_ * 128;
    k_gemm_mfma<<<N_ / 64, 256, 0, stream>>>(nullptr, WbT6 + 4 * 16384, bm1, Pb,
                                             nullptr, nullptr, nullptr, 0,
                                             xbuf, h_cur, colsum, colsq,
                                             gam3, bet3, h_cur, 1,
                                             WbT6 + 5 * 16384, Qb);
    k_edge_mlp3<<<2048, 256, 0, stream>>>(Pb, Qb, srcv, dstv, eidv, Wm2T, bm2, Wm3, bm3, zout);
}

// Round 14
// 729.289 us; speedup vs baseline: 1.1188x; 1.0298x over previous
//
#include <hip/hip_runtime.h>
#include <hip/hip_bf16.h>
#include <math.h>

#define N_ 40000
#define E_ 640000
#define CB_ 400   // k_coarse partial blocks
#define CR_ 100   // rows per block (CB_*CR_ == N_)
#define SB_ 256
#define SNB_ 157  // ceil(N_/SB_)
#define AGGB_ 2048  // k_gat_agg grid (blocks); psum/psq sized to this

typedef short bf16x8 __attribute__((ext_vector_type(8)));
typedef float floatx4 __attribute__((ext_vector_type(4)));

__device__ __forceinline__ short f2bf(float f) {
    __hip_bfloat16 h = __float2bfloat16(f);
    return *reinterpret_cast<short*>(&h);
}
__device__ __forceinline__ float bf2f(short u) {
    unsigned int x = ((unsigned int)(unsigned short)u) << 16;
    return __int_as_float(x);
}
__device__ __forceinline__ float rdlane(float v, int l) {
    return __int_as_float(__builtin_amdgcn_readlane(__float_as_int(v), l));
}
// unpack 2 bf16 packed in a uint
__device__ __forceinline__ float bflo(unsigned int u) { return __int_as_float(u << 16); }
__device__ __forceinline__ float bfhi(unsigned int u) { return __int_as_float(u & 0xffff0000u); }

// ---------------- CSR build ----------------
__global__ void k_count(const int* __restrict__ dst, int* __restrict__ counts) {
    for (int e = blockIdx.x * blockDim.x + threadIdx.x; e < E_; e += gridDim.x * blockDim.x)
        atomicAdd(&counts[dst[e]], 1);
}

// ---- 3-phase parallel scan ----
__global__ __launch_bounds__(256) void k_scanA(const int* __restrict__ counts,
                                               int* __restrict__ excl,
                                               int* __restrict__ bsum) {
    int t = threadIdx.x;
    int i = blockIdx.x * SB_ + t;
    int v = (i < N_) ? counts[i] : 0;
    int lane = t & 63, wv = t >> 6;
    int x = v;
#pragma unroll
    for (int off = 1; off < 64; off <<= 1) {
        int y = __shfl_up(x, off);
        if (lane >= off) x += y;
    }
    __shared__ int wsum[4];
    __shared__ int woff[4];
    if (lane == 63) wsum[wv] = x;
    __syncthreads();
    if (t == 0) {
        int a = 0;
#pragma unroll
        for (int j = 0; j < 4; j++) { int tv = wsum[j]; woff[j] = a; a += tv; }
        bsum[blockIdx.x] = a;
    }
    __syncthreads();
    if (i < N_) excl[i] = x - v + woff[wv];
}

__global__ __launch_bounds__(256) void k_scanB(int* __restrict__ bsum) {
    int t = threadIdx.x;
    int v = (t < SNB_) ? bsum[t] : 0;
    int lane = t & 63, wv = t >> 6;
    int x = v;
#pragma unroll
    for (int off = 1; off < 64; off <<= 1) {
        int y = __shfl_up(x, off);
        if (lane >= off) x += y;
    }
    __shared__ int wsum[4];
    __shared__ int woff[4];
    if (lane == 63) wsum[wv] = x;
    __syncthreads();
    if (t == 0) {
        int a = 0;
#pragma unroll
        for (int j = 0; j < 4; j++) { int tv = wsum[j]; woff[j] = a; a += tv; }
    }
    __syncthreads();
    if (t < SNB_) bsum[t] = x - v + woff[wv];
}

__global__ __launch_bounds__(256) void k_scanC(const int* __restrict__ excl,
                                               const int* __restrict__ bsum,
                                               int* __restrict__ rowptr,
                                               int* __restrict__ cursor) {
    int i = blockIdx.x * 256 + threadIdx.x;
    if (i < N_) {
        int r = excl[i] + bsum[i / SB_];
        rowptr[i] = r;
        cursor[i] = r;
    }
    if (i == N_) rowptr[N_] = E_;
}

__global__ void k_fill(const int* __restrict__ src, const int* __restrict__ dst,
                       int* __restrict__ cursor, int* __restrict__ srcv,
                       unsigned short* __restrict__ dstv, int* __restrict__ eidv) {
    for (int e = blockIdx.x * blockDim.x + threadIdx.x; e < E_; e += gridDim.x * blockDim.x) {
        int d = dst[e];
        int pos = atomicAdd(&cursor[d], 1);
        srcv[pos] = src[e];
        dstv[pos] = (unsigned short)d;
        eidv[pos] = e;
    }
}

// ---------------- prep: 6x fp32 [k=128][n=128] -> bf16 [n][k] ----------------
__global__ __launch_bounds__(256) void k_prep_all(const float* __restrict__ Wg,
                                                  const float* __restrict__ W3,
                                                  const float* __restrict__ Wm1,
                                                  short* __restrict__ WbT6) {
    int i = blockIdx.x * 256 + threadIdx.x;   // 6*16384 total
    if (i >= 6 * 16384) return;
    int m = i >> 14;
    int r = i & 16383;
    int n = r >> 7, k = r & 127;
    const float* srcp;
    switch (m) {
        case 0: srcp = Wg; break;
        case 1: srcp = Wg + 16384; break;
        case 2: srcp = Wg + 32768; break;
        case 3: srcp = W3; break;
        case 4: srcp = Wm1; break;
        default: srcp = Wm1 + 16384; break;
    }
    WbT6[m * 16384 + n * 128 + k] = f2bf(srcp[k * 128 + n]);
}

// ---------------- prep: fused el/er weight tiles Wel[layer][16][128] ----------------
// el = (A@W)·al = A@(W@Aexp): Wel[n][k] = sum_d W[k][h*16+d]*a[h*16+d], h=n&7,
// a = al (n<8) or ar (n>=8). Layer 3 (H=1): n==0 -> W3·al3, n==1 -> W3·ar3, else 0.
__global__ __launch_bounds__(256) void k_prep_wela(const float* __restrict__ Wg,
                                                   const float* __restrict__ alg,
                                                   const float* __restrict__ arg_,
                                                   const float* __restrict__ W3,
                                                   const float* __restrict__ al3,
                                                   const float* __restrict__ ar3,
                                                   short* __restrict__ WelT) {
    int i = blockIdx.x * 256 + threadIdx.x;   // 4*16*128 = 8192 total
    if (i >= 4 * 2048) return;
    int layer = i >> 11;
    int r = i & 2047;
    int n = r >> 7, k = r & 127;
    float val = 0.f;
    if (layer < 3) {
        const float* W = Wg + layer * 16384;
        const float* a = (n < 8 ? alg : arg_) + layer * 128;
        int h = n & 7;
#pragma unroll
        for (int d = 0; d < 16; d++)
            val += W[k * 128 + h * 16 + d] * a[h * 16 + d];
    } else {
        if (n == 0) { for (int c = 0; c < 128; c++) val += W3[k * 128 + c] * al3[c]; }
        else if (n == 1) { for (int c = 0; c < 128; c++) val += W3[k * 128 + c] * ar3[c]; }
    }
    WelT[layer * 2048 + n * 128 + k] = f2bf(val);
}

// ---------------- prep: hi/lo bf16 splits of W_emb [128,128] and Wa [128,100] ----------------
// outputs transposed [n][k]; Wa zero-padded to n=128
__global__ __launch_bounds__(256) void k_prep_hilo(const float* __restrict__ W_emb,
                                                   const float* __restrict__ Wa,
                                                   short* __restrict__ WembT_hi,
                                                   short* __restrict__ WembT_lo,
                                                   short* __restrict__ WaT_hi,
                                                   short* __restrict__ WaT_lo) {
    int i = blockIdx.x * 256 + threadIdx.x;   // 2*16384 total
    if (i >= 2 * 16384) return;
    int m = i >> 14;
    int r = i & 16383;
    int n = r >> 7, k = r & 127;
    if (m == 0) {
        float w = W_emb[k * 128 + n];
        short h = f2bf(w);
        WembT_hi[n * 128 + k] = h;
        WembT_lo[n * 128 + k] = f2bf(w - bf2f(h));
    } else {
        float w = (n < 100) ? Wa[k * 100 + n] : 0.f;
        short h = f2bf(w);
        WaT_hi[n * 128 + k] = h;
        WaT_lo[n * 128 + k] = f2bf(w - bf2f(h));
    }
}

// ---------------- fp32-accurate MFMA GEMM via 3-term hi/lo split ----------------
__global__ __launch_bounds__(256) void k_mfma_hilo(const float* __restrict__ A,
                                                   const short* __restrict__ BT_hi,
                                                   const short* __restrict__ BT_lo,
                                                   const float* __restrict__ bias,
                                                   float* __restrict__ C, int ncols) {
    __shared__ short sAh[64 * 136];
    __shared__ short sAl[64 * 136];
    __shared__ short sBh[128 * 136];
    int t = threadIdx.x;
    int r0 = blockIdx.x * 64;
    // stage B_hi: each thread copies 64 bf16
    {
        int n = t >> 1;
        int k0 = (t & 1) * 64;
#pragma unroll
        for (int j = 0; j < 8; j++) {
            bf16x8 v = *(const bf16x8*)(BT_hi + n * 128 + k0 + 8 * j);
            *(bf16x8*)(sBh + n * 136 + k0 + 8 * j) = v;
        }
    }
    // stage A hi/lo: each thread converts 32 floats
    {
        int r = t >> 2;
        int k0 = (t & 3) * 32;
        const float* ar = A + (size_t)(r0 + r) * 128 + k0;
#pragma unroll
        for (int j = 0; j < 4; j++) {
            float4 f0 = *(const float4*)(ar + 8 * j);
            float4 f1 = *(const float4*)(ar + 8 * j + 4);
            float x[8] = {f0.x, f0.y, f0.z, f0.w, f1.x, f1.y, f1.z, f1.w};
            bf16x8 vh, vl;
#pragma unroll
            for (int q = 0; q < 8; q++) {
                short hh = f2bf(x[q]);
                vh[q] = hh;
                vl[q] = f2bf(x[q] - bf2f(hh));
            }
            *(bf16x8*)(sAh + r * 136 + k0 + 8 * j) = vh;
            *(bf16x8*)(sAl + r * 136 + k0 + 8 * j) = vl;
        }
    }
    __syncthreads();
    int lane = t & 63, wv = t >> 6;
    int lm = lane & 15, quad = lane >> 4;
    int m0 = wv * 16;
    bf16x8 aH[4], aL[4];
#pragma unroll
    for (int kt = 0; kt < 4; kt++) {
        aH[kt] = *(const bf16x8*)(sAh + (m0 + lm) * 136 + kt * 32 + quad * 8);
        aL[kt] = *(const bf16x8*)(sAl + (m0 + lm) * 136 + kt * 32 + quad * 8);
    }
#pragma unroll
    for (int nt = 0; nt < 8; nt++) {
        const short* blp = BT_lo + (nt * 16 + lm) * 128 + quad * 8;
        floatx4 acc = (floatx4){0.f, 0.f, 0.f, 0.f};
#pragma unroll
        for (int kt = 0; kt < 4; kt++) {
            bf16x8 bH = *(const bf16x8*)(sBh + (nt * 16 + lm) * 136 + kt * 32 + quad * 8);
            bf16x8 bL = *(const bf16x8*)(blp + kt * 32);
            acc = __builtin_amdgcn_mfma_f32_16x16x32_bf16(aH[kt], bH, acc, 0, 0, 0);
            acc = __builtin_amdgcn_mfma_f32_16x16x32_bf16(aL[kt], bH, acc, 0, 0, 0);
            acc = __builtin_amdgcn_mfma_f32_16x16x32_bf16(aH[kt], bL, acc, 0, 0, 0);
        }
        int col = nt * 16 + lm;
        if (col < ncols) {
            float bv = bias ? bias[col] : 0.f;
#pragma unroll
            for (int r = 0; r < 4; r++) {
                int row = r0 + m0 + quad * 4 + r;
                C[(size_t)row * ncols + col] = acc[r] + bv;
            }
        }
    }
}

// ---------------- MFMA GEMM: [N,128](fp32) @ WbT(bf16 [n][k]) -> bf16 out ----------------
// 64 rows/block, full N=128. A converted fp32->bf16 into LDS (+8 pad = 2-way bank, free).
// Optional fused el/er epilogue (r9) + BN prologue (r10) + second output (r13).
__global__ __launch_bounds__(256) void k_gemm_mfma(const float* __restrict__ A,
                                                   const short* __restrict__ WbT,
                                                   const float* __restrict__ bias,
                                                   short* __restrict__ C,
                                                   const short* __restrict__ WelT,
                                                   float* __restrict__ el,
                                                   float* __restrict__ er,
                                                   int H,
                                                   const float* __restrict__ bnx,
                                                   const float* __restrict__ bnh,
                                                   const float* __restrict__ csum,
                                                   const float* __restrict__ csq,
                                                   const float* __restrict__ bng,
                                                   const float* __restrict__ bnb,
                                                   float* __restrict__ hout,
                                                   int do_mask,
                                                   const short* __restrict__ WbT2,
                                                   short* __restrict__ C2) {
    __shared__ short sA[64 * 136];
    __shared__ short sB[128 * 136];
    __shared__ float sScale[128];
    __shared__ float sShift[128];
    int t = threadIdx.x;
    int r0 = blockIdx.x * 64;
    if (bnx) {
        if (t < 128) {
            const float invN = 1.f / (float)N_;
            float mu = csum[t] * invN;
            float var = csq[t] * invN - mu * mu;
            float inv = rsqrtf(var + 1e-5f);
            float sc = bng[t] * inv;
            sScale[t] = sc;
            sShift[t] = bnb[t] - mu * sc;
        }
        __syncthreads();
    }
    // stage B: each thread copies 64 bf16
    {
        int n = t >> 1;
        int k0 = (t & 1) * 64;
#pragma unroll
        for (int j = 0; j < 8; j++) {
            bf16x8 v = *(const bf16x8*)(WbT + n * 128 + k0 + 8 * j);
            *(bf16x8*)(sB + n * 136 + k0 + 8 * j) = v;
        }
    }
    // stage A: each thread handles 32 elements of one row-quarter
    {
        int r = t >> 2;
        int k0 = (t & 3) * 32;
        if (bnx) {
            const float* xr = bnx + (size_t)(r0 + r) * 128 + k0;
            const float* hr = bnh + (size_t)(r0 + r) * 128 + k0;
            float* ho = hout + (size_t)(r0 + r) * 128 + k0;
#pragma unroll
            for (int j = 0; j < 4; j++) {
                float4 x0 = *(const float4*)(xr + 8 * j);
                float4 x1 = *(const float4*)(xr + 8 * j + 4);
                float4 h0 = *(const float4*)(hr + 8 * j);
                float4 h1 = *(const float4*)(hr + 8 * j + 4);
                float xs[8] = {x0.x, x0.y, x0.z, x0.w, x1.x, x1.y, x1.z, x1.w};
                float hs[8] = {h0.x, h0.y, h0.z, h0.w, h1.x, h1.y, h1.z, h1.w};
                float ov[8];
                bf16x8 v;
#pragma unroll
                for (int q = 0; q < 8; q++) {
                    int c = k0 + 8 * j + q;
                    float y = sScale[c] * xs[q] + sShift[c];
                    y = y > 0.f ? y : (__expf(y) - 1.f);
                    float hv = hs[q] + y;
                    if (do_mask && isinf(hv)) hv = 1e9f;
                    ov[q] = hv;
                    v[q] = f2bf(hv);
                }
                *(float4*)(ho + 8 * j) = make_float4(ov[0], ov[1], ov[2], ov[3]);
                *(float4*)(ho + 8 * j + 4) = make_float4(ov[4], ov[5], ov[6], ov[7]);
                *(bf16x8*)(sA + r * 136 + k0 + 8 * j) = v;
            }
        } else {
            const float* ar = A + (size_t)(r0 + r) * 128 + k0;
#pragma unroll
            for (int j = 0; j < 4; j++) {
                float4 f0 = *(const float4*)(ar + 8 * j);
                float4 f1 = *(const float4*)(ar + 8 * j + 4);
                bf16x8 v;
                v[0] = f2bf(f0.x); v[1] = f2bf(f0.y); v[2] = f2bf(f0.z); v[3] = f2bf(f0.w);
                v[4] = f2bf(f1.x); v[5] = f2bf(f1.y); v[6] = f2bf(f1.z); v[7] = f2bf(f1.w);
                *(bf16x8*)(sA + r * 136 + k0 + 8 * j) = v;
            }
        }
    }
    __syncthreads();
    int lane = t & 63, wv = t >> 6;
    int lm = lane & 15, quad = lane >> 4;
    int m0 = wv * 16;
    bf16x8 aF[4];
#pragma unroll
    for (int kt = 0; kt < 4; kt++)
        aF[kt] = *(const bf16x8*)(sA + (m0 + lm) * 136 + kt * 32 + quad * 8);
#pragma unroll
    for (int nt = 0; nt < 8; nt++) {
        floatx4 acc = (floatx4){0.f, 0.f, 0.f, 0.f};
#pragma unroll
        for (int kt = 0; kt < 4; kt++) {
            bf16x8 bF = *(const bf16x8*)(sB + (nt * 16 + lm) * 136 + kt * 32 + quad * 8);
            acc = __builtin_amdgcn_mfma_f32_16x16x32_bf16(aF[kt], bF, acc, 0, 0, 0);
        }
        int col = nt * 16 + lm;
        float bv = bias ? bias[col] : 0.f;
#pragma unroll
        for (int r = 0; r < 4; r++) {
            int row = r0 + m0 + quad * 4 + r;
            C[(size_t)row * 128 + col] = f2bf(acc[r] + bv);
        }
    }
    // fused el/er tile: cols 0..7 = el heads, 8..15 = er heads (H=1: col0=el, col1=er)
    if (WelT) {
        floatx4 acc = (floatx4){0.f, 0.f, 0.f, 0.f};
#pragma unroll
        for (int kt = 0; kt < 4; kt++) {
            bf16x8 wF = *(const bf16x8*)(WelT + lm * 128 + kt * 32 + quad * 8);
            acc = __builtin_amdgcn_mfma_f32_16x16x32_bf16(aF[kt], wF, acc, 0, 0, 0);
        }
        if (H == 8) {
#pragma unroll
            for (int r = 0; r < 4; r++) {
                int row = r0 + m0 + quad * 4 + r;
                if (lm < 8) el[(size_t)row * 8 + lm] = acc[r];
                else        er[(size_t)row * 8 + (lm - 8)] = acc[r];
            }
        } else {
#pragma unroll
            for (int r = 0; r < 4; r++) {
                int row = r0 + m0 + quad * 4 + r;
                if (lm == 0) el[row] = acc[r];
                if (lm == 1) er[row] = acc[r];
            }
        }
    }
    // second output: re-stage sB, recompute with same aF (Pb/Qb merge)
    if (WbT2) {
        __syncthreads();   // all compute reads of sB complete
        {
            int n = t >> 1;
            int k0 = (t & 1) * 64;
#pragma unroll
            for (int j = 0; j < 8; j++) {
                bf16x8 v = *(const bf16x8*)(WbT2 + n * 128 + k0 + 8 * j);
                *(bf16x8*)(sB + n * 136 + k0 + 8 * j) = v;
            }
        }
        __syncthreads();
#pragma unroll
        for (int nt = 0; nt < 8; nt++) {
            floatx4 acc = (floatx4){0.f, 0.f, 0.f, 0.f};
#pragma unroll
            for (int kt = 0; kt < 4; kt++) {
                bf16x8 bF = *(const bf16x8*)(sB + (nt * 16 + lm) * 136 + kt * 32 + quad * 8);
                acc = __builtin_amdgcn_mfma_f32_16x16x32_bf16(aF[kt], bF, acc, 0, 0, 0);
            }
            int col = nt * 16 + lm;
#pragma unroll
            for (int r = 0; r < 4; r++) {
                int row = r0 + m0 + quad * 4 + r;
                C2[(size_t)row * 128 + col] = f2bf(acc[r]);
            }
        }
    }
}

// ---------------- softmax over 100 logits, wave per node, barrier-free ----------------
__global__ __launch_bounds__(256) void k_smax100(const float* __restrict__ logits,
                                                 float* __restrict__ s) {
    int lane = threadIdx.x & 63;
    int n = blockIdx.x * 4 + (threadIdx.x >> 6);
    if (n >= N_) return;
    bool act = lane < 50;
    float2 v = make_float2(-INFINITY, -INFINITY);
    if (act) v = *(const float2*)(logits + (size_t)n * 100 + 2 * lane);
    float mx = fmaxf(v.x, v.y);
#pragma unroll
    for (int off = 1; off < 64; off <<= 1) mx = fmaxf(mx, __shfl_xor(mx, off));
    float e0 = act ? __expf(v.x - mx) : 0.f;
    float e1 = act ? __expf(v.y - mx) : 0.f;
    float sm = e0 + e1;
#pragma unroll
    for (int off = 1; off < 64; off <<= 1) sm += __shfl_xor(sm, off);
    float inv = 1.f / sm;
    if (act) *(float2*)(s + (size_t)n * 100 + 2 * lane) = make_float2(e0 * inv, e1 * inv);
}

// ---------------- GAT edge-softmax + aggregate (wave per dst node, bf16 feat) ----------------
// v7: SINGLE-PASS flash-style online softmax-aggregate. Pass 1 + butterfly DELETED.
// The proven pass-2 memory structure (chunk-8 x2 interleave, batch prefetch, shfl
// distribution) is preserved byte-for-byte; computing lanes shfl the raw logit lr
// instead of the exp'd weight, and each consumer lane keeps running (m, ss, acc2)
// with rescale-on-new-max, normalizing at the end. Masked tail edges: lr=-INF -> w=0.
// VALU is free in this regime (r3: VALUBusy 51->33% with zero time change); this
// trades exp count for deleting a full gather pass per node.
// BN stats epilogue: per-block coalesced partials (r12, NO atomics).
template <int H>
__global__ __launch_bounds__(256) void k_gat_agg(const short* __restrict__ feat,
                                                 const float* __restrict__ el,
                                                 const float* __restrict__ er,
                                                 const int* __restrict__ rowptr,
                                                 const int* __restrict__ srcv,
                                                 const float* __restrict__ bias,
                                                 float* __restrict__ xout,
                                                 float* __restrict__ psum,
                                                 float* __restrict__ psq) {
    int t = threadIdx.x;
    int lane = t & 63;
    int gw = (blockIdx.x * blockDim.x + t) >> 6;
    int nw = (gridDim.x * blockDim.x) >> 6;
    int h = lane & (H - 1);
    int f0 = 2 * lane;
    int hf = (H == 8) ? (lane >> 3) : 0;   // head owning this lane's feature slice

    float stx = 0.f, sty = 0.f, qtx = 0.f, qty = 0.f;  // fused BN stats

    for (int n = gw; n < N_; n += nw) {
        int beg = rowptr[n], end = rowptr[n + 1];
        if (beg == end) {
            float2 b2 = *(const float2*)(bias + f0);
            *(float2*)(xout + (size_t)n * 128 + f0) = b2;
            stx += b2.x; sty += b2.y;
            qtx += b2.x * b2.x; qty += b2.y * b2.y;
            continue;
        }
        float ern = er[(size_t)n * H + h];
        int endm1 = end - 1;
        float m = -INFINITY, ss = 0.f;
        float accx = 0.f, accy = 0.f;
        for (int e0 = beg; e0 < end; e0 += 16) {
            int le = lane >> 3;
            int eLA = e0 + le, eLB = e0 + 8 + le;
            int eCA = eLA <= endm1 ? eLA : endm1;
            int eCB = eLB <= endm1 ? eLB : endm1;
            int sLA = srcv[eCA];
            int sLB = srcv[eCB];
            float xA = el[(size_t)sLA * H + h] + ern;
            float xB = el[(size_t)sLB * H + h] + ern;
            float lrA = xA > 0.f ? xA : 0.2f * xA;
            float lrB = xB > 0.f ? xB : 0.2f * xB;
            if (eLA > endm1) lrA = -INFINITY;
            if (eLB > endm1) lrB = -INFINITY;
            bool haveB = (e0 + 8) < end;    // wave-uniform
            unsigned int uuA[8], uuB[8];
#pragma unroll
            for (int j = 0; j < 8; j++) {
                int sj = __builtin_amdgcn_readlane(sLA, j * 8);
                uuA[j] = *(const unsigned int*)(feat + (size_t)sj * 128 + f0);
            }
            if (haveB) {
#pragma unroll
                for (int j = 0; j < 8; j++) {
                    int sj = __builtin_amdgcn_readlane(sLB, j * 8);
                    uuB[j] = *(const unsigned int*)(feat + (size_t)sj * 128 + f0);
                }
            }
#pragma unroll
            for (int j = 0; j < 8; j++) {
                float lj;
                if (H == 8) lj = __shfl(lrA, j * 8 + hf);
                else        lj = rdlane(lrA, j * 8);
                if (lj > m) {
                    float r = __expf(m - lj);   // m=-INF first time -> r=0 (acc,ss are 0)
                    accx *= r; accy *= r; ss *= r; m = lj;
                }
                float w = __expf(lj - m);       // lj=-INF (masked) -> w=0
                accx += w * bflo(uuA[j]);
                accy += w * bfhi(uuA[j]);
                ss += w;
            }
            if (haveB) {
#pragma unroll
                for (int j = 0; j < 8; j++) {
                    float lj;
                    if (H == 8) lj = __shfl(lrB, j * 8 + hf);
                    else        lj = rdlane(lrB, j * 8);
                    if (lj > m) {
                        float r = __expf(m - lj);
                        accx *= r; accy *= r; ss *= r; m = lj;
                    }
                    float w = __expf(lj - m);
                    accx += w * bflo(uuB[j]);
                    accy += w * bfhi(uuB[j]);
                    ss += w;
                }
            }
        }
        float inv_d = 1.f / ss;
        float2 b2 = *(const float2*)(bias + f0);
        float ox = accx * inv_d + b2.x, oy = accy * inv_d + b2.y;
        *(float2*)(xout + (size_t)n * 128 + f0) = make_float2(ox, oy);
        stx += ox; sty += oy;
        qtx += ox * ox; qty += oy * oy;
    }

    // ---- per-block partial stats: LDS reduce across 4 waves, coalesced plain store ----
    __shared__ float red[4][256];
    red[0][t] = stx; red[1][t] = sty; red[2][t] = qtx; red[3][t] = qty;
    __syncthreads();
    if (t < 64) {
        float a0 = red[0][t] + red[0][t + 64] + red[0][t + 128] + red[0][t + 192];
        float a1 = red[1][t] + red[1][t + 64] + red[1][t + 128] + red[1][t + 192];
        float q0 = red[2][t] + red[2][t + 64] + red[2][t + 128] + red[2][t + 192];
        float q1 = red[3][t] + red[3][t + 64] + red[3][t + 128] + red[3][t + 192];
        *(float2*)(psum + (size_t)blockIdx.x * 128 + 2 * t) = make_float2(a0, a1);
        *(float2*)(psq + (size_t)blockIdx.x * 128 + 2 * t) = make_float2(q0, q1);
    }
}

// ---------------- reduce per-block stats partials -> colsum/colsq ----------------
__global__ __launch_bounds__(256) void k_stats_reduce(const float* __restrict__ psum,
                                                      const float* __restrict__ psq,
                                                      float* __restrict__ colsum,
                                                      float* __restrict__ colsq) {
    __shared__ float ls[256], lq[256];
    int t = threadIdx.x;
    int col = t & 127, half = t >> 7;
    float s = 0.f, q = 0.f;
    for (int b = blockIdx.x * 2 + half; b < AGGB_; b += gridDim.x * 2) {
        s += psum[(size_t)b * 128 + col];
        q += psq[(size_t)b * 128 + col];
    }
    ls[t] = s; lq[t] = q;
    __syncthreads();
    if (t < 128) {
        atomicAdd(&colsum[col], ls[t] + ls[t + 128]);
        atomicAdd(&colsq[col], lq[t] + lq[t + 128]);
    }
}

// ---------------- BN apply + ELU + residual (+mask) — layer-1 only ----------------
__global__ __launch_bounds__(256) void k_bn_apply(const float* __restrict__ x,
                                                  const float* __restrict__ hprev,
                                                  const float* __restrict__ sum,
                                                  const float* __restrict__ sumsq,
                                                  const float* __restrict__ g,
                                                  const float* __restrict__ b,
                                                  float* __restrict__ out, int do_mask) {
    int i = blockIdx.x * blockDim.x + threadIdx.x;
    if (i >= N_ * 128) return;
    int c = i & 127;
    const float invN = 1.f / (float)N_;
    float mu = sum[c] * invN;
    float var = sumsq[c] * invN - mu * mu;
    float inv = rsqrtf(var + 1e-5f);
    float y = g[c] * (x[i] - mu) * inv + b[c];
    y = y > 0.f ? y : (__expf(y) - 1.f);
    float hv = hprev[i] + y;
    if (do_mask && isinf(hv)) hv = 1e9f;
    out[i] = hv;
}

// ---------------- h_coarse partials ----------------
__global__ __launch_bounds__(512) void k_coarse_part(const float* __restrict__ s,
                                                     const float* __restrict__ hf,
                                                     float* __restrict__ part) {
    int t = threadIdx.x;
    int c = t & 127;
    int g = t >> 7;        // 0..3
    int lane = t & 63;
    float acc[25];
#pragma unroll
    for (int a = 0; a < 25; a++) acc[a] = 0.f;
    int n0 = blockIdx.x * CR_;
    for (int n = n0; n < n0 + CR_; n += 2) {
        float hv0 = hf[(size_t)n * 128 + c];
        float hv1 = hf[(size_t)(n + 1) * 128 + c];
        float sv0 = 0.f, sv1 = 0.f;
        if (lane < 25) {
            sv0 = s[(size_t)n * 100 + 25 * g + lane];
            sv1 = s[(size_t)(n + 1) * 100 + 25 * g + lane];
        }
#pragma unroll
        for (int a = 0; a < 25; ++a) {
            float a0 = rdlane(sv0, a);
            float a1 = rdlane(sv1, a);
            acc[a] += a0 * hv0 + a1 * hv1;
        }
    }
    float* dstp = part + (size_t)blockIdx.x * 12800 + (size_t)(25 * g) * 128 + c;
#pragma unroll
    for (int a = 0; a < 25; a++) dstp[a * 128] = acc[a];
}

// ---------------- reduce partials -> hc[100][128] ----------------
__global__ __launch_bounds__(256) void k_coarse_reduce(const float* __restrict__ part,
                                                       float* __restrict__ hc) {
    int i = blockIdx.x * blockDim.x + threadIdx.x;  // 12800 total
    if (i >= 12800) return;
    float s0 = 0.f, s1 = 0.f, s2 = 0.f, s3 = 0.f;
    for (int b = 0; b < CB_; b += 4) {
        s0 += part[(size_t)(b + 0) * 12800 + i];
        s1 += part[(size_t)(b + 1) * 12800 + i];
        s2 += part[(size_t)(b + 2) * 12800 + i];
        s3 += part[(size_t)(b + 3) * 12800 + i];
    }
    hc[i] = (s0 + s1) + (s2 + s3);
}

// ---------------- h = mask(0.5*h_fine + 0.5*(s@h_coarse)) ----------------
__global__ __launch_bounds__(256) void k_combine(const float* __restrict__ s,
                                                 const float* __restrict__ hc,
                                                 const float* __restrict__ hfine,
                                                 float* __restrict__ hout) {
    __shared__ float ssh[16 * 100];
    int t = threadIdx.x;
    int n0 = blockIdx.x * 16;
    for (int u = t; u < 1600; u += 256) ssh[u] = s[(size_t)n0 * 100 + u];
    __syncthreads();
    int c = t & 127, g = t >> 7;
    float acc[8];
#pragma unroll
    for (int r = 0; r < 8; r++) acc[r] = 0.f;
    const float* hcp = hc + c;
    for (int a = 0; a < 100; a += 4) {
        float h0 = hcp[(a + 0) * 128];
        float h1 = hcp[(a + 1) * 128];
        float h2 = hcp[(a + 2) * 128];
        float h3 = hcp[(a + 3) * 128];
#pragma unroll
        for (int r = 0; r < 8; r++) {
            float4 sv = *(const float4*)(ssh + (g * 8 + r) * 100 + a);
            acc[r] += sv.x * h0 + sv.y * h1 + sv.z * h2 + sv.w * h3;
        }
    }
#pragma unroll
    for (int r = 0; r < 8; r++) {
        int row = n0 + g * 8 + r;
        float v = 0.5f * hfine[(size_t)row * 128 + c] + 0.5f * acc[r];
        if (isinf(v)) v = 1e9f;
        hout[(size_t)row * 128 + c] = v;
    }
}

// ---------------- prep: Wm2 [128][64] fp32 -> Wm2T bf16 [64][128] ----------------
__global__ __launch_bounds__(256) void k_prep_w(const float* __restrict__ Wm2,
                                                short* __restrict__ Wm2T) {
    int i = blockIdx.x * blockDim.x + threadIdx.x;  // 8192 total
    if (i >= 64 * 128) return;
    int n = i & 63, k = i >> 6;
    Wm2T[n * 128 + k] = f2bf(Wm2[k * 64 + n]);
}

// ---------------- edge MLP readout: dst-sorted order, barrier-free persistent MFMA ----------------
// v2 — LOCAL OPTIMUM at ~54us, VGPR 84. Do not register-diet (v3: spills, 3x dur).
// Do not 2-tile (v4: compiler serializes the B-tile loads, occupancy drops, +6us).
__global__ __launch_bounds__(256) void k_edge_mlp3(const short* __restrict__ Pb,
                                                   const short* __restrict__ Qb,
                                                   const int* __restrict__ srcv,
                                                   const unsigned short* __restrict__ dstv,
                                                   const int* __restrict__ eidv,
                                                   const short* __restrict__ Wm2T,
                                                   const float* __restrict__ bm2,
                                                   const float* __restrict__ Wm3,
                                                   const float* __restrict__ bm3,
                                                   float* __restrict__ zout) {
    __shared__ short sW[64 * 128];  // 16 KiB
    int t = threadIdx.x;
    // stage Wm2T -> LDS with 16B-unit XOR swizzle: phys_unit = n*16 + (k16 ^ (n&15))
    for (int u = t; u < 1024; u += 256) {
        int n = u >> 4, k16 = u & 15;
        int phys = (n << 4) | (k16 ^ (n & 15));
        *(bf16x8*)(sW + phys * 8) = *(const bf16x8*)(Wm2T + n * 128 + k16 * 8);
    }
    int lane = t & 63;
    int lm = lane & 15, quad = lane >> 4;
    float bv[4], w30[4], w31[4];
#pragma unroll
    for (int nt = 0; nt < 4; nt++) {
        int n = nt * 16 + lm;
        bv[nt] = bm2[n]; w30[nt] = Wm3[2 * n]; w31[nt] = Wm3[2 * n + 1];
    }
    float b30 = bm3[0], b31 = bm3[1];
    __syncthreads();

    int gw = (blockIdx.x * blockDim.x + t) >> 6;
    int nw = (gridDim.x * blockDim.x) >> 6;

    for (int tile = gw; tile < E_ / 16; tile += nw) {
        int p0 = tile * 16;
        int sI = srcv[p0 + lm];
        int dI = (int)dstv[p0 + lm];
        const short* pr = Pb + (size_t)sI * 128 + quad * 8;
        const short* qr = Qb + (size_t)dI * 128 + quad * 8;
        // issue all 8 gathers up-front (latency hidden within wave)
        uint4 pu[4], qu[4];
#pragma unroll
        for (int kt = 0; kt < 4; kt++) {
            pu[kt] = *(const uint4*)(pr + kt * 32);
            qu[kt] = *(const uint4*)(qr + kt * 32);
        }
        bf16x8 aF[4];
#pragma unroll
        for (int kt = 0; kt < 4; kt++) {
            unsigned int pv[4] = {pu[kt].x, pu[kt].y, pu[kt].z, pu[kt].w};
            unsigned int qv[4] = {qu[kt].x, qu[kt].y, qu[kt].z, qu[kt].w};
            union { uint4 u; bf16x8 v; } cv;
            unsigned int rr[4];
#pragma unroll
            for (int j = 0; j < 4; j++) {
                float fl = fmaxf(bflo(pv[j]) + bflo(qv[j]), 0.f);
                float fh = fmaxf(bfhi(pv[j]) + bfhi(qv[j]), 0.f);
                rr[j] = (unsigned int)(unsigned short)f2bf(fl) |
                        ((unsigned int)(unsigned short)f2bf(fh) << 16);
            }
            cv.u.x = rr[0]; cv.u.y = rr[1]; cv.u.z = rr[2]; cv.u.w = rr[3];
            aF[kt] = cv.v;
        }
        float pz0[4] = {0.f, 0.f, 0.f, 0.f};
        float pz1[4] = {0.f, 0.f, 0.f, 0.f};
#pragma unroll
        for (int nt = 0; nt < 4; nt++) {
            floatx4 acc = (floatx4){0.f, 0.f, 0.f, 0.f};
#pragma unroll
            for (int kt = 0; kt < 4; kt++) {
                int phys = ((nt * 16 + lm) << 4) | (((kt << 2) | quad) ^ lm);
                bf16x8 bF = *(const bf16x8*)(sW + phys * 8);
                acc = __builtin_amdgcn_mfma_f32_16x16x32_bf16(aF[kt], bF, acc, 0, 0, 0);
            }
#pragma unroll
            for (int r = 0; r < 4; r++) {
                float u = fmaxf(acc[r] + bv[nt], 0.f);
                pz0[r] += u * w30[nt];
                pz1[r] += u * w31[nt];
            }
        }
#pragma unroll
        for (int off = 1; off < 16; off <<= 1) {
#pragma unroll
            for (int r = 0; r < 4; r++) {
                pz0[r] += __shfl_xor(pz0[r], off);
                pz1[r] += __shfl_xor(pz1[r], off);
            }
        }
        if (lm < 4) {
            int eid = eidv[p0 + quad * 4 + lm];
            float z0 = pz0[lm] + b30;
            float z1 = pz1[lm] + b31;
            if (isinf(z0)) z0 = 1e9f;
            if (isinf(z1)) z1 = 1e9f;
            *(float2*)(zout + (size_t)eid * 2) = make_float2(z0, z1);
        }
    }
}

extern "C" void kernel_launch(void* const* d_in, const int* in_sizes, int n_in,
                              void* d_out, int out_size, void* d_ws, size_t ws_size,
                              hipStream_t stream) {
    const float* h_in  = (const float*)d_in[0];
    const int*   src   = (const int*)d_in[2];
    const int*   dst   = (const int*)d_in[3];
    const float* W_emb = (const float*)d_in[4];
    const float* b_emb = (const float*)d_in[5];
    const float* Wg    = (const float*)d_in[6];
    const float* alg   = (const float*)d_in[7];
    const float* arg_  = (const float*)d_in[8];
    const float* bg    = (const float*)d_in[9];
    const float* gam   = (const float*)d_in[10];
    const float* bet   = (const float*)d_in[11];
    const float* W3    = (const float*)d_in[12];
    const float* al3   = (const float*)d_in[13];
    const float* ar3   = (const float*)d_in[14];
    const float* b3    = (const float*)d_in[15];
    const float* gam3  = (const float*)d_in[16];
    const float* bet3  = (const float*)d_in[17];
    const float* Wa    = (const float*)d_in[18];
    const float* ba    = (const float*)d_in[19];
    const float* Wm1   = (const float*)d_in[20];
    const float* bm1   = (const float*)d_in[21];
    const float* Wm2   = (const float*)d_in[22];
    const float* bm2   = (const float*)d_in[23];
    const float* Wm3   = (const float*)d_in[24];
    const float* bm3   = (const float*)d_in[25];

    float* zout = (float*)d_out;
    float* sout = zout + (size_t)E_ * 2;

    float* ws = (float*)d_ws;
    size_t o = 0;
    float* h_cur = ws + o; o += (size_t)N_ * 128;
    float* xbuf  = ws + o; o += (size_t)N_ * 128;
    float* featb = ws + o; o += (size_t)N_ * 128;   // reused: bf16 feat, coarse partials, bf16 P/Q
    float* el    = ws + o; o += (size_t)N_ * 8;
    float* er    = ws + o; o += (size_t)N_ * 8;
    float* colsum = ws + o; o += 128;
    float* colsq  = ws + o; o += 128;
    float* hc     = ws + o; o += 100 * 128;
    float* psum   = ws + o; o += (size_t)AGGB_ * 128;
    float* psq    = ws + o; o += (size_t)AGGB_ * 128;
    short* Wm2T = (short*)(ws + o); o += (64 * 128) / 2;
    short* WbT6 = (short*)(ws + o); o += (6 * 16384) / 2;
    short* WelT = (short*)(ws + o); o += (4 * 2048) / 2;
    short* WembT_hi = (short*)(ws + o); o += 16384 / 2;
    short* WembT_lo = (short*)(ws + o); o += 16384 / 2;
    short* WaT_hi   = (short*)(ws + o); o += 16384 / 2;
    short* WaT_lo   = (short*)(ws + o); o += 16384 / 2;
    int* counts = (int*)(ws + o); o += N_;
    int* rowptr = (int*)(ws + o); o += N_ + 4;
    int* cursor = (int*)(ws + o); o += N_;
    int* srcv   = (int*)(ws + o); o += E_;
    unsigned short* dstv = (unsigned short*)(ws + o); o += E_ / 2;
    int* eidv   = (int*)(ws + o); o += E_;
    int* bsum   = (int*)(ws + o); o += SNB_ + 4;

    short* featw = (short*)featb;  // bf16 per-layer projection

    // ---- CSR build (parallel scan; excl scratch reuses eidv pre-fill) ----
    hipMemsetAsync(counts, 0, N_ * sizeof(int), stream);
    k_count<<<1024, 256, 0, stream>>>(dst, counts);
    k_scanA<<<SNB_, 256, 0, stream>>>(counts, eidv, bsum);
    k_scanB<<<1, 256, 0, stream>>>(bsum);
    k_scanC<<<SNB_ + 1, 256, 0, stream>>>(eidv, bsum, rowptr, cursor);
    k_fill<<<1024, 256, 0, stream>>>(src, dst, cursor, srcv, dstv, eidv);
    k_prep_w<<<32, 256, 0, stream>>>(Wm2, Wm2T);
    k_prep_all<<<384, 256, 0, stream>>>(Wg, W3, Wm1, WbT6);
    k_prep_wela<<<32, 256, 0, stream>>>(Wg, alg, arg_, W3, al3, ar3, WelT);
    k_prep_hilo<<<128, 256, 0, stream>>>(W_emb, Wa, WembT_hi, WembT_lo, WaT_hi, WaT_lo);

    // ---- embedding (fp32-accurate via hi/lo MFMA) ----
    k_mfma_hilo<<<N_ / 64, 256, 0, stream>>>(h_in, WembT_hi, WembT_lo, b_emb, h_cur, 128);

    // ---- layer 0 (H=8) ----
    k_gemm_mfma<<<N_ / 64, 256, 0, stream>>>(h_cur, WbT6 + 0 * 16384, nullptr, featw,
                                             WelT + 0 * 2048, el, er, 8,
                                             nullptr, nullptr, nullptr, nullptr,
                                             nullptr, nullptr, nullptr, 0,
                                             nullptr, nullptr);
    hipMemsetAsync(colsum, 0, 256 * sizeof(float), stream);
    k_gat_agg<8><<<AGGB_, 256, 0, stream>>>(featw, el, er, rowptr, srcv, bg + 0 * 128, xbuf,
                                            psum, psq);
    k_stats_reduce<<<64, 256, 0, stream>>>(psum, psq, colsum, colsq);

    // ---- layer 1 (biGAT, H=8): gemm fused with layer-0 BN (writes h_cur) ----
    k_gemm_mfma<<<N_ / 64, 256, 0, stream>>>(nullptr, WbT6 + 1 * 16384, nullptr, featw,
                                             WelT + 1 * 2048, el, er, 8,
                                             xbuf, h_cur, colsum, colsq,
                                             gam + 0 * 128, bet + 0 * 128, h_cur, 1,
                                             nullptr, nullptr);
    k_mfma_hilo<<<N_ / 64, 256, 0, stream>>>(h_cur, WaT_hi, WaT_lo, ba, xbuf, 100);
    k_smax100<<<N_ / 4, 256, 0, stream>>>(xbuf, sout);
    hipMemsetAsync(colsum, 0, 256 * sizeof(float), stream);
    k_gat_agg<8><<<AGGB_, 256, 0, stream>>>(featw, el, er, rowptr, srcv, bg + 1 * 128, xbuf,
                                            psum, psq);
    k_stats_reduce<<<64, 256, 0, stream>>>(psum, psq, colsum, colsq);
    k_bn_apply<<<(N_ * 128) / 256, 256, 0, stream>>>(xbuf, h_cur, colsum, colsq,
                                                     gam + 1 * 128, bet + 1 * 128, xbuf, 0);
    k_coarse_part<<<CB_, 512, 0, stream>>>(sout, xbuf, featb);
    k_coarse_reduce<<<50, 256, 0, stream>>>(featb, hc);
    k_combine<<<N_ / 16, 256, 0, stream>>>(sout, hc, xbuf, h_cur);

    // ---- layer 2 (H=8) ----
    k_gemm_mfma<<<N_ / 64, 256, 0, stream>>>(h_cur, WbT6 + 2 * 16384, nullptr, featw,
                                             WelT + 2 * 2048, el, er, 8,
                                             nullptr, nullptr, nullptr, nullptr,
                                             nullptr, nullptr, nullptr, 0,
                                             nullptr, nullptr);
    hipMemsetAsync(colsum, 0, 256 * sizeof(float), stream);
    k_gat_agg<8><<<AGGB_, 256, 0, stream>>>(featw, el, er, rowptr, srcv, bg + 2 * 128, xbuf,
                                            psum, psq);
    k_stats_reduce<<<64, 256, 0, stream>>>(psum, psq, colsum, colsq);

    // ---- layer 3 (H=1): gemm fused with layer-2 BN (writes h_cur) ----
    k_gemm_mfma<<<N_ / 64, 256, 0, stream>>>(nullptr, WbT6 + 3 * 16384, nullptr, featw,
                                             WelT + 3 * 2048, el, er, 1,
                                             xbuf, h_cur, colsum, colsq,
                                             gam + 2 * 128, bet + 2 * 128, h_cur, 1,
                                             nullptr, nullptr);
    hipMemsetAsync(colsum, 0, 256 * sizeof(float), stream);
    k_gat_agg<1><<<AGGB_, 256, 0, stream>>>(featw, el, er, rowptr, srcv, b3, xbuf,
                                            psum, psq);
    k_stats_reduce<<<64, 256, 0, stream>>>(psum, psq, colsum, colsq);

    // ---- edge MLP readout: ONE gemm (layer-3 BN fused) producing BOTH Pb and Qb ----
    short* Pb = (short*)featb;
    short* Qb = Pb + (size_t)N_ * 128;
    k_gemm_mfma<<<N_ / 64, 256, 0, stream>>>(nullptr, WbT6 + 4 * 16384, bm1, Pb,
                                             nullptr, nullptr, nullptr, 0,
                                             xbuf, h_cur, colsum, colsq,
                                             gam3, bet3, h_cur, 1,
                                             WbT6 + 5 * 16384, Qb);
    k_edge_mlp3<<<2048, 256, 0, stream>>>(Pb, Qb, srcv, dstv, eidv, Wm2T, bm2, Wm3, bm3, zout);
}

// Round 15
// 722.113 us; speedup vs baseline: 1.1299x; 1.0099x over previous
//
#include <hip/hip_runtime.h>
#include <hip/hip_bf16.h>
#include <math.h>

#define N_ 40000
#define E_ 640000
#define CB_ 400   // k_coarse partial blocks
#define CR_ 100   // rows per block (CB_*CR_ == N_)
#define SB_ 256
#define SNB_ 157  // ceil(N_/SB_)
#define AGGB_ 2048  // k_gat_agg grid (blocks); psum/psq sized to this

typedef short bf16x8 __attribute__((ext_vector_type(8)));
typedef float floatx4 __attribute__((ext_vector_type(4)));

__device__ __forceinline__ short f2bf(float f) {
    __hip_bfloat16 h = __float2bfloat16(f);
    return *reinterpret_cast<short*>(&h);
}
__device__ __forceinline__ float bf2f(short u) {
    unsigned int x = ((unsigned int)(unsigned short)u) << 16;
    return __int_as_float(x);
}
__device__ __forceinline__ float rdlane(float v, int l) {
    return __int_as_float(__builtin_amdgcn_readlane(__float_as_int(v), l));
}
// unpack 2 bf16 packed in a uint
__device__ __forceinline__ float bflo(unsigned int u) { return __int_as_float(u << 16); }
__device__ __forceinline__ float bfhi(unsigned int u) { return __int_as_float(u & 0xffff0000u); }

// ---------------- CSR build ----------------
__global__ void k_count(const int* __restrict__ dst, int* __restrict__ counts) {
    for (int e = blockIdx.x * blockDim.x + threadIdx.x; e < E_; e += gridDim.x * blockDim.x)
        atomicAdd(&counts[dst[e]], 1);
}

// ---- 3-phase parallel scan ----
__global__ __launch_bounds__(256) void k_scanA(const int* __restrict__ counts,
                                               int* __restrict__ excl,
                                               int* __restrict__ bsum) {
    int t = threadIdx.x;
    int i = blockIdx.x * SB_ + t;
    int v = (i < N_) ? counts[i] : 0;
    int lane = t & 63, wv = t >> 6;
    int x = v;
#pragma unroll
    for (int off = 1; off < 64; off <<= 1) {
        int y = __shfl_up(x, off);
        if (lane >= off) x += y;
    }
    __shared__ int wsum[4];
    __shared__ int woff[4];
    if (lane == 63) wsum[wv] = x;
    __syncthreads();
    if (t == 0) {
        int a = 0;
#pragma unroll
        for (int j = 0; j < 4; j++) { int tv = wsum[j]; woff[j] = a; a += tv; }
        bsum[blockIdx.x] = a;
    }
    __syncthreads();
    if (i < N_) excl[i] = x - v + woff[wv];
}

__global__ __launch_bounds__(256) void k_scanB(int* __restrict__ bsum) {
    int t = threadIdx.x;
    int v = (t < SNB_) ? bsum[t] : 0;
    int lane = t & 63, wv = t >> 6;
    int x = v;
#pragma unroll
    for (int off = 1; off < 64; off <<= 1) {
        int y = __shfl_up(x, off);
        if (lane >= off) x += y;
    }
    __shared__ int wsum[4];
    __shared__ int woff[4];
    if (lane == 63) wsum[wv] = x;
    __syncthreads();
    if (t == 0) {
        int a = 0;
#pragma unroll
        for (int j = 0; j < 4; j++) { int tv = wsum[j]; woff[j] = a; a += tv; }
    }
    __syncthreads();
    if (t < SNB_) bsum[t] = x - v + woff[wv];
}

__global__ __launch_bounds__(256) void k_scanC(const int* __restrict__ excl,
                                               const int* __restrict__ bsum,
                                               int* __restrict__ rowptr,
                                               int* __restrict__ cursor) {
    int i = blockIdx.x * 256 + threadIdx.x;
    if (i < N_) {
        int r = excl[i] + bsum[i / SB_];
        rowptr[i] = r;
        cursor[i] = r;
    }
    if (i == N_) rowptr[N_] = E_;
}

__global__ void k_fill(const int* __restrict__ src, const int* __restrict__ dst,
                       int* __restrict__ cursor, int* __restrict__ srcv,
                       unsigned short* __restrict__ dstv, int* __restrict__ eidv) {
    for (int e = blockIdx.x * blockDim.x + threadIdx.x; e < E_; e += gridDim.x * blockDim.x) {
        int d = dst[e];
        int pos = atomicAdd(&cursor[d], 1);
        srcv[pos] = src[e];
        dstv[pos] = (unsigned short)d;
        eidv[pos] = e;
    }
}

// ---------------- prep: 6x fp32 [k=128][n=128] -> bf16 [n][k] ----------------
__global__ __launch_bounds__(256) void k_prep_all(const float* __restrict__ Wg,
                                                  const float* __restrict__ W3,
                                                  const float* __restrict__ Wm1,
                                                  short* __restrict__ WbT6) {
    int i = blockIdx.x * 256 + threadIdx.x;   // 6*16384 total
    if (i >= 6 * 16384) return;
    int m = i >> 14;
    int r = i & 16383;
    int n = r >> 7, k = r & 127;
    const float* srcp;
    switch (m) {
        case 0: srcp = Wg; break;
        case 1: srcp = Wg + 16384; break;
        case 2: srcp = Wg + 32768; break;
        case 3: srcp = W3; break;
        case 4: srcp = Wm1; break;
        default: srcp = Wm1 + 16384; break;
    }
    WbT6[m * 16384 + n * 128 + k] = f2bf(srcp[k * 128 + n]);
}

// ---------------- prep: fused el/er weight tiles Wel[layer][16][128] ----------------
// el = (A@W)·al = A@(W@Aexp): Wel[n][k] = sum_d W[k][h*16+d]*a[h*16+d], h=n&7,
// a = al (n<8) or ar (n>=8). Layer 3 (H=1): n==0 -> W3·al3, n==1 -> W3·ar3, else 0.
__global__ __launch_bounds__(256) void k_prep_wela(const float* __restrict__ Wg,
                                                   const float* __restrict__ alg,
                                                   const float* __restrict__ arg_,
                                                   const float* __restrict__ W3,
                                                   const float* __restrict__ al3,
                                                   const float* __restrict__ ar3,
                                                   short* __restrict__ WelT) {
    int i = blockIdx.x * 256 + threadIdx.x;   // 4*16*128 = 8192 total
    if (i >= 4 * 2048) return;
    int layer = i >> 11;
    int r = i & 2047;
    int n = r >> 7, k = r & 127;
    float val = 0.f;
    if (layer < 3) {
        const float* W = Wg + layer * 16384;
        const float* a = (n < 8 ? alg : arg_) + layer * 128;
        int h = n & 7;
#pragma unroll
        for (int d = 0; d < 16; d++)
            val += W[k * 128 + h * 16 + d] * a[h * 16 + d];
    } else {
        if (n == 0) { for (int c = 0; c < 128; c++) val += W3[k * 128 + c] * al3[c]; }
        else if (n == 1) { for (int c = 0; c < 128; c++) val += W3[k * 128 + c] * ar3[c]; }
    }
    WelT[layer * 2048 + n * 128 + k] = f2bf(val);
}

// ---------------- prep: hi/lo bf16 splits of W_emb [128,128] and Wa [128,100] ----------------
// outputs transposed [n][k]; Wa zero-padded to n=128
__global__ __launch_bounds__(256) void k_prep_hilo(const float* __restrict__ W_emb,
                                                   const float* __restrict__ Wa,
                                                   short* __restrict__ WembT_hi,
                                                   short* __restrict__ WembT_lo,
                                                   short* __restrict__ WaT_hi,
                                                   short* __restrict__ WaT_lo) {
    int i = blockIdx.x * 256 + threadIdx.x;   // 2*16384 total
    if (i >= 2 * 16384) return;
    int m = i >> 14;
    int r = i & 16383;
    int n = r >> 7, k = r & 127;
    if (m == 0) {
        float w = W_emb[k * 128 + n];
        short h = f2bf(w);
        WembT_hi[n * 128 + k] = h;
        WembT_lo[n * 128 + k] = f2bf(w - bf2f(h));
    } else {
        float w = (n < 100) ? Wa[k * 100 + n] : 0.f;
        short h = f2bf(w);
        WaT_hi[n * 128 + k] = h;
        WaT_lo[n * 128 + k] = f2bf(w - bf2f(h));
    }
}

// ---------------- fp32-accurate MFMA GEMM via 3-term hi/lo split ----------------
__global__ __launch_bounds__(256) void k_mfma_hilo(const float* __restrict__ A,
                                                   const short* __restrict__ BT_hi,
                                                   const short* __restrict__ BT_lo,
                                                   const float* __restrict__ bias,
                                                   float* __restrict__ C, int ncols) {
    __shared__ short sAh[64 * 136];
    __shared__ short sAl[64 * 136];
    __shared__ short sBh[128 * 136];
    int t = threadIdx.x;
    int r0 = blockIdx.x * 64;
    // stage B_hi: each thread copies 64 bf16
    {
        int n = t >> 1;
        int k0 = (t & 1) * 64;
#pragma unroll
        for (int j = 0; j < 8; j++) {
            bf16x8 v = *(const bf16x8*)(BT_hi + n * 128 + k0 + 8 * j);
            *(bf16x8*)(sBh + n * 136 + k0 + 8 * j) = v;
        }
    }
    // stage A hi/lo: each thread converts 32 floats
    {
        int r = t >> 2;
        int k0 = (t & 3) * 32;
        const float* ar = A + (size_t)(r0 + r) * 128 + k0;
#pragma unroll
        for (int j = 0; j < 4; j++) {
            float4 f0 = *(const float4*)(ar + 8 * j);
            float4 f1 = *(const float4*)(ar + 8 * j + 4);
            float x[8] = {f0.x, f0.y, f0.z, f0.w, f1.x, f1.y, f1.z, f1.w};
            bf16x8 vh, vl;
#pragma unroll
            for (int q = 0; q < 8; q++) {
                short hh = f2bf(x[q]);
                vh[q] = hh;
                vl[q] = f2bf(x[q] - bf2f(hh));
            }
            *(bf16x8*)(sAh + r * 136 + k0 + 8 * j) = vh;
            *(bf16x8*)(sAl + r * 136 + k0 + 8 * j) = vl;
        }
    }
    __syncthreads();
    int lane = t & 63, wv = t >> 6;
    int lm = lane & 15, quad = lane >> 4;
    int m0 = wv * 16;
    bf16x8 aH[4], aL[4];
#pragma unroll
    for (int kt = 0; kt < 4; kt++) {
        aH[kt] = *(const bf16x8*)(sAh + (m0 + lm) * 136 + kt * 32 + quad * 8);
        aL[kt] = *(const bf16x8*)(sAl + (m0 + lm) * 136 + kt * 32 + quad * 8);
    }
#pragma unroll
    for (int nt = 0; nt < 8; nt++) {
        const short* blp = BT_lo + (nt * 16 + lm) * 128 + quad * 8;
        floatx4 acc = (floatx4){0.f, 0.f, 0.f, 0.f};
#pragma unroll
        for (int kt = 0; kt < 4; kt++) {
            bf16x8 bH = *(const bf16x8*)(sBh + (nt * 16 + lm) * 136 + kt * 32 + quad * 8);
            bf16x8 bL = *(const bf16x8*)(blp + kt * 32);
            acc = __builtin_amdgcn_mfma_f32_16x16x32_bf16(aH[kt], bH, acc, 0, 0, 0);
            acc = __builtin_amdgcn_mfma_f32_16x16x32_bf16(aL[kt], bH, acc, 0, 0, 0);
            acc = __builtin_amdgcn_mfma_f32_16x16x32_bf16(aH[kt], bL, acc, 0, 0, 0);
        }
        int col = nt * 16 + lm;
        if (col < ncols) {
            float bv = bias ? bias[col] : 0.f;
#pragma unroll
            for (int r = 0; r < 4; r++) {
                int row = r0 + m0 + quad * 4 + r;
                C[(size_t)row * ncols + col] = acc[r] + bv;
            }
        }
    }
}

// ---------------- MFMA GEMM: [N,128](fp32) @ WbT(bf16 [n][k]) -> bf16 out ----------------
// 64 rows/block, full N=128. A converted fp32->bf16 into LDS (+8 pad = 2-way bank, free).
// Optional fused el/er epilogue (r9) + BN prologue (r10) + second output (r13).
__global__ __launch_bounds__(256) void k_gemm_mfma(const float* __restrict__ A,
                                                   const short* __restrict__ WbT,
                                                   const float* __restrict__ bias,
                                                   short* __restrict__ C,
                                                   const short* __restrict__ WelT,
                                                   float* __restrict__ el,
                                                   float* __restrict__ er,
                                                   int H,
                                                   const float* __restrict__ bnx,
                                                   const float* __restrict__ bnh,
                                                   const float* __restrict__ csum,
                                                   const float* __restrict__ csq,
                                                   const float* __restrict__ bng,
                                                   const float* __restrict__ bnb,
                                                   float* __restrict__ hout,
                                                   int do_mask,
                                                   const short* __restrict__ WbT2,
                                                   short* __restrict__ C2) {
    __shared__ short sA[64 * 136];
    __shared__ short sB[128 * 136];
    __shared__ float sScale[128];
    __shared__ float sShift[128];
    int t = threadIdx.x;
    int r0 = blockIdx.x * 64;
    if (bnx) {
        if (t < 128) {
            const float invN = 1.f / (float)N_;
            float mu = csum[t] * invN;
            float var = csq[t] * invN - mu * mu;
            float inv = rsqrtf(var + 1e-5f);
            float sc = bng[t] * inv;
            sScale[t] = sc;
            sShift[t] = bnb[t] - mu * sc;
        }
        __syncthreads();
    }
    // stage B: each thread copies 64 bf16
    {
        int n = t >> 1;
        int k0 = (t & 1) * 64;
#pragma unroll
        for (int j = 0; j < 8; j++) {
            bf16x8 v = *(const bf16x8*)(WbT + n * 128 + k0 + 8 * j);
            *(bf16x8*)(sB + n * 136 + k0 + 8 * j) = v;
        }
    }
    // stage A: each thread handles 32 elements of one row-quarter
    {
        int r = t >> 2;
        int k0 = (t & 3) * 32;
        if (bnx) {
            const float* xr = bnx + (size_t)(r0 + r) * 128 + k0;
            const float* hr = bnh + (size_t)(r0 + r) * 128 + k0;
            float* ho = hout + (size_t)(r0 + r) * 128 + k0;
#pragma unroll
            for (int j = 0; j < 4; j++) {
                float4 x0 = *(const float4*)(xr + 8 * j);
                float4 x1 = *(const float4*)(xr + 8 * j + 4);
                float4 h0 = *(const float4*)(hr + 8 * j);
                float4 h1 = *(const float4*)(hr + 8 * j + 4);
                float xs[8] = {x0.x, x0.y, x0.z, x0.w, x1.x, x1.y, x1.z, x1.w};
                float hs[8] = {h0.x, h0.y, h0.z, h0.w, h1.x, h1.y, h1.z, h1.w};
                float ov[8];
                bf16x8 v;
#pragma unroll
                for (int q = 0; q < 8; q++) {
                    int c = k0 + 8 * j + q;
                    float y = sScale[c] * xs[q] + sShift[c];
                    y = y > 0.f ? y : (__expf(y) - 1.f);
                    float hv = hs[q] + y;
                    if (do_mask && isinf(hv)) hv = 1e9f;
                    ov[q] = hv;
                    v[q] = f2bf(hv);
                }
                *(float4*)(ho + 8 * j) = make_float4(ov[0], ov[1], ov[2], ov[3]);
                *(float4*)(ho + 8 * j + 4) = make_float4(ov[4], ov[5], ov[6], ov[7]);
                *(bf16x8*)(sA + r * 136 + k0 + 8 * j) = v;
            }
        } else {
            const float* ar = A + (size_t)(r0 + r) * 128 + k0;
#pragma unroll
            for (int j = 0; j < 4; j++) {
                float4 f0 = *(const float4*)(ar + 8 * j);
                float4 f1 = *(const float4*)(ar + 8 * j + 4);
                bf16x8 v;
                v[0] = f2bf(f0.x); v[1] = f2bf(f0.y); v[2] = f2bf(f0.z); v[3] = f2bf(f0.w);
                v[4] = f2bf(f1.x); v[5] = f2bf(f1.y); v[6] = f2bf(f1.z); v[7] = f2bf(f1.w);
                *(bf16x8*)(sA + r * 136 + k0 + 8 * j) = v;
            }
        }
    }
    __syncthreads();
    int lane = t & 63, wv = t >> 6;
    int lm = lane & 15, quad = lane >> 4;
    int m0 = wv * 16;
    bf16x8 aF[4];
#pragma unroll
    for (int kt = 0; kt < 4; kt++)
        aF[kt] = *(const bf16x8*)(sA + (m0 + lm) * 136 + kt * 32 + quad * 8);
#pragma unroll
    for (int nt = 0; nt < 8; nt++) {
        floatx4 acc = (floatx4){0.f, 0.f, 0.f, 0.f};
#pragma unroll
        for (int kt = 0; kt < 4; kt++) {
            bf16x8 bF = *(const bf16x8*)(sB + (nt * 16 + lm) * 136 + kt * 32 + quad * 8);
            acc = __builtin_amdgcn_mfma_f32_16x16x32_bf16(aF[kt], bF, acc, 0, 0, 0);
        }
        int col = nt * 16 + lm;
        float bv = bias ? bias[col] : 0.f;
#pragma unroll
        for (int r = 0; r < 4; r++) {
            int row = r0 + m0 + quad * 4 + r;
            C[(size_t)row * 128 + col] = f2bf(acc[r] + bv);
        }
    }
    // fused el/er tile: cols 0..7 = el heads, 8..15 = er heads (H=1: col0=el, col1=er)
    if (WelT) {
        floatx4 acc = (floatx4){0.f, 0.f, 0.f, 0.f};
#pragma unroll
        for (int kt = 0; kt < 4; kt++) {
            bf16x8 wF = *(const bf16x8*)(WelT + lm * 128 + kt * 32 + quad * 8);
            acc = __builtin_amdgcn_mfma_f32_16x16x32_bf16(aF[kt], wF, acc, 0, 0, 0);
        }
        if (H == 8) {
#pragma unroll
            for (int r = 0; r < 4; r++) {
                int row = r0 + m0 + quad * 4 + r;
                if (lm < 8) el[(size_t)row * 8 + lm] = acc[r];
                else        er[(size_t)row * 8 + (lm - 8)] = acc[r];
            }
        } else {
#pragma unroll
            for (int r = 0; r < 4; r++) {
                int row = r0 + m0 + quad * 4 + r;
                if (lm == 0) el[row] = acc[r];
                if (lm == 1) er[row] = acc[r];
            }
        }
    }
    // second output: re-stage sB, recompute with same aF (Pb/Qb merge)
    if (WbT2) {
        __syncthreads();   // all compute reads of sB complete
        {
            int n = t >> 1;
            int k0 = (t & 1) * 64;
#pragma unroll
            for (int j = 0; j < 8; j++) {
                bf16x8 v = *(const bf16x8*)(WbT2 + n * 128 + k0 + 8 * j);
                *(bf16x8*)(sB + n * 136 + k0 + 8 * j) = v;
            }
        }
        __syncthreads();
#pragma unroll
        for (int nt = 0; nt < 8; nt++) {
            floatx4 acc = (floatx4){0.f, 0.f, 0.f, 0.f};
#pragma unroll
            for (int kt = 0; kt < 4; kt++) {
                bf16x8 bF = *(const bf16x8*)(sB + (nt * 16 + lm) * 136 + kt * 32 + quad * 8);
                acc = __builtin_amdgcn_mfma_f32_16x16x32_bf16(aF[kt], bF, acc, 0, 0, 0);
            }
            int col = nt * 16 + lm;
#pragma unroll
            for (int r = 0; r < 4; r++) {
                int row = r0 + m0 + quad * 4 + r;
                C2[(size_t)row * 128 + col] = f2bf(acc[r]);
            }
        }
    }
}

// ---------------- softmax over 100 logits, wave per node, barrier-free ----------------
__global__ __launch_bounds__(256) void k_smax100(const float* __restrict__ logits,
                                                 float* __restrict__ s) {
    int lane = threadIdx.x & 63;
    int n = blockIdx.x * 4 + (threadIdx.x >> 6);
    if (n >= N_) return;
    bool act = lane < 50;
    float2 v = make_float2(-INFINITY, -INFINITY);
    if (act) v = *(const float2*)(logits + (size_t)n * 100 + 2 * lane);
    float mx = fmaxf(v.x, v.y);
#pragma unroll
    for (int off = 1; off < 64; off <<= 1) mx = fmaxf(mx, __shfl_xor(mx, off));
    float e0 = act ? __expf(v.x - mx) : 0.f;
    float e1 = act ? __expf(v.y - mx) : 0.f;
    float sm = e0 + e1;
#pragma unroll
    for (int off = 1; off < 64; off <<= 1) sm += __shfl_xor(sm, off);
    float inv = 1.f / sm;
    if (act) *(float2*)(s + (size_t)n * 100 + 2 * lane) = make_float2(e0 * inv, e1 * inv);
}

// ---------------- GAT edge-softmax + aggregate (wave per dst node, bf16 feat) ----------------
// v7 (r14, VALIDATED 729us): single-pass flash-style online softmax-aggregate.
// BN stats epilogue: per-block coalesced partials (r12, NO atomics).
template <int H>
__global__ __launch_bounds__(256) void k_gat_agg(const short* __restrict__ feat,
                                                 const float* __restrict__ el,
                                                 const float* __restrict__ er,
                                                 const int* __restrict__ rowptr,
                                                 const int* __restrict__ srcv,
                                                 const float* __restrict__ bias,
                                                 float* __restrict__ xout,
                                                 float* __restrict__ psum,
                                                 float* __restrict__ psq) {
    int t = threadIdx.x;
    int lane = t & 63;
    int gw = (blockIdx.x * blockDim.x + t) >> 6;
    int nw = (gridDim.x * blockDim.x) >> 6;
    int h = lane & (H - 1);
    int f0 = 2 * lane;
    int hf = (H == 8) ? (lane >> 3) : 0;   // head owning this lane's feature slice

    float stx = 0.f, sty = 0.f, qtx = 0.f, qty = 0.f;  // fused BN stats

    for (int n = gw; n < N_; n += nw) {
        int beg = rowptr[n], end = rowptr[n + 1];
        if (beg == end) {
            float2 b2 = *(const float2*)(bias + f0);
            *(float2*)(xout + (size_t)n * 128 + f0) = b2;
            stx += b2.x; sty += b2.y;
            qtx += b2.x * b2.x; qty += b2.y * b2.y;
            continue;
        }
        float ern = er[(size_t)n * H + h];
        int endm1 = end - 1;
        float m = -INFINITY, ss = 0.f;
        float accx = 0.f, accy = 0.f;
        for (int e0 = beg; e0 < end; e0 += 16) {
            int le = lane >> 3;
            int eLA = e0 + le, eLB = e0 + 8 + le;
            int eCA = eLA <= endm1 ? eLA : endm1;
            int eCB = eLB <= endm1 ? eLB : endm1;
            int sLA = srcv[eCA];
            int sLB = srcv[eCB];
            float xA = el[(size_t)sLA * H + h] + ern;
            float xB = el[(size_t)sLB * H + h] + ern;
            float lrA = xA > 0.f ? xA : 0.2f * xA;
            float lrB = xB > 0.f ? xB : 0.2f * xB;
            if (eLA > endm1) lrA = -INFINITY;
            if (eLB > endm1) lrB = -INFINITY;
            bool haveB = (e0 + 8) < end;    // wave-uniform
            unsigned int uuA[8], uuB[8];
#pragma unroll
            for (int j = 0; j < 8; j++) {
                int sj = __builtin_amdgcn_readlane(sLA, j * 8);
                uuA[j] = *(const unsigned int*)(feat + (size_t)sj * 128 + f0);
            }
            if (haveB) {
#pragma unroll
                for (int j = 0; j < 8; j++) {
                    int sj = __builtin_amdgcn_readlane(sLB, j * 8);
                    uuB[j] = *(const unsigned int*)(feat + (size_t)sj * 128 + f0);
                }
            }
#pragma unroll
            for (int j = 0; j < 8; j++) {
                float lj;
                if (H == 8) lj = __shfl(lrA, j * 8 + hf);
                else        lj = rdlane(lrA, j * 8);
                if (lj > m) {
                    float r = __expf(m - lj);   // m=-INF first time -> r=0 (acc,ss are 0)
                    accx *= r; accy *= r; ss *= r; m = lj;
                }
                float w = __expf(lj - m);       // lj=-INF (masked) -> w=0
                accx += w * bflo(uuA[j]);
                accy += w * bfhi(uuA[j]);
                ss += w;
            }
            if (haveB) {
#pragma unroll
                for (int j = 0; j < 8; j++) {
                    float lj;
                    if (H == 8) lj = __shfl(lrB, j * 8 + hf);
                    else        lj = rdlane(lrB, j * 8);
                    if (lj > m) {
                        float r = __expf(m - lj);
                        accx *= r; accy *= r; ss *= r; m = lj;
                    }
                    float w = __expf(lj - m);
                    accx += w * bflo(uuB[j]);
                    accy += w * bfhi(uuB[j]);
                    ss += w;
                }
            }
        }
        float inv_d = 1.f / ss;
        float2 b2 = *(const float2*)(bias + f0);
        float ox = accx * inv_d + b2.x, oy = accy * inv_d + b2.y;
        *(float2*)(xout + (size_t)n * 128 + f0) = make_float2(ox, oy);
        stx += ox; sty += oy;
        qtx += ox * ox; qty += oy * oy;
    }

    // ---- per-block partial stats: LDS reduce across 4 waves, coalesced plain store ----
    __shared__ float red[4][256];
    red[0][t] = stx; red[1][t] = sty; red[2][t] = qtx; red[3][t] = qty;
    __syncthreads();
    if (t < 64) {
        float a0 = red[0][t] + red[0][t + 64] + red[0][t + 128] + red[0][t + 192];
        float a1 = red[1][t] + red[1][t + 64] + red[1][t + 128] + red[1][t + 192];
        float q0 = red[2][t] + red[2][t + 64] + red[2][t + 128] + red[2][t + 192];
        float q1 = red[3][t] + red[3][t + 64] + red[3][t + 128] + red[3][t + 192];
        *(float2*)(psum + (size_t)blockIdx.x * 128 + 2 * t) = make_float2(a0, a1);
        *(float2*)(psq + (size_t)blockIdx.x * 128 + 2 * t) = make_float2(q0, q1);
    }
}

// ---------------- reduce per-block stats partials -> colsum/colsq ----------------
__global__ __launch_bounds__(256) void k_stats_reduce(const float* __restrict__ psum,
                                                      const float* __restrict__ psq,
                                                      float* __restrict__ colsum,
                                                      float* __restrict__ colsq) {
    __shared__ float ls[256], lq[256];
    int t = threadIdx.x;
    int col = t & 127, half = t >> 7;
    float s = 0.f, q = 0.f;
    for (int b = blockIdx.x * 2 + half; b < AGGB_; b += gridDim.x * 2) {
        s += psum[(size_t)b * 128 + col];
        q += psq[(size_t)b * 128 + col];
    }
    ls[t] = s; lq[t] = q;
    __syncthreads();
    if (t < 128) {
        atomicAdd(&colsum[col], ls[t] + ls[t + 128]);
        atomicAdd(&colsq[col], lq[t] + lq[t + 128]);
    }
}

// ---------------- h_coarse partials (layer-1 BN fused: hf = hprev + elu(bn(xraw))) ----------------
__global__ __launch_bounds__(512) void k_coarse_part(const float* __restrict__ s,
                                                     const float* __restrict__ xraw,
                                                     const float* __restrict__ hprev,
                                                     const float* __restrict__ csum,
                                                     const float* __restrict__ csq,
                                                     const float* __restrict__ bng,
                                                     const float* __restrict__ bnb,
                                                     float* __restrict__ part) {
    __shared__ float sSc[128], sSh[128];
    int t = threadIdx.x;
    if (t < 128) {
        const float invN = 1.f / (float)N_;
        float mu = csum[t] * invN;
        float var = csq[t] * invN - mu * mu;
        float inv = rsqrtf(var + 1e-5f);
        float sc = bng[t] * inv;
        sSc[t] = sc;
        sSh[t] = bnb[t] - mu * sc;
    }
    __syncthreads();
    int c = t & 127;
    int g = t >> 7;        // 0..3
    int lane = t & 63;
    float scl = sSc[c], shf = sSh[c];
    float acc[25];
#pragma unroll
    for (int a = 0; a < 25; a++) acc[a] = 0.f;
    int n0 = blockIdx.x * CR_;
    for (int n = n0; n < n0 + CR_; n += 2) {
        float y0 = scl * xraw[(size_t)n * 128 + c] + shf;
        float y1 = scl * xraw[(size_t)(n + 1) * 128 + c] + shf;
        y0 = y0 > 0.f ? y0 : (__expf(y0) - 1.f);
        y1 = y1 > 0.f ? y1 : (__expf(y1) - 1.f);
        float hv0 = hprev[(size_t)n * 128 + c] + y0;
        float hv1 = hprev[(size_t)(n + 1) * 128 + c] + y1;
        float sv0 = 0.f, sv1 = 0.f;
        if (lane < 25) {
            sv0 = s[(size_t)n * 100 + 25 * g + lane];
            sv1 = s[(size_t)(n + 1) * 100 + 25 * g + lane];
        }
#pragma unroll
        for (int a = 0; a < 25; ++a) {
            float a0 = rdlane(sv0, a);
            float a1 = rdlane(sv1, a);
            acc[a] += a0 * hv0 + a1 * hv1;
        }
    }
    float* dstp = part + (size_t)blockIdx.x * 12800 + (size_t)(25 * g) * 128 + c;
#pragma unroll
    for (int a = 0; a < 25; a++) dstp[a * 128] = acc[a];
}

// ---------------- reduce partials -> hc[100][128] ----------------
__global__ __launch_bounds__(256) void k_coarse_reduce(const float* __restrict__ part,
                                                       float* __restrict__ hc) {
    int i = blockIdx.x * blockDim.x + threadIdx.x;  // 12800 total
    if (i >= 12800) return;
    float s0 = 0.f, s1 = 0.f, s2 = 0.f, s3 = 0.f;
    for (int b = 0; b < CB_; b += 4) {
        s0 += part[(size_t)(b + 0) * 12800 + i];
        s1 += part[(size_t)(b + 1) * 12800 + i];
        s2 += part[(size_t)(b + 2) * 12800 + i];
        s3 += part[(size_t)(b + 3) * 12800 + i];
    }
    hc[i] = (s0 + s1) + (s2 + s3);
}

// ---------------- h = mask(0.5*h_fine + 0.5*(s@h_coarse)), layer-1 BN fused ----------------
// hfine computed inline: hprev + elu(bn(xraw)); writes h_cur in place (per-element RMW).
__global__ __launch_bounds__(256) void k_combine(const float* __restrict__ s,
                                                 const float* __restrict__ hc,
                                                 const float* __restrict__ xraw,
                                                 const float* __restrict__ csum,
                                                 const float* __restrict__ csq,
                                                 const float* __restrict__ bng,
                                                 const float* __restrict__ bnb,
                                                 float* __restrict__ hout) {
    __shared__ float ssh[16 * 100];
    __shared__ float sSc[128], sSh[128];
    int t = threadIdx.x;
    int n0 = blockIdx.x * 16;
    if (t < 128) {
        const float invN = 1.f / (float)N_;
        float mu = csum[t] * invN;
        float var = csq[t] * invN - mu * mu;
        float inv = rsqrtf(var + 1e-5f);
        float sc = bng[t] * inv;
        sSc[t] = sc;
        sSh[t] = bnb[t] - mu * sc;
    }
    for (int u = t; u < 1600; u += 256) ssh[u] = s[(size_t)n0 * 100 + u];
    __syncthreads();
    int c = t & 127, g = t >> 7;
    float scl = sSc[c], shf = sSh[c];
    float acc[8];
#pragma unroll
    for (int r = 0; r < 8; r++) acc[r] = 0.f;
    const float* hcp = hc + c;
    for (int a = 0; a < 100; a += 4) {
        float h0 = hcp[(a + 0) * 128];
        float h1 = hcp[(a + 1) * 128];
        float h2 = hcp[(a + 2) * 128];
        float h3 = hcp[(a + 3) * 128];
#pragma unroll
        for (int r = 0; r < 8; r++) {
            float4 sv = *(const float4*)(ssh + (g * 8 + r) * 100 + a);
            acc[r] += sv.x * h0 + sv.y * h1 + sv.z * h2 + sv.w * h3;
        }
    }
#pragma unroll
    for (int r = 0; r < 8; r++) {
        int row = n0 + g * 8 + r;
        float y = scl * xraw[(size_t)row * 128 + c] + shf;
        y = y > 0.f ? y : (__expf(y) - 1.f);
        float hfine = hout[(size_t)row * 128 + c] + y;   // hout holds h_prev here
        float v = 0.5f * hfine + 0.5f * acc[r];
        if (isinf(v)) v = 1e9f;
        hout[(size_t)row * 128 + c] = v;
    }
}

// ---------------- prep: Wm2 [128][64] fp32 -> Wm2T bf16 [64][128] ----------------
__global__ __launch_bounds__(256) void k_prep_w(const float* __restrict__ Wm2,
                                                short* __restrict__ Wm2T) {
    int i = blockIdx.x * blockDim.x + threadIdx.x;  // 8192 total
    if (i >= 64 * 128) return;
    int n = i & 63, k = i >> 6;
    Wm2T[n * 128 + k] = f2bf(Wm2[k * 64 + n]);
}

// ---------------- edge MLP readout: dst-sorted order, barrier-free persistent MFMA ----------------
// v2 — LOCAL OPTIMUM at ~54us, VGPR 84. Do not register-diet (v3: spills, 3x dur).
// Do not 2-tile (v4: compiler serializes the B-tile loads, occupancy drops, +6us).
__global__ __launch_bounds__(256) void k_edge_mlp3(const short* __restrict__ Pb,
                                                   const short* __restrict__ Qb,
                                                   const int* __restrict__ srcv,
                                                   const unsigned short* __restrict__ dstv,
                                                   const int* __restrict__ eidv,
                                                   const short* __restrict__ Wm2T,
                                                   const float* __restrict__ bm2,
                                                   const float* __restrict__ Wm3,
                                                   const float* __restrict__ bm3,
                                                   float* __restrict__ zout) {
    __shared__ short sW[64 * 128];  // 16 KiB
    int t = threadIdx.x;
    // stage Wm2T -> LDS with 16B-unit XOR swizzle: phys_unit = n*16 + (k16 ^ (n&15))
    for (int u = t; u < 1024; u += 256) {
        int n = u >> 4, k16 = u & 15;
        int phys = (n << 4) | (k16 ^ (n & 15));
        *(bf16x8*)(sW + phys * 8) = *(const bf16x8*)(Wm2T + n * 128 + k16 * 8);
    }
    int lane = t & 63;
    int lm = lane & 15, quad = lane >> 4;
    float bv[4], w30[4], w31[4];
#pragma unroll
    for (int nt = 0; nt < 4; nt++) {
        int n = nt * 16 + lm;
        bv[nt] = bm2[n]; w30[nt] = Wm3[2 * n]; w31[nt] = Wm3[2 * n + 1];
    }
    float b30 = bm3[0], b31 = bm3[1];
    __syncthreads();

    int gw = (blockIdx.x * blockDim.x + t) >> 6;
    int nw = (gridDim.x * blockDim.x) >> 6;

    for (int tile = gw; tile < E_ / 16; tile += nw) {
        int p0 = tile * 16;
        int sI = srcv[p0 + lm];
        int dI = (int)dstv[p0 + lm];
        const short* pr = Pb + (size_t)sI * 128 + quad * 8;
        const short* qr = Qb + (size_t)dI * 128 + quad * 8;
        // issue all 8 gathers up-front (latency hidden within wave)
        uint4 pu[4], qu[4];
#pragma unroll
        for (int kt = 0; kt < 4; kt++) {
            pu[kt] = *(const uint4*)(pr + kt * 32);
            qu[kt] = *(const uint4*)(qr + kt * 32);
        }
        bf16x8 aF[4];
#pragma unroll
        for (int kt = 0; kt < 4; kt++) {
            unsigned int pv[4] = {pu[kt].x, pu[kt].y, pu[kt].z, pu[kt].w};
            unsigned int qv[4] = {qu[kt].x, qu[kt].y, qu[kt].z, qu[kt].w};
            union { uint4 u; bf16x8 v; } cv;
            unsigned int rr[4];
#pragma unroll
            for (int j = 0; j < 4; j++) {
                float fl = fmaxf(bflo(pv[j]) + bflo(qv[j]), 0.f);
                float fh = fmaxf(bfhi(pv[j]) + bfhi(qv[j]), 0.f);
                rr[j] = (unsigned int)(unsigned short)f2bf(fl) |
                        ((unsigned int)(unsigned short)f2bf(fh) << 16);
            }
            cv.u.x = rr[0]; cv.u.y = rr[1]; cv.u.z = rr[2]; cv.u.w = rr[3];
            aF[kt] = cv.v;
        }
        float pz0[4] = {0.f, 0.f, 0.f, 0.f};
        float pz1[4] = {0.f, 0.f, 0.f, 0.f};
#pragma unroll
        for (int nt = 0; nt < 4; nt++) {
            floatx4 acc = (floatx4){0.f, 0.f, 0.f, 0.f};
#pragma unroll
            for (int kt = 0; kt < 4; kt++) {
                int phys = ((nt * 16 + lm) << 4) | (((kt << 2) | quad) ^ lm);
                bf16x8 bF = *(const bf16x8*)(sW + phys * 8);
                acc = __builtin_amdgcn_mfma_f32_16x16x32_bf16(aF[kt], bF, acc, 0, 0, 0);
            }
#pragma unroll
            for (int r = 0; r < 4; r++) {
                float u = fmaxf(acc[r] + bv[nt], 0.f);
                pz0[r] += u * w30[nt];
                pz1[r] += u * w31[nt];
            }
        }
#pragma unroll
        for (int off = 1; off < 16; off <<= 1) {
#pragma unroll
            for (int r = 0; r < 4; r++) {
                pz0[r] += __shfl_xor(pz0[r], off);
                pz1[r] += __shfl_xor(pz1[r], off);
            }
        }
        if (lm < 4) {
            int eid = eidv[p0 + quad * 4 + lm];
            float z0 = pz0[lm] + b30;
            float z1 = pz1[lm] + b31;
            if (isinf(z0)) z0 = 1e9f;
            if (isinf(z1)) z1 = 1e9f;
            *(float2*)(zout + (size_t)eid * 2) = make_float2(z0, z1);
        }
    }
}

extern "C" void kernel_launch(void* const* d_in, const int* in_sizes, int n_in,
                              void* d_out, int out_size, void* d_ws, size_t ws_size,
                              hipStream_t stream) {
    const float* h_in  = (const float*)d_in[0];
    const int*   src   = (const int*)d_in[2];
    const int*   dst   = (const int*)d_in[3];
    const float* W_emb = (const float*)d_in[4];
    const float* b_emb = (const float*)d_in[5];
    const float* Wg    = (const float*)d_in[6];
    const float* alg   = (const float*)d_in[7];
    const float* arg_  = (const float*)d_in[8];
    const float* bg    = (const float*)d_in[9];
    const float* gam   = (const float*)d_in[10];
    const float* bet   = (const float*)d_in[11];
    const float* W3    = (const float*)d_in[12];
    const float* al3   = (const float*)d_in[13];
    const float* ar3   = (const float*)d_in[14];
    const float* b3    = (const float*)d_in[15];
    const float* gam3  = (const float*)d_in[16];
    const float* bet3  = (const float*)d_in[17];
    const float* Wa    = (const float*)d_in[18];
    const float* ba    = (const float*)d_in[19];
    const float* Wm1   = (const float*)d_in[20];
    const float* bm1   = (const float*)d_in[21];
    const float* Wm2   = (const float*)d_in[22];
    const float* bm2   = (const float*)d_in[23];
    const float* Wm3   = (const float*)d_in[24];
    const float* bm3   = (const float*)d_in[25];

    float* zout = (float*)d_out;
    float* sout = zout + (size_t)E_ * 2;

    float* ws = (float*)d_ws;
    size_t o = 0;
    float* h_cur = ws + o; o += (size_t)N_ * 128;
    float* xbuf  = ws + o; o += (size_t)N_ * 128;
    float* featb = ws + o; o += (size_t)N_ * 128;   // reused: bf16 feat, coarse partials, bf16 P/Q
    float* el    = ws + o; o += (size_t)N_ * 8;
    float* er    = ws + o; o += (size_t)N_ * 8;
    float* colsum = ws + o; o += 128;
    float* colsq  = ws + o; o += 128;
    float* hc     = ws + o; o += 100 * 128;
    float* psum   = ws + o; o += (size_t)AGGB_ * 128;
    float* psq    = ws + o; o += (size_t)AGGB_ * 128;
    short* Wm2T = (short*)(ws + o); o += (64 * 128) / 2;
    short* WbT6 = (short*)(ws + o); o += (6 * 16384) / 2;
    short* WelT = (short*)(ws + o); o += (4 * 2048) / 2;
    short* WembT_hi = (short*)(ws + o); o += 16384 / 2;
    short* WembT_lo = (short*)(ws + o); o += 16384 / 2;
    short* WaT_hi   = (short*)(ws + o); o += 16384 / 2;
    short* WaT_lo   = (short*)(ws + o); o += 16384 / 2;
    int* counts = (int*)(ws + o); o += N_;
    int* rowptr = (int*)(ws + o); o += N_ + 4;
    int* cursor = (int*)(ws + o); o += N_;
    int* srcv   = (int*)(ws + o); o += E_;
    unsigned short* dstv = (unsigned short*)(ws + o); o += E_ / 2;
    int* eidv   = (int*)(ws + o); o += E_;
    int* bsum   = (int*)(ws + o); o += SNB_ + 4;

    short* featw = (short*)featb;  // bf16 per-layer projection

    // ---- CSR build (parallel scan; excl scratch reuses eidv pre-fill) ----
    hipMemsetAsync(counts, 0, N_ * sizeof(int), stream);
    k_count<<<1024, 256, 0, stream>>>(dst, counts);
    k_scanA<<<SNB_, 256, 0, stream>>>(counts, eidv, bsum);
    k_scanB<<<1, 256, 0, stream>>>(bsum);
    k_scanC<<<SNB_ + 1, 256, 0, stream>>>(eidv, bsum, rowptr, cursor);
    k_fill<<<1024, 256, 0, stream>>>(src, dst, cursor, srcv, dstv, eidv);
    k_prep_w<<<32, 256, 0, stream>>>(Wm2, Wm2T);
    k_prep_all<<<384, 256, 0, stream>>>(Wg, W3, Wm1, WbT6);
    k_prep_wela<<<32, 256, 0, stream>>>(Wg, alg, arg_, W3, al3, ar3, WelT);
    k_prep_hilo<<<128, 256, 0, stream>>>(W_emb, Wa, WembT_hi, WembT_lo, WaT_hi, WaT_lo);

    // ---- embedding (fp32-accurate via hi/lo MFMA) ----
    k_mfma_hilo<<<N_ / 64, 256, 0, stream>>>(h_in, WembT_hi, WembT_lo, b_emb, h_cur, 128);

    // ---- layer 0 (H=8) ----
    k_gemm_mfma<<<N_ / 64, 256, 0, stream>>>(h_cur, WbT6 + 0 * 16384, nullptr, featw,
                                             WelT + 0 * 2048, el, er, 8,
                                             nullptr, nullptr, nullptr, nullptr,
                                             nullptr, nullptr, nullptr, 0,
                                             nullptr, nullptr);
    hipMemsetAsync(colsum, 0, 256 * sizeof(float), stream);
    k_gat_agg<8><<<AGGB_, 256, 0, stream>>>(featw, el, er, rowptr, srcv, bg + 0 * 128, xbuf,
                                            psum, psq);
    k_stats_reduce<<<64, 256, 0, stream>>>(psum, psq, colsum, colsq);

    // ---- layer 1 (biGAT, H=8): gemm fused with layer-0 BN (writes h_cur) ----
    k_gemm_mfma<<<N_ / 64, 256, 0, stream>>>(nullptr, WbT6 + 1 * 16384, nullptr, featw,
                                             WelT + 1 * 2048, el, er, 8,
                                             xbuf, h_cur, colsum, colsq,
                                             gam + 0 * 128, bet + 0 * 128, h_cur, 1,
                                             nullptr, nullptr);
    k_mfma_hilo<<<N_ / 64, 256, 0, stream>>>(h_cur, WaT_hi, WaT_lo, ba, xbuf, 100);
    k_smax100<<<N_ / 4, 256, 0, stream>>>(xbuf, sout);
    hipMemsetAsync(colsum, 0, 256 * sizeof(float), stream);
    k_gat_agg<8><<<AGGB_, 256, 0, stream>>>(featw, el, er, rowptr, srcv, bg + 1 * 128, xbuf,
                                            psum, psq);
    k_stats_reduce<<<64, 256, 0, stream>>>(psum, psq, colsum, colsq);
    // layer-1 BN fused into BOTH consumers (coarse_part + combine); k_bn_apply deleted
    k_coarse_part<<<CB_, 512, 0, stream>>>(sout, xbuf, h_cur, colsum, colsq,
                                           gam + 1 * 128, bet + 1 * 128, featb);
    k_coarse_reduce<<<50, 256, 0, stream>>>(featb, hc);
    k_combine<<<N_ / 16, 256, 0, stream>>>(sout, hc, xbuf, colsum, colsq,
                                           gam + 1 * 128, bet + 1 * 128, h_cur);

    // ---- layer 2 (H=8) ----
    k_gemm_mfma<<<N_ / 64, 256, 0, stream>>>(h_cur, WbT6 + 2 * 16384, nullptr, featw,
                                             WelT + 2 * 2048, el, er, 8,
                                             nullptr, nullptr, nullptr, nullptr,
                                             nullptr, nullptr, nullptr, 0,
                                             nullptr, nullptr);
    hipMemsetAsync(colsum, 0, 256 * sizeof(float), stream);
    k_gat_agg<8><<<AGGB_, 256, 0, stream>>>(featw, el, er, rowptr, srcv, bg + 2 * 128, xbuf,
                                            psum, psq);
    k_stats_reduce<<<64, 256, 0, stream>>>(psum, psq, colsum, colsq);

    // ---- layer 3 (H=1): gemm fused with layer-2 BN (writes h_cur) ----
    k_gemm_mfma<<<N_ / 64, 256, 0, stream>>>(nullptr, WbT6 + 3 * 16384, nullptr, featw,
                                             WelT + 3 * 2048, el, er, 1,
                                             xbuf, h_cur, colsum, colsq,
                                             gam + 2 * 128, bet + 2 * 128, h_cur, 1,
                                             nullptr, nullptr);
    hipMemsetAsync(colsum, 0, 256 * sizeof(float), stream);
    k_gat_agg<1><<<AGGB_, 256, 0, stream>>>(featw, el, er, rowptr, srcv, b3, xbuf,
                                            psum, psq);
    k_stats_reduce<<<64, 256, 0, stream>>>(psum, psq, colsum, colsq);

    // ---- edge MLP readout: ONE gemm (layer-3 BN fused) producing BOTH Pb and Qb ----
    short* Pb = (short*)featb;
    short* Qb = Pb + (size_t)N_ * 128;
    k_gemm_mfma<<<N_ / 64, 256, 0, stream>>>(nullptr, WbT6 + 4 * 16384, bm1, Pb,
                                             nullptr, nullptr, nullptr, 0,
                                             xbuf, h_cur, colsum, colsq,
                                             gam3, bet3, h_cur, 1,
                                             WbT6 + 5 * 16384, Qb);
    k_edge_mlp3<<<2048, 256, 0, stream>>>(Pb, Qb, srcv, dstv, eidv, Wm2T, bm2, Wm3, bm3, zout);
}

// Round 16
// 721.879 us; speedup vs baseline: 1.1303x; 1.0003x over previous
//
#include <hip/hip_runtime.h>
#include <hip/hip_bf16.h>
#include <math.h>

#define N_ 40000
#define E_ 640000
#define CB_ 400   // k_coarse partial blocks
#define CR_ 100   // rows per block (CB_*CR_ == N_)
#define SB_ 256
#define SNB_ 157  // ceil(N_/SB_)
#define AGGB_ 2048  // k_gat_agg grid (blocks); psum/psq sized to this

typedef short bf16x8 __attribute__((ext_vector_type(8)));
typedef float floatx4 __attribute__((ext_vector_type(4)));

__device__ __forceinline__ short f2bf(float f) {
    __hip_bfloat16 h = __float2bfloat16(f);
    return *reinterpret_cast<short*>(&h);
}
__device__ __forceinline__ float bf2f(short u) {
    unsigned int x = ((unsigned int)(unsigned short)u) << 16;
    return __int_as_float(x);
}
__device__ __forceinline__ float rdlane(float v, int l) {
    return __int_as_float(__builtin_amdgcn_readlane(__float_as_int(v), l));
}
// unpack 2 bf16 packed in a uint
__device__ __forceinline__ float bflo(unsigned int u) { return __int_as_float(u << 16); }
__device__ __forceinline__ float bfhi(unsigned int u) { return __int_as_float(u & 0xffff0000u); }

// ---------------- CSR build ----------------
__global__ void k_count(const int* __restrict__ dst, int* __restrict__ counts) {
    for (int e = blockIdx.x * blockDim.x + threadIdx.x; e < E_; e += gridDim.x * blockDim.x)
        atomicAdd(&counts[dst[e]], 1);
}

// ---- 3-phase parallel scan ----
__global__ __launch_bounds__(256) void k_scanA(const int* __restrict__ counts,
                                               int* __restrict__ excl,
                                               int* __restrict__ bsum) {
    int t = threadIdx.x;
    int i = blockIdx.x * SB_ + t;
    int v = (i < N_) ? counts[i] : 0;
    int lane = t & 63, wv = t >> 6;
    int x = v;
#pragma unroll
    for (int off = 1; off < 64; off <<= 1) {
        int y = __shfl_up(x, off);
        if (lane >= off) x += y;
    }
    __shared__ int wsum[4];
    __shared__ int woff[4];
    if (lane == 63) wsum[wv] = x;
    __syncthreads();
    if (t == 0) {
        int a = 0;
#pragma unroll
        for (int j = 0; j < 4; j++) { int tv = wsum[j]; woff[j] = a; a += tv; }
        bsum[blockIdx.x] = a;
    }
    __syncthreads();
    if (i < N_) excl[i] = x - v + woff[wv];
}

__global__ __launch_bounds__(256) void k_scanB(int* __restrict__ bsum) {
    int t = threadIdx.x;
    int v = (t < SNB_) ? bsum[t] : 0;
    int lane = t & 63, wv = t >> 6;
    int x = v;
#pragma unroll
    for (int off = 1; off < 64; off <<= 1) {
        int y = __shfl_up(x, off);
        if (lane >= off) x += y;
    }
    __shared__ int wsum[4];
    __shared__ int woff[4];
    if (lane == 63) wsum[wv] = x;
    __syncthreads();
    if (t == 0) {
        int a = 0;
#pragma unroll
        for (int j = 0; j < 4; j++) { int tv = wsum[j]; woff[j] = a; a += tv; }
    }
    __syncthreads();
    if (t < SNB_) bsum[t] = x - v + woff[wv];
}

__global__ __launch_bounds__(256) void k_scanC(const int* __restrict__ excl,
                                               const int* __restrict__ bsum,
                                               int* __restrict__ rowptr,
                                               int* __restrict__ cursor) {
    int i = blockIdx.x * 256 + threadIdx.x;
    if (i < N_) {
        int r = excl[i] + bsum[i / SB_];
        rowptr[i] = r;
        cursor[i] = r;
    }
    if (i == N_) rowptr[N_] = E_;
}

__global__ void k_fill(const int* __restrict__ src, const int* __restrict__ dst,
                       int* __restrict__ cursor, int* __restrict__ srcv,
                       unsigned short* __restrict__ dstv, int* __restrict__ eidv) {
    for (int e = blockIdx.x * blockDim.x + threadIdx.x; e < E_; e += gridDim.x * blockDim.x) {
        int d = dst[e];
        int pos = atomicAdd(&cursor[d], 1);
        srcv[pos] = src[e];
        dstv[pos] = (unsigned short)d;
        eidv[pos] = e;
    }
}

// ---------------- prep: 6x fp32 [k=128][n=128] -> bf16 [n][k] ----------------
__global__ __launch_bounds__(256) void k_prep_all(const float* __restrict__ Wg,
                                                  const float* __restrict__ W3,
                                                  const float* __restrict__ Wm1,
                                                  short* __restrict__ WbT6) {
    int i = blockIdx.x * 256 + threadIdx.x;   // 6*16384 total
    if (i >= 6 * 16384) return;
    int m = i >> 14;
    int r = i & 16383;
    int n = r >> 7, k = r & 127;
    const float* srcp;
    switch (m) {
        case 0: srcp = Wg; break;
        case 1: srcp = Wg + 16384; break;
        case 2: srcp = Wg + 32768; break;
        case 3: srcp = W3; break;
        case 4: srcp = Wm1; break;
        default: srcp = Wm1 + 16384; break;
    }
    WbT6[m * 16384 + n * 128 + k] = f2bf(srcp[k * 128 + n]);
}

// ---------------- prep: fused el/er weight tiles Wel[layer][16][128] ----------------
// el = (A@W)·al = A@(W@Aexp): Wel[n][k] = sum_d W[k][h*16+d]*a[h*16+d], h=n&7,
// a = al (n<8) or ar (n>=8). Layer 3 (H=1): n==0 -> W3·al3, n==1 -> W3·ar3, else 0.
__global__ __launch_bounds__(256) void k_prep_wela(const float* __restrict__ Wg,
                                                   const float* __restrict__ alg,
                                                   const float* __restrict__ arg_,
                                                   const float* __restrict__ W3,
                                                   const float* __restrict__ al3,
                                                   const float* __restrict__ ar3,
                                                   short* __restrict__ WelT) {
    int i = blockIdx.x * 256 + threadIdx.x;   // 4*16*128 = 8192 total
    if (i >= 4 * 2048) return;
    int layer = i >> 11;
    int r = i & 2047;
    int n = r >> 7, k = r & 127;
    float val = 0.f;
    if (layer < 3) {
        const float* W = Wg + layer * 16384;
        const float* a = (n < 8 ? alg : arg_) + layer * 128;
        int h = n & 7;
#pragma unroll
        for (int d = 0; d < 16; d++)
            val += W[k * 128 + h * 16 + d] * a[h * 16 + d];
    } else {
        if (n == 0) { for (int c = 0; c < 128; c++) val += W3[k * 128 + c] * al3[c]; }
        else if (n == 1) { for (int c = 0; c < 128; c++) val += W3[k * 128 + c] * ar3[c]; }
    }
    WelT[layer * 2048 + n * 128 + k] = f2bf(val);
}

// ---------------- prep: hi/lo bf16 splits of W_emb [128,128] and Wa [128,100] ----------------
// outputs transposed [n][k]; Wa zero-padded to n=128
__global__ __launch_bounds__(256) void k_prep_hilo(const float* __restrict__ W_emb,
                                                   const float* __restrict__ Wa,
                                                   short* __restrict__ WembT_hi,
                                                   short* __restrict__ WembT_lo,
                                                   short* __restrict__ WaT_hi,
                                                   short* __restrict__ WaT_lo) {
    int i = blockIdx.x * 256 + threadIdx.x;   // 2*16384 total
    if (i >= 2 * 16384) return;
    int m = i >> 14;
    int r = i & 16383;
    int n = r >> 7, k = r & 127;
    if (m == 0) {
        float w = W_emb[k * 128 + n];
        short h = f2bf(w);
        WembT_hi[n * 128 + k] = h;
        WembT_lo[n * 128 + k] = f2bf(w - bf2f(h));
    } else {
        float w = (n < 100) ? Wa[k * 100 + n] : 0.f;
        short h = f2bf(w);
        WaT_hi[n * 128 + k] = h;
        WaT_lo[n * 128 + k] = f2bf(w - bf2f(h));
    }
}

// ---------------- fp32-accurate MFMA GEMM via 3-term hi/lo split ----------------
__global__ __launch_bounds__(256) void k_mfma_hilo(const float* __restrict__ A,
                                                   const short* __restrict__ BT_hi,
                                                   const short* __restrict__ BT_lo,
                                                   const float* __restrict__ bias,
                                                   float* __restrict__ C, int ncols) {
    __shared__ short sAh[64 * 136];
    __shared__ short sAl[64 * 136];
    __shared__ short sBh[128 * 136];
    int t = threadIdx.x;
    int r0 = blockIdx.x * 64;
    // stage B_hi: each thread copies 64 bf16
    {
        int n = t >> 1;
        int k0 = (t & 1) * 64;
#pragma unroll
        for (int j = 0; j < 8; j++) {
            bf16x8 v = *(const bf16x8*)(BT_hi + n * 128 + k0 + 8 * j);
            *(bf16x8*)(sBh + n * 136 + k0 + 8 * j) = v;
        }
    }
    // stage A hi/lo: each thread converts 32 floats
    {
        int r = t >> 2;
        int k0 = (t & 3) * 32;
        const float* ar = A + (size_t)(r0 + r) * 128 + k0;
#pragma unroll
        for (int j = 0; j < 4; j++) {
            float4 f0 = *(const float4*)(ar + 8 * j);
            float4 f1 = *(const float4*)(ar + 8 * j + 4);
            float x[8] = {f0.x, f0.y, f0.z, f0.w, f1.x, f1.y, f1.z, f1.w};
            bf16x8 vh, vl;
#pragma unroll
            for (int q = 0; q < 8; q++) {
                short hh = f2bf(x[q]);
                vh[q] = hh;
                vl[q] = f2bf(x[q] - bf2f(hh));
            }
            *(bf16x8*)(sAh + r * 136 + k0 + 8 * j) = vh;
            *(bf16x8*)(sAl + r * 136 + k0 + 8 * j) = vl;
        }
    }
    __syncthreads();
    int lane = t & 63, wv = t >> 6;
    int lm = lane & 15, quad = lane >> 4;
    int m0 = wv * 16;
    bf16x8 aH[4], aL[4];
#pragma unroll
    for (int kt = 0; kt < 4; kt++) {
        aH[kt] = *(const bf16x8*)(sAh + (m0 + lm) * 136 + kt * 32 + quad * 8);
        aL[kt] = *(const bf16x8*)(sAl + (m0 + lm) * 136 + kt * 32 + quad * 8);
    }
#pragma unroll
    for (int nt = 0; nt < 8; nt++) {
        const short* blp = BT_lo + (nt * 16 + lm) * 128 + quad * 8;
        floatx4 acc = (floatx4){0.f, 0.f, 0.f, 0.f};
#pragma unroll
        for (int kt = 0; kt < 4; kt++) {
            bf16x8 bH = *(const bf16x8*)(sBh + (nt * 16 + lm) * 136 + kt * 32 + quad * 8);
            bf16x8 bL = *(const bf16x8*)(blp + kt * 32);
            acc = __builtin_amdgcn_mfma_f32_16x16x32_bf16(aH[kt], bH, acc, 0, 0, 0);
            acc = __builtin_amdgcn_mfma_f32_16x16x32_bf16(aL[kt], bH, acc, 0, 0, 0);
            acc = __builtin_amdgcn_mfma_f32_16x16x32_bf16(aH[kt], bL, acc, 0, 0, 0);
        }
        int col = nt * 16 + lm;
        if (col < ncols) {
            float bv = bias ? bias[col] : 0.f;
#pragma unroll
            for (int r = 0; r < 4; r++) {
                int row = r0 + m0 + quad * 4 + r;
                C[(size_t)row * ncols + col] = acc[r] + bv;
            }
        }
    }
}

// ---------------- MFMA GEMM: [N,128](fp32) @ WbT(bf16 [n][k]) -> bf16 out ----------------
// 64 rows/block, full N=128. A converted fp32->bf16 into LDS (+8 pad = 2-way bank, free).
// Optional fused el/er epilogue (r9) + BN prologue (r10) + second output (r13).
__global__ __launch_bounds__(256) void k_gemm_mfma(const float* __restrict__ A,
                                                   const short* __restrict__ WbT,
                                                   const float* __restrict__ bias,
                                                   short* __restrict__ C,
                                                   const short* __restrict__ WelT,
                                                   float* __restrict__ el,
                                                   float* __restrict__ er,
                                                   int H,
                                                   const float* __restrict__ bnx,
                                                   const float* __restrict__ bnh,
                                                   const float* __restrict__ csum,
                                                   const float* __restrict__ csq,
                                                   const float* __restrict__ bng,
                                                   const float* __restrict__ bnb,
                                                   float* __restrict__ hout,
                                                   int do_mask,
                                                   const short* __restrict__ WbT2,
                                                   short* __restrict__ C2) {
    __shared__ short sA[64 * 136];
    __shared__ short sB[128 * 136];
    __shared__ float sScale[128];
    __shared__ float sShift[128];
    int t = threadIdx.x;
    int r0 = blockIdx.x * 64;
    if (bnx) {
        if (t < 128) {
            const float invN = 1.f / (float)N_;
            float mu = csum[t] * invN;
            float var = csq[t] * invN - mu * mu;
            float inv = rsqrtf(var + 1e-5f);
            float sc = bng[t] * inv;
            sScale[t] = sc;
            sShift[t] = bnb[t] - mu * sc;
        }
        __syncthreads();
    }
    // stage B: each thread copies 64 bf16
    {
        int n = t >> 1;
        int k0 = (t & 1) * 64;
#pragma unroll
        for (int j = 0; j < 8; j++) {
            bf16x8 v = *(const bf16x8*)(WbT + n * 128 + k0 + 8 * j);
            *(bf16x8*)(sB + n * 136 + k0 + 8 * j) = v;
        }
    }
    // stage A: each thread handles 32 elements of one row-quarter
    {
        int r = t >> 2;
        int k0 = (t & 3) * 32;
        if (bnx) {
            const float* xr = bnx + (size_t)(r0 + r) * 128 + k0;
            const float* hr = bnh + (size_t)(r0 + r) * 128 + k0;
            float* ho = hout + (size_t)(r0 + r) * 128 + k0;
#pragma unroll
            for (int j = 0; j < 4; j++) {
                float4 x0 = *(const float4*)(xr + 8 * j);
                float4 x1 = *(const float4*)(xr + 8 * j + 4);
                float4 h0 = *(const float4*)(hr + 8 * j);
                float4 h1 = *(const float4*)(hr + 8 * j + 4);
                float xs[8] = {x0.x, x0.y, x0.z, x0.w, x1.x, x1.y, x1.z, x1.w};
                float hs[8] = {h0.x, h0.y, h0.z, h0.w, h1.x, h1.y, h1.z, h1.w};
                float ov[8];
                bf16x8 v;
#pragma unroll
                for (int q = 0; q < 8; q++) {
                    int c = k0 + 8 * j + q;
                    float y = sScale[c] * xs[q] + sShift[c];
                    y = y > 0.f ? y : (__expf(y) - 1.f);
                    float hv = hs[q] + y;
                    if (do_mask && isinf(hv)) hv = 1e9f;
                    ov[q] = hv;
                    v[q] = f2bf(hv);
                }
                *(float4*)(ho + 8 * j) = make_float4(ov[0], ov[1], ov[2], ov[3]);
                *(float4*)(ho + 8 * j + 4) = make_float4(ov[4], ov[5], ov[6], ov[7]);
                *(bf16x8*)(sA + r * 136 + k0 + 8 * j) = v;
            }
        } else {
            const float* ar = A + (size_t)(r0 + r) * 128 + k0;
#pragma unroll
            for (int j = 0; j < 4; j++) {
                float4 f0 = *(const float4*)(ar + 8 * j);
                float4 f1 = *(const float4*)(ar + 8 * j + 4);
                bf16x8 v;
                v[0] = f2bf(f0.x); v[1] = f2bf(f0.y); v[2] = f2bf(f0.z); v[3] = f2bf(f0.w);
                v[4] = f2bf(f1.x); v[5] = f2bf(f1.y); v[6] = f2bf(f1.z); v[7] = f2bf(f1.w);
                *(bf16x8*)(sA + r * 136 + k0 + 8 * j) = v;
            }
        }
    }
    __syncthreads();
    int lane = t & 63, wv = t >> 6;
    int lm = lane & 15, quad = lane >> 4;
    int m0 = wv * 16;
    bf16x8 aF[4];
#pragma unroll
    for (int kt = 0; kt < 4; kt++)
        aF[kt] = *(const bf16x8*)(sA + (m0 + lm) * 136 + kt * 32 + quad * 8);
#pragma unroll
    for (int nt = 0; nt < 8; nt++) {
        floatx4 acc = (floatx4){0.f, 0.f, 0.f, 0.f};
#pragma unroll
        for (int kt = 0; kt < 4; kt++) {
            bf16x8 bF = *(const bf16x8*)(sB + (nt * 16 + lm) * 136 + kt * 32 + quad * 8);
            acc = __builtin_amdgcn_mfma_f32_16x16x32_bf16(aF[kt], bF, acc, 0, 0, 0);
        }
        int col = nt * 16 + lm;
        float bv = bias ? bias[col] : 0.f;
#pragma unroll
        for (int r = 0; r < 4; r++) {
            int row = r0 + m0 + quad * 4 + r;
            C[(size_t)row * 128 + col] = f2bf(acc[r] + bv);
        }
    }
    // fused el/er tile: cols 0..7 = el heads, 8..15 = er heads (H=1: col0=el, col1=er)
    if (WelT) {
        floatx4 acc = (floatx4){0.f, 0.f, 0.f, 0.f};
#pragma unroll
        for (int kt = 0; kt < 4; kt++) {
            bf16x8 wF = *(const bf16x8*)(WelT + lm * 128 + kt * 32 + quad * 8);
            acc = __builtin_amdgcn_mfma_f32_16x16x32_bf16(aF[kt], wF, acc, 0, 0, 0);
        }
        if (H == 8) {
#pragma unroll
            for (int r = 0; r < 4; r++) {
                int row = r0 + m0 + quad * 4 + r;
                if (lm < 8) el[(size_t)row * 8 + lm] = acc[r];
                else        er[(size_t)row * 8 + (lm - 8)] = acc[r];
            }
        } else {
#pragma unroll
            for (int r = 0; r < 4; r++) {
                int row = r0 + m0 + quad * 4 + r;
                if (lm == 0) el[row] = acc[r];
                if (lm == 1) er[row] = acc[r];
            }
        }
    }
    // second output: re-stage sB, recompute with same aF (Pb/Qb merge)
    if (WbT2) {
        __syncthreads();   // all compute reads of sB complete
        {
            int n = t >> 1;
            int k0 = (t & 1) * 64;
#pragma unroll
            for (int j = 0; j < 8; j++) {
                bf16x8 v = *(const bf16x8*)(WbT2 + n * 128 + k0 + 8 * j);
                *(bf16x8*)(sB + n * 136 + k0 + 8 * j) = v;
            }
        }
        __syncthreads();
#pragma unroll
        for (int nt = 0; nt < 8; nt++) {
            floatx4 acc = (floatx4){0.f, 0.f, 0.f, 0.f};
#pragma unroll
            for (int kt = 0; kt < 4; kt++) {
                bf16x8 bF = *(const bf16x8*)(sB + (nt * 16 + lm) * 136 + kt * 32 + quad * 8);
                acc = __builtin_amdgcn_mfma_f32_16x16x32_bf16(aF[kt], bF, acc, 0, 0, 0);
            }
            int col = nt * 16 + lm;
#pragma unroll
            for (int r = 0; r < 4; r++) {
                int row = r0 + m0 + quad * 4 + r;
                C2[(size_t)row * 128 + col] = f2bf(acc[r]);
            }
        }
    }
}

// ---------------- softmax over 100 logits, wave per node, barrier-free ----------------
__global__ __launch_bounds__(256) void k_smax100(const float* __restrict__ logits,
                                                 float* __restrict__ s) {
    int lane = threadIdx.x & 63;
    int n = blockIdx.x * 4 + (threadIdx.x >> 6);
    if (n >= N_) return;
    bool act = lane < 50;
    float2 v = make_float2(-INFINITY, -INFINITY);
    if (act) v = *(const float2*)(logits + (size_t)n * 100 + 2 * lane);
    float mx = fmaxf(v.x, v.y);
#pragma unroll
    for (int off = 1; off < 64; off <<= 1) mx = fmaxf(mx, __shfl_xor(mx, off));
    float e0 = act ? __expf(v.x - mx) : 0.f;
    float e1 = act ? __expf(v.y - mx) : 0.f;
    float sm = e0 + e1;
#pragma unroll
    for (int off = 1; off < 64; off <<= 1) sm += __shfl_xor(sm, off);
    float inv = 1.f / sm;
    if (act) *(float2*)(s + (size_t)n * 100 + 2 * lane) = make_float2(e0 * inv, e1 * inv);
}

// ---------------- GAT edge-softmax + aggregate (wave per dst node, bf16 feat) ----------------
// v7 (r14, VALIDATED 729us): single-pass flash-style online softmax-aggregate.
// BN stats epilogue: per-block coalesced partials (r12, NO atomics).
template <int H>
__global__ __launch_bounds__(256) void k_gat_agg(const short* __restrict__ feat,
                                                 const float* __restrict__ el,
                                                 const float* __restrict__ er,
                                                 const int* __restrict__ rowptr,
                                                 const int* __restrict__ srcv,
                                                 const float* __restrict__ bias,
                                                 float* __restrict__ xout,
                                                 float* __restrict__ psum,
                                                 float* __restrict__ psq) {
    int t = threadIdx.x;
    int lane = t & 63;
    int gw = (blockIdx.x * blockDim.x + t) >> 6;
    int nw = (gridDim.x * blockDim.x) >> 6;
    int h = lane & (H - 1);
    int f0 = 2 * lane;
    int hf = (H == 8) ? (lane >> 3) : 0;   // head owning this lane's feature slice

    float stx = 0.f, sty = 0.f, qtx = 0.f, qty = 0.f;  // fused BN stats

    for (int n = gw; n < N_; n += nw) {
        int beg = rowptr[n], end = rowptr[n + 1];
        if (beg == end) {
            float2 b2 = *(const float2*)(bias + f0);
            *(float2*)(xout + (size_t)n * 128 + f0) = b2;
            stx += b2.x; sty += b2.y;
            qtx += b2.x * b2.x; qty += b2.y * b2.y;
            continue;
        }
        float ern = er[(size_t)n * H + h];
        int endm1 = end - 1;
        float m = -INFINITY, ss = 0.f;
        float accx = 0.f, accy = 0.f;
        for (int e0 = beg; e0 < end; e0 += 16) {
            int le = lane >> 3;
            int eLA = e0 + le, eLB = e0 + 8 + le;
            int eCA = eLA <= endm1 ? eLA : endm1;
            int eCB = eLB <= endm1 ? eLB : endm1;
            int sLA = srcv[eCA];
            int sLB = srcv[eCB];
            float xA = el[(size_t)sLA * H + h] + ern;
            float xB = el[(size_t)sLB * H + h] + ern;
            float lrA = xA > 0.f ? xA : 0.2f * xA;
            float lrB = xB > 0.f ? xB : 0.2f * xB;
            if (eLA > endm1) lrA = -INFINITY;
            if (eLB > endm1) lrB = -INFINITY;
            bool haveB = (e0 + 8) < end;    // wave-uniform
            unsigned int uuA[8], uuB[8];
#pragma unroll
            for (int j = 0; j < 8; j++) {
                int sj = __builtin_amdgcn_readlane(sLA, j * 8);
                uuA[j] = *(const unsigned int*)(feat + (size_t)sj * 128 + f0);
            }
            if (haveB) {
#pragma unroll
                for (int j = 0; j < 8; j++) {
                    int sj = __builtin_amdgcn_readlane(sLB, j * 8);
                    uuB[j] = *(const unsigned int*)(feat + (size_t)sj * 128 + f0);
                }
            }
#pragma unroll
            for (int j = 0; j < 8; j++) {
                float lj;
                if (H == 8) lj = __shfl(lrA, j * 8 + hf);
                else        lj = rdlane(lrA, j * 8);
                if (lj > m) {
                    float r = __expf(m - lj);   // m=-INF first time -> r=0 (acc,ss are 0)
                    accx *= r; accy *= r; ss *= r; m = lj;
                }
                float w = __expf(lj - m);       // lj=-INF (masked) -> w=0
                accx += w * bflo(uuA[j]);
                accy += w * bfhi(uuA[j]);
                ss += w;
            }
            if (haveB) {
#pragma unroll
                for (int j = 0; j < 8; j++) {
                    float lj;
                    if (H == 8) lj = __shfl(lrB, j * 8 + hf);
                    else        lj = rdlane(lrB, j * 8);
                    if (lj > m) {
                        float r = __expf(m - lj);
                        accx *= r; accy *= r; ss *= r; m = lj;
                    }
                    float w = __expf(lj - m);
                    accx += w * bflo(uuB[j]);
                    accy += w * bfhi(uuB[j]);
                    ss += w;
                }
            }
        }
        float inv_d = 1.f / ss;
        float2 b2 = *(const float2*)(bias + f0);
        float ox = accx * inv_d + b2.x, oy = accy * inv_d + b2.y;
        *(float2*)(xout + (size_t)n * 128 + f0) = make_float2(ox, oy);
        stx += ox; sty += oy;
        qtx += ox * ox; qty += oy * oy;
    }

    // ---- per-block partial stats: LDS reduce across 4 waves, coalesced plain store ----
    __shared__ float red[4][256];
    red[0][t] = stx; red[1][t] = sty; red[2][t] = qtx; red[3][t] = qty;
    __syncthreads();
    if (t < 64) {
        float a0 = red[0][t] + red[0][t + 64] + red[0][t + 128] + red[0][t + 192];
        float a1 = red[1][t] + red[1][t + 64] + red[1][t + 128] + red[1][t + 192];
        float q0 = red[2][t] + red[2][t + 64] + red[2][t + 128] + red[2][t + 192];
        float q1 = red[3][t] + red[3][t + 64] + red[3][t + 128] + red[3][t + 192];
        *(float2*)(psum + (size_t)blockIdx.x * 128 + 2 * t) = make_float2(a0, a1);
        *(float2*)(psq + (size_t)blockIdx.x * 128 + 2 * t) = make_float2(q0, q1);
    }
}

// ---------------- reduce per-block stats partials -> colsum/colsq ----------------
__global__ __launch_bounds__(256) void k_stats_reduce(const float* __restrict__ psum,
                                                      const float* __restrict__ psq,
                                                      float* __restrict__ colsum,
                                                      float* __restrict__ colsq) {
    __shared__ float ls[256], lq[256];
    int t = threadIdx.x;
    int col = t & 127, half = t >> 7;
    float s = 0.f, q = 0.f;
    for (int b = blockIdx.x * 2 + half; b < AGGB_; b += gridDim.x * 2) {
        s += psum[(size_t)b * 128 + col];
        q += psq[(size_t)b * 128 + col];
    }
    ls[t] = s; lq[t] = q;
    __syncthreads();
    if (t < 128) {
        atomicAdd(&colsum[col], ls[t] + ls[t + 128]);
        atomicAdd(&colsq[col], lq[t] + lq[t + 128]);
    }
}

// ---------------- h_coarse partials (layer-1 BN fused: hf = hprev + elu(bn(xraw))) ----------------
// v2 (r16): 1024 threads/block, split-K within block — half h processes nodes
// [h*50, h*50+50) of the block's 100-node chunk; half 1 dumps acc[25] to LDS and
// half 0 merges before the part write. Doubles waves/CU (12.5 -> ~25) in a
// latency-bound kernel with zero extra global traffic and no part-buffer growth.
__global__ __launch_bounds__(1024) void k_coarse_part(const float* __restrict__ s,
                                                      const float* __restrict__ xraw,
                                                      const float* __restrict__ hprev,
                                                      const float* __restrict__ csum,
                                                      const float* __restrict__ csq,
                                                      const float* __restrict__ bng,
                                                      const float* __restrict__ bnb,
                                                      float* __restrict__ part) {
    __shared__ float sSc[128], sSh[128];
    __shared__ float red[512 * 25];   // 51.2 KB
    int t = threadIdx.x;
    if (t < 128) {
        const float invN = 1.f / (float)N_;
        float mu = csum[t] * invN;
        float var = csq[t] * invN - mu * mu;
        float inv = rsqrtf(var + 1e-5f);
        float sc = bng[t] * inv;
        sSc[t] = sc;
        sSh[t] = bnb[t] - mu * sc;
    }
    __syncthreads();
    int tl = t & 511;          // position within half
    int half = t >> 9;         // 0 or 1
    int c = tl & 127;
    int g = (tl >> 7) & 3;     // 0..3 (25-assign group)
    int lane = t & 63;
    float scl = sSc[c], shf = sSh[c];
    float acc[25];
#pragma unroll
    for (int a = 0; a < 25; a++) acc[a] = 0.f;
    int n0 = blockIdx.x * CR_ + half * (CR_ / 2);
    for (int n = n0; n < n0 + CR_ / 2; n += 2) {
        float y0 = scl * xraw[(size_t)n * 128 + c] + shf;
        float y1 = scl * xraw[(size_t)(n + 1) * 128 + c] + shf;
        y0 = y0 > 0.f ? y0 : (__expf(y0) - 1.f);
        y1 = y1 > 0.f ? y1 : (__expf(y1) - 1.f);
        float hv0 = hprev[(size_t)n * 128 + c] + y0;
        float hv1 = hprev[(size_t)(n + 1) * 128 + c] + y1;
        float sv0 = 0.f, sv1 = 0.f;
        if (lane < 25) {
            sv0 = s[(size_t)n * 100 + 25 * g + lane];
            sv1 = s[(size_t)(n + 1) * 100 + 25 * g + lane];
        }
#pragma unroll
        for (int a = 0; a < 25; ++a) {
            float a0 = rdlane(sv0, a);
            float a1 = rdlane(sv1, a);
            acc[a] += a0 * hv0 + a1 * hv1;
        }
    }
    if (half == 1) {
#pragma unroll
        for (int a = 0; a < 25; a++) red[tl * 25 + a] = acc[a];
    }
    __syncthreads();
    if (half == 0) {
#pragma unroll
        for (int a = 0; a < 25; a++) acc[a] += red[tl * 25 + a];
        float* dstp = part + (size_t)blockIdx.x * 12800 + (size_t)(25 * g) * 128 + c;
#pragma unroll
        for (int a = 0; a < 25; a++) dstp[a * 128] = acc[a];
    }
}

// ---------------- reduce partials -> hc[100][128] ----------------
__global__ __launch_bounds__(256) void k_coarse_reduce(const float* __restrict__ part,
                                                       float* __restrict__ hc) {
    int i = blockIdx.x * blockDim.x + threadIdx.x;  // 12800 total
    if (i >= 12800) return;
    float s0 = 0.f, s1 = 0.f, s2 = 0.f, s3 = 0.f;
    for (int b = 0; b < CB_; b += 4) {
        s0 += part[(size_t)(b + 0) * 12800 + i];
        s1 += part[(size_t)(b + 1) * 12800 + i];
        s2 += part[(size_t)(b + 2) * 12800 + i];
        s3 += part[(size_t)(b + 3) * 12800 + i];
    }
    hc[i] = (s0 + s1) + (s2 + s3);
}

// ---------------- h = mask(0.5*h_fine + 0.5*(s@h_coarse)), layer-1 BN fused ----------------
// hfine computed inline: hprev + elu(bn(xraw)); writes h_cur in place (per-element RMW).
__global__ __launch_bounds__(256) void k_combine(const float* __restrict__ s,
                                                 const float* __restrict__ hc,
                                                 const float* __restrict__ xraw,
                                                 const float* __restrict__ csum,
                                                 const float* __restrict__ csq,
                                                 const float* __restrict__ bng,
                                                 const float* __restrict__ bnb,
                                                 float* __restrict__ hout) {
    __shared__ float ssh[16 * 100];
    __shared__ float sSc[128], sSh[128];
    int t = threadIdx.x;
    int n0 = blockIdx.x * 16;
    if (t < 128) {
        const float invN = 1.f / (float)N_;
        float mu = csum[t] * invN;
        float var = csq[t] * invN - mu * mu;
        float inv = rsqrtf(var + 1e-5f);
        float sc = bng[t] * inv;
        sSc[t] = sc;
        sSh[t] = bnb[t] - mu * sc;
    }
    for (int u = t; u < 1600; u += 256) ssh[u] = s[(size_t)n0 * 100 + u];
    __syncthreads();
    int c = t & 127, g = t >> 7;
    float scl = sSc[c], shf = sSh[c];
    float acc[8];
#pragma unroll
    for (int r = 0; r < 8; r++) acc[r] = 0.f;
    const float* hcp = hc + c;
    for (int a = 0; a < 100; a += 4) {
        float h0 = hcp[(a + 0) * 128];
        float h1 = hcp[(a + 1) * 128];
        float h2 = hcp[(a + 2) * 128];
        float h3 = hcp[(a + 3) * 128];
#pragma unroll
        for (int r = 0; r < 8; r++) {
            float4 sv = *(const float4*)(ssh + (g * 8 + r) * 100 + a);
            acc[r] += sv.x * h0 + sv.y * h1 + sv.z * h2 + sv.w * h3;
        }
    }
#pragma unroll
    for (int r = 0; r < 8; r++) {
        int row = n0 + g * 8 + r;
        float y = scl * xraw[(size_t)row * 128 + c] + shf;
        y = y > 0.f ? y : (__expf(y) - 1.f);
        float hfine = hout[(size_t)row * 128 + c] + y;   // hout holds h_prev here
        float v = 0.5f * hfine + 0.5f * acc[r];
        if (isinf(v)) v = 1e9f;
        hout[(size_t)row * 128 + c] = v;
    }
}

// ---------------- prep: Wm2 [128][64] fp32 -> Wm2T bf16 [64][128] ----------------
__global__ __launch_bounds__(256) void k_prep_w(const float* __restrict__ Wm2,
                                                short* __restrict__ Wm2T) {
    int i = blockIdx.x * blockDim.x + threadIdx.x;  // 8192 total
    if (i >= 64 * 128) return;
    int n = i & 63, k = i >> 6;
    Wm2T[n * 128 + k] = f2bf(Wm2[k * 64 + n]);
}

// ---------------- edge MLP readout: dst-sorted order, barrier-free persistent MFMA ----------------
// v2 — LOCAL OPTIMUM at ~54us, VGPR 84. Do not register-diet (v3: spills, 3x dur).
// Do not 2-tile (v4: compiler serializes the B-tile loads, occupancy drops, +6us).
__global__ __launch_bounds__(256) void k_edge_mlp3(const short* __restrict__ Pb,
                                                   const short* __restrict__ Qb,
                                                   const int* __restrict__ srcv,
                                                   const unsigned short* __restrict__ dstv,
                                                   const int* __restrict__ eidv,
                                                   const short* __restrict__ Wm2T,
                                                   const float* __restrict__ bm2,
                                                   const float* __restrict__ Wm3,
                                                   const float* __restrict__ bm3,
                                                   float* __restrict__ zout) {
    __shared__ short sW[64 * 128];  // 16 KiB
    int t = threadIdx.x;
    // stage Wm2T -> LDS with 16B-unit XOR swizzle: phys_unit = n*16 + (k16 ^ (n&15))
    for (int u = t; u < 1024; u += 256) {
        int n = u >> 4, k16 = u & 15;
        int phys = (n << 4) | (k16 ^ (n & 15));
        *(bf16x8*)(sW + phys * 8) = *(const bf16x8*)(Wm2T + n * 128 + k16 * 8);
    }
    int lane = t & 63;
    int lm = lane & 15, quad = lane >> 4;
    float bv[4], w30[4], w31[4];
#pragma unroll
    for (int nt = 0; nt < 4; nt++) {
        int n = nt * 16 + lm;
        bv[nt] = bm2[n]; w30[nt] = Wm3[2 * n]; w31[nt] = Wm3[2 * n + 1];
    }
    float b30 = bm3[0], b31 = bm3[1];
    __syncthreads();

    int gw = (blockIdx.x * blockDim.x + t) >> 6;
    int nw = (gridDim.x * blockDim.x) >> 6;

    for (int tile = gw; tile < E_ / 16; tile += nw) {
        int p0 = tile * 16;
        int sI = srcv[p0 + lm];
        int dI = (int)dstv[p0 + lm];
        const short* pr = Pb + (size_t)sI * 128 + quad * 8;
        const short* qr = Qb + (size_t)dI * 128 + quad * 8;
        // issue all 8 gathers up-front (latency hidden within wave)
        uint4 pu[4], qu[4];
#pragma unroll
        for (int kt = 0; kt < 4; kt++) {
            pu[kt] = *(const uint4*)(pr + kt * 32);
            qu[kt] = *(const uint4*)(qr + kt * 32);
        }
        bf16x8 aF[4];
#pragma unroll
        for (int kt = 0; kt < 4; kt++) {
            unsigned int pv[4] = {pu[kt].x, pu[kt].y, pu[kt].z, pu[kt].w};
            unsigned int qv[4] = {qu[kt].x, qu[kt].y, qu[kt].z, qu[kt].w};
            union { uint4 u; bf16x8 v; } cv;
            unsigned int rr[4];
#pragma unroll
            for (int j = 0; j < 4; j++) {
                float fl = fmaxf(bflo(pv[j]) + bflo(qv[j]), 0.f);
                float fh = fmaxf(bfhi(pv[j]) + bfhi(qv[j]), 0.f);
                rr[j] = (unsigned int)(unsigned short)f2bf(fl) |
                        ((unsigned int)(unsigned short)f2bf(fh) << 16);
            }
            cv.u.x = rr[0]; cv.u.y = rr[1]; cv.u.z = rr[2]; cv.u.w = rr[3];
            aF[kt] = cv.v;
        }
        float pz0[4] = {0.f, 0.f, 0.f, 0.f};
        float pz1[4] = {0.f, 0.f, 0.f, 0.f};
#pragma unroll
        for (int nt = 0; nt < 4; nt++) {
            floatx4 acc = (floatx4){0.f, 0.f, 0.f, 0.f};
#pragma unroll
            for (int kt = 0; kt < 4; kt++) {
                int phys = ((nt * 16 + lm) << 4) | (((kt << 2) | quad) ^ lm);
                bf16x8 bF = *(const bf16x8*)(sW + phys * 8);
                acc = __builtin_amdgcn_mfma_f32_16x16x32_bf16(aF[kt], bF, acc, 0, 0, 0);
            }
#pragma unroll
            for (int r = 0; r < 4; r++) {
                float u = fmaxf(acc[r] + bv[nt], 0.f);
                pz0[r] += u * w30[nt];
                pz1[r] += u * w31[nt];
            }
        }
#pragma unroll
        for (int off = 1; off < 16; off <<= 1) {
#pragma unroll
            for (int r = 0; r < 4; r++) {
                pz0[r] += __shfl_xor(pz0[r], off);
                pz1[r] += __shfl_xor(pz1[r], off);
            }
        }
        if (lm < 4) {
            int eid = eidv[p0 + quad * 4 + lm];
            float z0 = pz0[lm] + b30;
            float z1 = pz1[lm] + b31;
            if (isinf(z0)) z0 = 1e9f;
            if (isinf(z1)) z1 = 1e9f;
            *(float2*)(zout + (size_t)eid * 2) = make_float2(z0, z1);
        }
    }
}

extern "C" void kernel_launch(void* const* d_in, const int* in_sizes, int n_in,
                              void* d_out, int out_size, void* d_ws, size_t ws_size,
                              hipStream_t stream) {
    const float* h_in  = (const float*)d_in[0];
    const int*   src   = (const int*)d_in[2];
    const int*   dst   = (const int*)d_in[3];
    const float* W_emb = (const float*)d_in[4];
    const float* b_emb = (const float*)d_in[5];
    const float* Wg    = (const float*)d_in[6];
    const float* alg   = (const float*)d_in[7];
    const float* arg_  = (const float*)d_in[8];
    const float* bg    = (const float*)d_in[9];
    const float* gam   = (const float*)d_in[10];
    const float* bet   = (const float*)d_in[11];
    const float* W3    = (const float*)d_in[12];
    const float* al3   = (const float*)d_in[13];
    const float* ar3   = (const float*)d_in[14];
    const float* b3    = (const float*)d_in[15];
    const float* gam3  = (const float*)d_in[16];
    const float* bet3  = (const float*)d_in[17];
    const float* Wa    = (const float*)d_in[18];
    const float* ba    = (const float*)d_in[19];
    const float* Wm1   = (const float*)d_in[20];
    const float* bm1   = (const float*)d_in[21];
    const float* Wm2   = (const float*)d_in[22];
    const float* bm2   = (const float*)d_in[23];
    const float* Wm3   = (const float*)d_in[24];
    const float* bm3   = (const float*)d_in[25];

    float* zout = (float*)d_out;
    float* sout = zout + (size_t)E_ * 2;

    float* ws = (float*)d_ws;
    size_t o = 0;
    float* h_cur = ws + o; o += (size_t)N_ * 128;
    float* xbuf  = ws + o; o += (size_t)N_ * 128;
    float* featb = ws + o; o += (size_t)N_ * 128;   // reused: bf16 feat, coarse partials, bf16 P/Q
    float* el    = ws + o; o += (size_t)N_ * 8;
    float* er    = ws + o; o += (size_t)N_ * 8;
    float* colsum = ws + o; o += 128;
    float* colsq  = ws + o; o += 128;
    float* hc     = ws + o; o += 100 * 128;
    float* psum   = ws + o; o += (size_t)AGGB_ * 128;
    float* psq    = ws + o; o += (size_t)AGGB_ * 128;
    short* Wm2T = (short*)(ws + o); o += (64 * 128) / 2;
    short* WbT6 = (short*)(ws + o); o += (6 * 16384) / 2;
    short* WelT = (short*)(ws + o); o += (4 * 2048) / 2;
    short* WembT_hi = (short*)(ws + o); o += 16384 / 2;
    short* WembT_lo = (short*)(ws + o); o += 16384 / 2;
    short* WaT_hi   = (short*)(ws + o); o += 16384 / 2;
    short* WaT_lo   = (short*)(ws + o); o += 16384 / 2;
    int* counts = (int*)(ws + o); o += N_;
    int* rowptr = (int*)(ws + o); o += N_ + 4;
    int* cursor = (int*)(ws + o); o += N_;
    int* srcv   = (int*)(ws + o); o += E_;
    unsigned short* dstv = (unsigned short*)(ws + o); o += E_ / 2;
    int* eidv   = (int*)(ws + o); o += E_;
    int* bsum   = (int*)(ws + o); o += SNB_ + 4;

    short* featw = (short*)featb;  // bf16 per-layer projection

    // ---- CSR build (parallel scan; excl scratch reuses eidv pre-fill) ----
    hipMemsetAsync(counts, 0, N_ * sizeof(int), stream);
    k_count<<<1024, 256, 0, stream>>>(dst, counts);
    k_scanA<<<SNB_, 256, 0, stream>>>(counts, eidv, bsum);
    k_scanB<<<1, 256, 0, stream>>>(bsum);
    k_scanC<<<SNB_ + 1, 256, 0, stream>>>(eidv, bsum, rowptr, cursor);
    k_fill<<<1024, 256, 0, stream>>>(src, dst, cursor, srcv, dstv, eidv);
    k_prep_w<<<32, 256, 0, stream>>>(Wm2, Wm2T);
    k_prep_all<<<384, 256, 0, stream>>>(Wg, W3, Wm1, WbT6);
    k_prep_wela<<<32, 256, 0, stream>>>(Wg, alg, arg_, W3, al3, ar3, WelT);
    k_prep_hilo<<<128, 256, 0, stream>>>(W_emb, Wa, WembT_hi, WembT_lo, WaT_hi, WaT_lo);

    // ---- embedding (fp32-accurate via hi/lo MFMA) ----
    k_mfma_hilo<<<N_ / 64, 256, 0, stream>>>(h_in, WembT_hi, WembT_lo, b_emb, h_cur, 128);

    // ---- layer 0 (H=8) ----
    k_gemm_mfma<<<N_ / 64, 256, 0, stream>>>(h_cur, WbT6 + 0 * 16384, nullptr, featw,
                                             WelT + 0 * 2048, el, er, 8,
                                             nullptr, nullptr, nullptr, nullptr,
                                             nullptr, nullptr, nullptr, 0,
                                             nullptr, nullptr);
    hipMemsetAsync(colsum, 0, 256 * sizeof(float), stream);
    k_gat_agg<8><<<AGGB_, 256, 0, stream>>>(featw, el, er, rowptr, srcv, bg + 0 * 128, xbuf,
                                            psum, psq);
    k_stats_reduce<<<64, 256, 0, stream>>>(psum, psq, colsum, colsq);

    // ---- layer 1 (biGAT, H=8): gemm fused with layer-0 BN (writes h_cur) ----
    k_gemm_mfma<<<N_ / 64, 256, 0, stream>>>(nullptr, WbT6 + 1 * 16384, nullptr, featw,
                                             WelT + 1 * 2048, el, er, 8,
                                             xbuf, h_cur, colsum, colsq,
                                             gam + 0 * 128, bet + 0 * 128, h_cur, 1,
                                             nullptr, nullptr);
    k_mfma_hilo<<<N_ / 64, 256, 0, stream>>>(h_cur, WaT_hi, WaT_lo, ba, xbuf, 100);
    k_smax100<<<N_ / 4, 256, 0, stream>>>(xbuf, sout);
    hipMemsetAsync(colsum, 0, 256 * sizeof(float), stream);
    k_gat_agg<8><<<AGGB_, 256, 0, stream>>>(featw, el, er, rowptr, srcv, bg + 1 * 128, xbuf,
                                            psum, psq);
    k_stats_reduce<<<64, 256, 0, stream>>>(psum, psq, colsum, colsq);
    // layer-1 BN fused into BOTH consumers (coarse_part + combine); k_bn_apply deleted
    k_coarse_part<<<CB_, 1024, 0, stream>>>(sout, xbuf, h_cur, colsum, colsq,
                                            gam + 1 * 128, bet + 1 * 128, featb);
    k_coarse_reduce<<<50, 256, 0, stream>>>(featb, hc);
    k_combine<<<N_ / 16, 256, 0, stream>>>(sout, hc, xbuf, colsum, colsq,
                                           gam + 1 * 128, bet + 1 * 128, h_cur);

    // ---- layer 2 (H=8) ----
    k_gemm_mfma<<<N_ / 64, 256, 0, stream>>>(h_cur, WbT6 + 2 * 16384, nullptr, featw,
                                             WelT + 2 * 2048, el, er, 8,
                                             nullptr, nullptr, nullptr, nullptr,
                                             nullptr, nullptr, nullptr, 0,
                                             nullptr, nullptr);
    hipMemsetAsync(colsum, 0, 256 * sizeof(float), stream);
    k_gat_agg<8><<<AGGB_, 256, 0, stream>>>(featw, el, er, rowptr, srcv, bg + 2 * 128, xbuf,
                                            psum, psq);
    k_stats_reduce<<<64, 256, 0, stream>>>(psum, psq, colsum, colsq);

    // ---- layer 3 (H=1): gemm fused with layer-2 BN (writes h_cur) ----
    k_gemm_mfma<<<N_ / 64, 256, 0, stream>>>(nullptr, WbT6 + 3 * 16384, nullptr, featw,
                                             WelT + 3 * 2048, el, er, 1,
                                             xbuf, h_cur, colsum, colsq,
                                             gam + 2 * 128, bet + 2 * 128, h_cur, 1,
                                             nullptr, nullptr);
    hipMemsetAsync(colsum, 0, 256 * sizeof(float), stream);
    k_gat_agg<1><<<AGGB_, 256, 0, stream>>>(featw, el, er, rowptr, srcv, b3, xbuf,
                                            psum, psq);
    k_stats_reduce<<<64, 256, 0, stream>>>(psum, psq, colsum, colsq);

    // ---- edge MLP readout: ONE gemm (layer-3 BN fused) producing BOTH Pb and Qb ----
    short* Pb = (short*)featb;
    short* Qb = Pb + (size_t)N_ * 128;
    k_gemm_mfma<<<N_ / 64, 256, 0, stream>>>(nullptr, WbT6 + 4 * 16384, bm1, Pb,
                                             nullptr, nullptr, nullptr, 0,
                                             xbuf, h_cur, colsum, colsq,
                                             gam3, bet3, h_cur, 1,
                                             WbT6 + 5 * 16384, Qb);
    k_edge_mlp3<<<2048, 256, 0, stream>>>(Pb, Qb, srcv, dstv, eidv, Wm2T, bm2, Wm3, bm3, zout);
}

// Round 17
// 702.510 us; speedup vs baseline: 1.1614x; 1.0276x over previous
//
#include <hip/hip_runtime.h>
#include <hip/hip_bf16.h>
#include <math.h>

#define N_ 40000
#define E_ 640000
#define CPB_ 250  // coarse MFMA blocks (250 x 5 chunks x 32 nodes = 40000)
#define SB_ 256
#define SNB_ 157  // ceil(N_/SB_)
#define AGGB_ 2048  // k_gat_agg grid (blocks); psum/psq sized to this

typedef short bf16x8 __attribute__((ext_vector_type(8)));
typedef float floatx4 __attribute__((ext_vector_type(4)));

__device__ __forceinline__ short f2bf(float f) {
    __hip_bfloat16 h = __float2bfloat16(f);
    return *reinterpret_cast<short*>(&h);
}
__device__ __forceinline__ float bf2f(short u) {
    unsigned int x = ((unsigned int)(unsigned short)u) << 16;
    return __int_as_float(x);
}
__device__ __forceinline__ float rdlane(float v, int l) {
    return __int_as_float(__builtin_amdgcn_readlane(__float_as_int(v), l));
}
// unpack 2 bf16 packed in a uint
__device__ __forceinline__ float bflo(unsigned int u) { return __int_as_float(u << 16); }
__device__ __forceinline__ float bfhi(unsigned int u) { return __int_as_float(u & 0xffff0000u); }

// ---------------- CSR build ----------------
__global__ void k_count(const int* __restrict__ dst, int* __restrict__ counts) {
    for (int e = blockIdx.x * blockDim.x + threadIdx.x; e < E_; e += gridDim.x * blockDim.x)
        atomicAdd(&counts[dst[e]], 1);
}

// ---- 3-phase parallel scan ----
__global__ __launch_bounds__(256) void k_scanA(const int* __restrict__ counts,
                                               int* __restrict__ excl,
                                               int* __restrict__ bsum) {
    int t = threadIdx.x;
    int i = blockIdx.x * SB_ + t;
    int v = (i < N_) ? counts[i] : 0;
    int lane = t & 63, wv = t >> 6;
    int x = v;
#pragma unroll
    for (int off = 1; off < 64; off <<= 1) {
        int y = __shfl_up(x, off);
        if (lane >= off) x += y;
    }
    __shared__ int wsum[4];
    __shared__ int woff[4];
    if (lane == 63) wsum[wv] = x;
    __syncthreads();
    if (t == 0) {
        int a = 0;
#pragma unroll
        for (int j = 0; j < 4; j++) { int tv = wsum[j]; woff[j] = a; a += tv; }
        bsum[blockIdx.x] = a;
    }
    __syncthreads();
    if (i < N_) excl[i] = x - v + woff[wv];
}

__global__ __launch_bounds__(256) void k_scanB(int* __restrict__ bsum) {
    int t = threadIdx.x;
    int v = (t < SNB_) ? bsum[t] : 0;
    int lane = t & 63, wv = t >> 6;
    int x = v;
#pragma unroll
    for (int off = 1; off < 64; off <<= 1) {
        int y = __shfl_up(x, off);
        if (lane >= off) x += y;
    }
    __shared__ int wsum[4];
    __shared__ int woff[4];
    if (lane == 63) wsum[wv] = x;
    __syncthreads();
    if (t == 0) {
        int a = 0;
#pragma unroll
        for (int j = 0; j < 4; j++) { int tv = wsum[j]; woff[j] = a; a += tv; }
    }
    __syncthreads();
    if (t < SNB_) bsum[t] = x - v + woff[wv];
}

__global__ __launch_bounds__(256) void k_scanC(const int* __restrict__ excl,
                                               const int* __restrict__ bsum,
                                               int* __restrict__ rowptr,
                                               int* __restrict__ cursor) {
    int i = blockIdx.x * 256 + threadIdx.x;
    if (i < N_) {
        int r = excl[i] + bsum[i / SB_];
        rowptr[i] = r;
        cursor[i] = r;
    }
    if (i == N_) rowptr[N_] = E_;
}

__global__ void k_fill(const int* __restrict__ src, const int* __restrict__ dst,
                       int* __restrict__ cursor, int* __restrict__ srcv,
                       unsigned short* __restrict__ dstv, int* __restrict__ eidv) {
    for (int e = blockIdx.x * blockDim.x + threadIdx.x; e < E_; e += gridDim.x * blockDim.x) {
        int d = dst[e];
        int pos = atomicAdd(&cursor[d], 1);
        srcv[pos] = src[e];
        dstv[pos] = (unsigned short)d;
        eidv[pos] = e;
    }
}

// ---------------- prep: 6x fp32 [k=128][n=128] -> bf16 [n][k] ----------------
__global__ __launch_bounds__(256) void k_prep_all(const float* __restrict__ Wg,
                                                  const float* __restrict__ W3,
                                                  const float* __restrict__ Wm1,
                                                  short* __restrict__ WbT6) {
    int i = blockIdx.x * 256 + threadIdx.x;   // 6*16384 total
    if (i >= 6 * 16384) return;
    int m = i >> 14;
    int r = i & 16383;
    int n = r >> 7, k = r & 127;
    const float* srcp;
    switch (m) {
        case 0: srcp = Wg; break;
        case 1: srcp = Wg + 16384; break;
        case 2: srcp = Wg + 32768; break;
        case 3: srcp = W3; break;
        case 4: srcp = Wm1; break;
        default: srcp = Wm1 + 16384; break;
    }
    WbT6[m * 16384 + n * 128 + k] = f2bf(srcp[k * 128 + n]);
}

// ---------------- prep: fused el/er weight tiles Wel[layer][16][128] ----------------
__global__ __launch_bounds__(256) void k_prep_wela(const float* __restrict__ Wg,
                                                   const float* __restrict__ alg,
                                                   const float* __restrict__ arg_,
                                                   const float* __restrict__ W3,
                                                   const float* __restrict__ al3,
                                                   const float* __restrict__ ar3,
                                                   short* __restrict__ WelT) {
    int i = blockIdx.x * 256 + threadIdx.x;   // 4*16*128 = 8192 total
    if (i >= 4 * 2048) return;
    int layer = i >> 11;
    int r = i & 2047;
    int n = r >> 7, k = r & 127;
    float val = 0.f;
    if (layer < 3) {
        const float* W = Wg + layer * 16384;
        const float* a = (n < 8 ? alg : arg_) + layer * 128;
        int h = n & 7;
#pragma unroll
        for (int d = 0; d < 16; d++)
            val += W[k * 128 + h * 16 + d] * a[h * 16 + d];
    } else {
        if (n == 0) { for (int c = 0; c < 128; c++) val += W3[k * 128 + c] * al3[c]; }
        else if (n == 1) { for (int c = 0; c < 128; c++) val += W3[k * 128 + c] * ar3[c]; }
    }
    WelT[layer * 2048 + n * 128 + k] = f2bf(val);
}

// ---------------- prep: hi/lo bf16 splits of W_emb [128,128] and Wa [128,100] ----------------
__global__ __launch_bounds__(256) void k_prep_hilo(const float* __restrict__ W_emb,
                                                   const float* __restrict__ Wa,
                                                   short* __restrict__ WembT_hi,
                                                   short* __restrict__ WembT_lo,
                                                   short* __restrict__ WaT_hi,
                                                   short* __restrict__ WaT_lo) {
    int i = blockIdx.x * 256 + threadIdx.x;   // 2*16384 total
    if (i >= 2 * 16384) return;
    int m = i >> 14;
    int r = i & 16383;
    int n = r >> 7, k = r & 127;
    if (m == 0) {
        float w = W_emb[k * 128 + n];
        short h = f2bf(w);
        WembT_hi[n * 128 + k] = h;
        WembT_lo[n * 128 + k] = f2bf(w - bf2f(h));
    } else {
        float w = (n < 100) ? Wa[k * 100 + n] : 0.f;
        short h = f2bf(w);
        WaT_hi[n * 128 + k] = h;
        WaT_lo[n * 128 + k] = f2bf(w - bf2f(h));
    }
}

// ---------------- fp32-accurate MFMA GEMM via 3-term hi/lo split ----------------
__global__ __launch_bounds__(256) void k_mfma_hilo(const float* __restrict__ A,
                                                   const short* __restrict__ BT_hi,
                                                   const short* __restrict__ BT_lo,
                                                   const float* __restrict__ bias,
                                                   float* __restrict__ C, int ncols) {
    __shared__ short sAh[64 * 136];
    __shared__ short sAl[64 * 136];
    __shared__ short sBh[128 * 136];
    int t = threadIdx.x;
    int r0 = blockIdx.x * 64;
    // stage B_hi: each thread copies 64 bf16
    {
        int n = t >> 1;
        int k0 = (t & 1) * 64;
#pragma unroll
        for (int j = 0; j < 8; j++) {
            bf16x8 v = *(const bf16x8*)(BT_hi + n * 128 + k0 + 8 * j);
            *(bf16x8*)(sBh + n * 136 + k0 + 8 * j) = v;
        }
    }
    // stage A hi/lo: each thread converts 32 floats
    {
        int r = t >> 2;
        int k0 = (t & 3) * 32;
        const float* ar = A + (size_t)(r0 + r) * 128 + k0;
#pragma unroll
        for (int j = 0; j < 4; j++) {
            float4 f0 = *(const float4*)(ar + 8 * j);
            float4 f1 = *(const float4*)(ar + 8 * j + 4);
            float x[8] = {f0.x, f0.y, f0.z, f0.w, f1.x, f1.y, f1.z, f1.w};
            bf16x8 vh, vl;
#pragma unroll
            for (int q = 0; q < 8; q++) {
                short hh = f2bf(x[q]);
                vh[q] = hh;
                vl[q] = f2bf(x[q] - bf2f(hh));
            }
            *(bf16x8*)(sAh + r * 136 + k0 + 8 * j) = vh;
            *(bf16x8*)(sAl + r * 136 + k0 + 8 * j) = vl;
        }
    }
    __syncthreads();
    int lane = t & 63, wv = t >> 6;
    int lm = lane & 15, quad = lane >> 4;
    int m0 = wv * 16;
    bf16x8 aH[4], aL[4];
#pragma unroll
    for (int kt = 0; kt < 4; kt++) {
        aH[kt] = *(const bf16x8*)(sAh + (m0 + lm) * 136 + kt * 32 + quad * 8);
        aL[kt] = *(const bf16x8*)(sAl + (m0 + lm) * 136 + kt * 32 + quad * 8);
    }
#pragma unroll
    for (int nt = 0; nt < 8; nt++) {
        const short* blp = BT_lo + (nt * 16 + lm) * 128 + quad * 8;
        floatx4 acc = (floatx4){0.f, 0.f, 0.f, 0.f};
#pragma unroll
        for (int kt = 0; kt < 4; kt++) {
            bf16x8 bH = *(const bf16x8*)(sBh + (nt * 16 + lm) * 136 + kt * 32 + quad * 8);
            bf16x8 bL = *(const bf16x8*)(blp + kt * 32);
            acc = __builtin_amdgcn_mfma_f32_16x16x32_bf16(aH[kt], bH, acc, 0, 0, 0);
            acc = __builtin_amdgcn_mfma_f32_16x16x32_bf16(aL[kt], bH, acc, 0, 0, 0);
            acc = __builtin_amdgcn_mfma_f32_16x16x32_bf16(aH[kt], bL, acc, 0, 0, 0);
        }
        int col = nt * 16 + lm;
        if (col < ncols) {
            float bv = bias ? bias[col] : 0.f;
#pragma unroll
            for (int r = 0; r < 4; r++) {
                int row = r0 + m0 + quad * 4 + r;
                C[(size_t)row * ncols + col] = acc[r] + bv;
            }
        }
    }
}

// ---------------- MFMA GEMM: [N,128](fp32) @ WbT(bf16 [n][k]) -> bf16 out ----------------
// Optional fused el/er epilogue (r9) + BN prologue (r10) + second output (r13).
__global__ __launch_bounds__(256) void k_gemm_mfma(const float* __restrict__ A,
                                                   const short* __restrict__ WbT,
                                                   const float* __restrict__ bias,
                                                   short* __restrict__ C,
                                                   const short* __restrict__ WelT,
                                                   float* __restrict__ el,
                                                   float* __restrict__ er,
                                                   int H,
                                                   const float* __restrict__ bnx,
                                                   const float* __restrict__ bnh,
                                                   const float* __restrict__ csum,
                                                   const float* __restrict__ csq,
                                                   const float* __restrict__ bng,
                                                   const float* __restrict__ bnb,
                                                   float* __restrict__ hout,
                                                   int do_mask,
                                                   const short* __restrict__ WbT2,
                                                   short* __restrict__ C2) {
    __shared__ short sA[64 * 136];
    __shared__ short sB[128 * 136];
    __shared__ float sScale[128];
    __shared__ float sShift[128];
    int t = threadIdx.x;
    int r0 = blockIdx.x * 64;
    if (bnx) {
        if (t < 128) {
            const float invN = 1.f / (float)N_;
            float mu = csum[t] * invN;
            float var = csq[t] * invN - mu * mu;
            float inv = rsqrtf(var + 1e-5f);
            float sc = bng[t] * inv;
            sScale[t] = sc;
            sShift[t] = bnb[t] - mu * sc;
        }
        __syncthreads();
    }
    // stage B: each thread copies 64 bf16
    {
        int n = t >> 1;
        int k0 = (t & 1) * 64;
#pragma unroll
        for (int j = 0; j < 8; j++) {
            bf16x8 v = *(const bf16x8*)(WbT + n * 128 + k0 + 8 * j);
            *(bf16x8*)(sB + n * 136 + k0 + 8 * j) = v;
        }
    }
    // stage A: each thread handles 32 elements of one row-quarter
    {
        int r = t >> 2;
        int k0 = (t & 3) * 32;
        if (bnx) {
            const float* xr = bnx + (size_t)(r0 + r) * 128 + k0;
            const float* hr = bnh + (size_t)(r0 + r) * 128 + k0;
            float* ho = hout + (size_t)(r0 + r) * 128 + k0;
#pragma unroll
            for (int j = 0; j < 4; j++) {
                float4 x0 = *(const float4*)(xr + 8 * j);
                float4 x1 = *(const float4*)(xr + 8 * j + 4);
                float4 h0 = *(const float4*)(hr + 8 * j);
                float4 h1 = *(const float4*)(hr + 8 * j + 4);
                float xs[8] = {x0.x, x0.y, x0.z, x0.w, x1.x, x1.y, x1.z, x1.w};
                float hs[8] = {h0.x, h0.y, h0.z, h0.w, h1.x, h1.y, h1.z, h1.w};
                float ov[8];
                bf16x8 v;
#pragma unroll
                for (int q = 0; q < 8; q++) {
                    int c = k0 + 8 * j + q;
                    float y = sScale[c] * xs[q] + sShift[c];
                    y = y > 0.f ? y : (__expf(y) - 1.f);
                    float hv = hs[q] + y;
                    if (do_mask && isinf(hv)) hv = 1e9f;
                    ov[q] = hv;
                    v[q] = f2bf(hv);
                }
                *(float4*)(ho + 8 * j) = make_float4(ov[0], ov[1], ov[2], ov[3]);
                *(float4*)(ho + 8 * j + 4) = make_float4(ov[4], ov[5], ov[6], ov[7]);
                *(bf16x8*)(sA + r * 136 + k0 + 8 * j) = v;
            }
        } else {
            const float* ar = A + (size_t)(r0 + r) * 128 + k0;
#pragma unroll
            for (int j = 0; j < 4; j++) {
                float4 f0 = *(const float4*)(ar + 8 * j);
                float4 f1 = *(const float4*)(ar + 8 * j + 4);
                bf16x8 v;
                v[0] = f2bf(f0.x); v[1] = f2bf(f0.y); v[2] = f2bf(f0.z); v[3] = f2bf(f0.w);
                v[4] = f2bf(f1.x); v[5] = f2bf(f1.y); v[6] = f2bf(f1.z); v[7] = f2bf(f1.w);
                *(bf16x8*)(sA + r * 136 + k0 + 8 * j) = v;
            }
        }
    }
    __syncthreads();
    int lane = t & 63, wv = t >> 6;
    int lm = lane & 15, quad = lane >> 4;
    int m0 = wv * 16;
    bf16x8 aF[4];
#pragma unroll
    for (int kt = 0; kt < 4; kt++)
        aF[kt] = *(const bf16x8*)(sA + (m0 + lm) * 136 + kt * 32 + quad * 8);
#pragma unroll
    for (int nt = 0; nt < 8; nt++) {
        floatx4 acc = (floatx4){0.f, 0.f, 0.f, 0.f};
#pragma unroll
        for (int kt = 0; kt < 4; kt++) {
            bf16x8 bF = *(const bf16x8*)(sB + (nt * 16 + lm) * 136 + kt * 32 + quad * 8);
            acc = __builtin_amdgcn_mfma_f32_16x16x32_bf16(aF[kt], bF, acc, 0, 0, 0);
        }
        int col = nt * 16 + lm;
        float bv = bias ? bias[col] : 0.f;
#pragma unroll
        for (int r = 0; r < 4; r++) {
            int row = r0 + m0 + quad * 4 + r;
            C[(size_t)row * 128 + col] = f2bf(acc[r] + bv);
        }
    }
    // fused el/er tile: cols 0..7 = el heads, 8..15 = er heads (H=1: col0=el, col1=er)
    if (WelT) {
        floatx4 acc = (floatx4){0.f, 0.f, 0.f, 0.f};
#pragma unroll
        for (int kt = 0; kt < 4; kt++) {
            bf16x8 wF = *(const bf16x8*)(WelT + lm * 128 + kt * 32 + quad * 8);
            acc = __builtin_amdgcn_mfma_f32_16x16x32_bf16(aF[kt], wF, acc, 0, 0, 0);
        }
        if (H == 8) {
#pragma unroll
            for (int r = 0; r < 4; r++) {
                int row = r0 + m0 + quad * 4 + r;
                if (lm < 8) el[(size_t)row * 8 + lm] = acc[r];
                else        er[(size_t)row * 8 + (lm - 8)] = acc[r];
            }
        } else {
#pragma unroll
            for (int r = 0; r < 4; r++) {
                int row = r0 + m0 + quad * 4 + r;
                if (lm == 0) el[row] = acc[r];
                if (lm == 1) er[row] = acc[r];
            }
        }
    }
    // second output: re-stage sB, recompute with same aF (Pb/Qb merge)
    if (WbT2) {
        __syncthreads();   // all compute reads of sB complete
        {
            int n = t >> 1;
            int k0 = (t & 1) * 64;
#pragma unroll
            for (int j = 0; j < 8; j++) {
                bf16x8 v = *(const bf16x8*)(WbT2 + n * 128 + k0 + 8 * j);
                *(bf16x8*)(sB + n * 136 + k0 + 8 * j) = v;
            }
        }
        __syncthreads();
#pragma unroll
        for (int nt = 0; nt < 8; nt++) {
            floatx4 acc = (floatx4){0.f, 0.f, 0.f, 0.f};
#pragma unroll
            for (int kt = 0; kt < 4; kt++) {
                bf16x8 bF = *(const bf16x8*)(sB + (nt * 16 + lm) * 136 + kt * 32 + quad * 8);
                acc = __builtin_amdgcn_mfma_f32_16x16x32_bf16(aF[kt], bF, acc, 0, 0, 0);
            }
            int col = nt * 16 + lm;
#pragma unroll
            for (int r = 0; r < 4; r++) {
                int row = r0 + m0 + quad * 4 + r;
                C2[(size_t)row * 128 + col] = f2bf(acc[r]);
            }
        }
    }
}

// ---------------- softmax over 100 logits, wave per node, barrier-free ----------------
__global__ __launch_bounds__(256) void k_smax100(const float* __restrict__ logits,
                                                 float* __restrict__ s) {
    int lane = threadIdx.x & 63;
    int n = blockIdx.x * 4 + (threadIdx.x >> 6);
    if (n >= N_) return;
    bool act = lane < 50;
    float2 v = make_float2(-INFINITY, -INFINITY);
    if (act) v = *(const float2*)(logits + (size_t)n * 100 + 2 * lane);
    float mx = fmaxf(v.x, v.y);
#pragma unroll
    for (int off = 1; off < 64; off <<= 1) mx = fmaxf(mx, __shfl_xor(mx, off));
    float e0 = act ? __expf(v.x - mx) : 0.f;
    float e1 = act ? __expf(v.y - mx) : 0.f;
    float sm = e0 + e1;
#pragma unroll
    for (int off = 1; off < 64; off <<= 1) sm += __shfl_xor(sm, off);
    float inv = 1.f / sm;
    if (act) *(float2*)(s + (size_t)n * 100 + 2 * lane) = make_float2(e0 * inv, e1 * inv);
}

// ---------------- GAT edge-softmax + aggregate (wave per dst node, bf16 feat) ----------------
// v7 (r14, VALIDATED 729us): single-pass flash-style online softmax-aggregate.
// BN stats epilogue: per-block coalesced partials (r12, NO atomics).
template <int H>
__global__ __launch_bounds__(256) void k_gat_agg(const short* __restrict__ feat,
                                                 const float* __restrict__ el,
                                                 const float* __restrict__ er,
                                                 const int* __restrict__ rowptr,
                                                 const int* __restrict__ srcv,
                                                 const float* __restrict__ bias,
                                                 float* __restrict__ xout,
                                                 float* __restrict__ psum,
                                                 float* __restrict__ psq) {
    int t = threadIdx.x;
    int lane = t & 63;
    int gw = (blockIdx.x * blockDim.x + t) >> 6;
    int nw = (gridDim.x * blockDim.x) >> 6;
    int h = lane & (H - 1);
    int f0 = 2 * lane;
    int hf = (H == 8) ? (lane >> 3) : 0;   // head owning this lane's feature slice

    float stx = 0.f, sty = 0.f, qtx = 0.f, qty = 0.f;  // fused BN stats

    for (int n = gw; n < N_; n += nw) {
        int beg = rowptr[n], end = rowptr[n + 1];
        if (beg == end) {
            float2 b2 = *(const float2*)(bias + f0);
            *(float2*)(xout + (size_t)n * 128 + f0) = b2;
            stx += b2.x; sty += b2.y;
            qtx += b2.x * b2.x; qty += b2.y * b2.y;
            continue;
        }
        float ern = er[(size_t)n * H + h];
        int endm1 = end - 1;
        float m = -INFINITY, ss = 0.f;
        float accx = 0.f, accy = 0.f;
        for (int e0 = beg; e0 < end; e0 += 16) {
            int le = lane >> 3;
            int eLA = e0 + le, eLB = e0 + 8 + le;
            int eCA = eLA <= endm1 ? eLA : endm1;
            int eCB = eLB <= endm1 ? eLB : endm1;
            int sLA = srcv[eCA];
            int sLB = srcv[eCB];
            float xA = el[(size_t)sLA * H + h] + ern;
            float xB = el[(size_t)sLB * H + h] + ern;
            float lrA = xA > 0.f ? xA : 0.2f * xA;
            float lrB = xB > 0.f ? xB : 0.2f * xB;
            if (eLA > endm1) lrA = -INFINITY;
            if (eLB > endm1) lrB = -INFINITY;
            bool haveB = (e0 + 8) < end;    // wave-uniform
            unsigned int uuA[8], uuB[8];
#pragma unroll
            for (int j = 0; j < 8; j++) {
                int sj = __builtin_amdgcn_readlane(sLA, j * 8);
                uuA[j] = *(const unsigned int*)(feat + (size_t)sj * 128 + f0);
            }
            if (haveB) {
#pragma unroll
                for (int j = 0; j < 8; j++) {
                    int sj = __builtin_amdgcn_readlane(sLB, j * 8);
                    uuB[j] = *(const unsigned int*)(feat + (size_t)sj * 128 + f0);
                }
            }
#pragma unroll
            for (int j = 0; j < 8; j++) {
                float lj;
                if (H == 8) lj = __shfl(lrA, j * 8 + hf);
                else        lj = rdlane(lrA, j * 8);
                if (lj > m) {
                    float r = __expf(m - lj);   // m=-INF first time -> r=0 (acc,ss are 0)
                    accx *= r; accy *= r; ss *= r; m = lj;
                }
                float w = __expf(lj - m);       // lj=-INF (masked) -> w=0
                accx += w * bflo(uuA[j]);
                accy += w * bfhi(uuA[j]);
                ss += w;
            }
            if (haveB) {
#pragma unroll
                for (int j = 0; j < 8; j++) {
                    float lj;
                    if (H == 8) lj = __shfl(lrB, j * 8 + hf);
                    else        lj = rdlane(lrB, j * 8);
                    if (lj > m) {
                        float r = __expf(m - lj);
                        accx *= r; accy *= r; ss *= r; m = lj;
                    }
                    float w = __expf(lj - m);
                    accx += w * bflo(uuB[j]);
                    accy += w * bfhi(uuB[j]);
                    ss += w;
                }
            }
        }
        float inv_d = 1.f / ss;
        float2 b2 = *(const float2*)(bias + f0);
        float ox = accx * inv_d + b2.x, oy = accy * inv_d + b2.y;
        *(float2*)(xout + (size_t)n * 128 + f0) = make_float2(ox, oy);
        stx += ox; sty += oy;
        qtx += ox * ox; qty += oy * oy;
    }

    // ---- per-block partial stats: LDS reduce across 4 waves, coalesced plain store ----
    __shared__ float red[4][256];
    red[0][t] = stx; red[1][t] = sty; red[2][t] = qtx; red[3][t] = qty;
    __syncthreads();
    if (t < 64) {
        float a0 = red[0][t] + red[0][t + 64] + red[0][t + 128] + red[0][t + 192];
        float a1 = red[1][t] + red[1][t + 64] + red[1][t + 128] + red[1][t + 192];
        float q0 = red[2][t] + red[2][t + 64] + red[2][t + 128] + red[2][t + 192];
        float q1 = red[3][t] + red[3][t + 64] + red[3][t + 128] + red[3][t + 192];
        *(float2*)(psum + (size_t)blockIdx.x * 128 + 2 * t) = make_float2(a0, a1);
        *(float2*)(psq + (size_t)blockIdx.x * 128 + 2 * t) = make_float2(q0, q1);
    }
}

// ---------------- reduce per-block stats partials -> colsum/colsq ----------------
__global__ __launch_bounds__(256) void k_stats_reduce(const float* __restrict__ psum,
                                                      const float* __restrict__ psq,
                                                      float* __restrict__ colsum,
                                                      float* __restrict__ colsq) {
    __shared__ float ls[256], lq[256];
    int t = threadIdx.x;
    int col = t & 127, half = t >> 7;
    float s = 0.f, q = 0.f;
    for (int b = blockIdx.x * 2 + half; b < AGGB_; b += gridDim.x * 2) {
        s += psum[(size_t)b * 128 + col];
        q += psq[(size_t)b * 128 + col];
    }
    ls[t] = s; lq[t] = q;
    __syncthreads();
    if (t < 128) {
        atomicAdd(&colsum[col], ls[t] + ls[t + 128]);
        atomicAdd(&colsq[col], lq[t] + lq[t + 128]);
    }
}

// ---------------- coarse pool via MFMA: part[b] = sT-chunk @ hf-chunk ----------------
// v3 (r17): replaces scalar k_coarse_part (which was at its VALU-instruction floor,
// r16: occupancy 21->44% with dur unchanged). The op is a GEMM: hc[100,128] =
// s^T[100,N] @ hf[N,128] with hf = hprev + elu(bn(xraw)) fused at staging.
// 250 blocks x 5 chunks of 32 nodes; per chunk stage sT[112][32] (rows 100..111
// zeroed) and hfT[128][32] as hi/lo bf16 in LDS (stride 40 shorts = 80B: 16B-aligned
// for ds_read_b128, 2-way bank alias = free), then 3-term hi/lo MFMA
// (aH@bH + aL@bH + aH@bL, validated fp32-equivalent scheme from k_mfma_hilo).
// Fragment convention cloned exactly from k_gemm_mfma.
__global__ __launch_bounds__(256) void k_coarse_mfma(const float* __restrict__ s,
                                                     const float* __restrict__ xraw,
                                                     const float* __restrict__ hprev,
                                                     const float* __restrict__ csum,
                                                     const float* __restrict__ csq,
                                                     const float* __restrict__ bng,
                                                     const float* __restrict__ bnb,
                                                     float* __restrict__ part) {
    __shared__ float sSc[128], sSh[128];
    __shared__ short sSTh[112 * 40], sSTl[112 * 40];
    __shared__ short sHfh[128 * 40], sHfl[128 * 40];
    int t = threadIdx.x;
    if (t < 128) {
        const float invN = 1.f / (float)N_;
        float mu = csum[t] * invN;
        float var = csq[t] * invN - mu * mu;
        float inv = rsqrtf(var + 1e-5f);
        float sc = bng[t] * inv;
        sSc[t] = sc;
        sSh[t] = bnb[t] - mu * sc;
    }
    int lane = t & 63, wv = t >> 6;
    int lm = lane & 15, quad = lane >> 4;
    floatx4 acc[7][2];
#pragma unroll
    for (int mt = 0; mt < 7; mt++)
#pragma unroll
        for (int ntl = 0; ntl < 2; ntl++)
            acc[mt][ntl] = (floatx4){0.f, 0.f, 0.f, 0.f};

    for (int ch = 0; ch < 5; ++ch) {
        int kn0 = (blockIdx.x * 5 + ch) * 32;
        __syncthreads();   // prior MFMA reads done (and sSc ready on first iter)
        // zero pad rows 100..111 of sST
        for (int u = t; u < 12 * 32; u += 256) {
            int a = 100 + (u >> 5), nd = u & 31;
            sSTh[a * 40 + nd] = 0;
            sSTl[a * 40 + nd] = 0;
        }
        // stage s^T hi/lo: 32 nodes x 100 assigns
        for (int u = t; u < 3200; u += 256) {
            int nd = u / 100, a = u - nd * 100;
            float v = s[(size_t)(kn0 + nd) * 100 + a];
            short hh = f2bf(v);
            sSTh[a * 40 + nd] = hh;
            sSTl[a * 40 + nd] = f2bf(v - bf2f(hh));
        }
        // stage hf^T hi/lo (BN fused): 8 threads per node, 16 cols each
        {
            int nd = t >> 3;
            int c0 = (t & 7) * 16;
            const float* xr = xraw + (size_t)(kn0 + nd) * 128 + c0;
            const float* hr = hprev + (size_t)(kn0 + nd) * 128 + c0;
#pragma unroll
            for (int j4 = 0; j4 < 4; ++j4) {
                float4 xv = *(const float4*)(xr + j4 * 4);
                float4 hv4 = *(const float4*)(hr + j4 * 4);
                float xs[4] = {xv.x, xv.y, xv.z, xv.w};
                float hs[4] = {hv4.x, hv4.y, hv4.z, hv4.w};
#pragma unroll
                for (int q = 0; q < 4; ++q) {
                    int c = c0 + j4 * 4 + q;
                    float y = sSc[c] * xs[q] + sSh[c];
                    y = y > 0.f ? y : (__expf(y) - 1.f);
                    float hv = hs[q] + y;
                    short hh = f2bf(hv);
                    sHfh[c * 40 + nd] = hh;
                    sHfl[c * 40 + nd] = f2bf(hv - bf2f(hh));
                }
            }
        }
        __syncthreads();
        // MFMA: wave wv handles N-tiles {2wv, 2wv+1}; 7 M-tiles (112 assign rows)
#pragma unroll
        for (int ntl = 0; ntl < 2; ++ntl) {
            int n0 = (wv * 2 + ntl) * 16;
            bf16x8 bH = *(const bf16x8*)(sHfh + (n0 + lm) * 40 + quad * 8);
            bf16x8 bL = *(const bf16x8*)(sHfl + (n0 + lm) * 40 + quad * 8);
#pragma unroll
            for (int mt = 0; mt < 7; ++mt) {
                bf16x8 aH = *(const bf16x8*)(sSTh + (mt * 16 + lm) * 40 + quad * 8);
                bf16x8 aL = *(const bf16x8*)(sSTl + (mt * 16 + lm) * 40 + quad * 8);
                acc[mt][ntl] = __builtin_amdgcn_mfma_f32_16x16x32_bf16(aH, bH, acc[mt][ntl], 0, 0, 0);
                acc[mt][ntl] = __builtin_amdgcn_mfma_f32_16x16x32_bf16(aL, bH, acc[mt][ntl], 0, 0, 0);
                acc[mt][ntl] = __builtin_amdgcn_mfma_f32_16x16x32_bf16(aH, bL, acc[mt][ntl], 0, 0, 0);
            }
        }
    }
    // write part: row = mt*16 + quad*4 + r (assign, <100), col = n0 + lm
    float* pb = part + (size_t)blockIdx.x * 12800;
#pragma unroll
    for (int ntl = 0; ntl < 2; ++ntl) {
        int col = (wv * 2 + ntl) * 16 + lm;
#pragma unroll
        for (int mt = 0; mt < 7; ++mt) {
#pragma unroll
            for (int r = 0; r < 4; ++r) {
                int row = mt * 16 + quad * 4 + r;
                if (row < 100) pb[row * 128 + col] = acc[mt][ntl][r];
            }
        }
    }
}

// ---------------- reduce partials -> hc[100][128] ----------------
__global__ __launch_bounds__(256) void k_coarse_reduce(const float* __restrict__ part,
                                                       float* __restrict__ hc) {
    int i = blockIdx.x * blockDim.x + threadIdx.x;  // 12800 total
    if (i >= 12800) return;
    float s0 = 0.f, s1 = 0.f;
    for (int b = 0; b < CPB_; b += 2) {
        s0 += part[(size_t)(b + 0) * 12800 + i];
        s1 += part[(size_t)(b + 1) * 12800 + i];
    }
    hc[i] = s0 + s1;
}

// ---------------- h = mask(0.5*h_fine + 0.5*(s@h_coarse)), layer-1 BN fused ----------------
// hfine computed inline: hprev + elu(bn(xraw)); writes h_cur in place (per-element RMW).
__global__ __launch_bounds__(256) void k_combine(const float* __restrict__ s,
                                                 const float* __restrict__ hc,
                                                 const float* __restrict__ xraw,
                                                 const float* __restrict__ csum,
                                                 const float* __restrict__ csq,
                                                 const float* __restrict__ bng,
                                                 const float* __restrict__ bnb,
                                                 float* __restrict__ hout) {
    __shared__ float ssh[16 * 100];
    __shared__ float sSc[128], sSh[128];
    int t = threadIdx.x;
    int n0 = blockIdx.x * 16;
    if (t < 128) {
        const float invN = 1.f / (float)N_;
        float mu = csum[t] * invN;
        float var = csq[t] * invN - mu * mu;
        float inv = rsqrtf(var + 1e-5f);
        float sc = bng[t] * inv;
        sSc[t] = sc;
        sSh[t] = bnb[t] - mu * sc;
    }
    for (int u = t; u < 1600; u += 256) ssh[u] = s[(size_t)n0 * 100 + u];
    __syncthreads();
    int c = t & 127, g = t >> 7;
    float scl = sSc[c], shf = sSh[c];
    float acc[8];
#pragma unroll
    for (int r = 0; r < 8; r++) acc[r] = 0.f;
    const float* hcp = hc + c;
    for (int a = 0; a < 100; a += 4) {
        float h0 = hcp[(a + 0) * 128];
        float h1 = hcp[(a + 1) * 128];
        float h2 = hcp[(a + 2) * 128];
        float h3 = hcp[(a + 3) * 128];
#pragma unroll
        for (int r = 0; r < 8; r++) {
            float4 sv = *(const float4*)(ssh + (g * 8 + r) * 100 + a);
            acc[r] += sv.x * h0 + sv.y * h1 + sv.z * h2 + sv.w * h3;
        }
    }
#pragma unroll
    for (int r = 0; r < 8; r++) {
        int row = n0 + g * 8 + r;
        float y = scl * xraw[(size_t)row * 128 + c] + shf;
        y = y > 0.f ? y : (__expf(y) - 1.f);
        float hfine = hout[(size_t)row * 128 + c] + y;   // hout holds h_prev here
        float v = 0.5f * hfine + 0.5f * acc[r];
        if (isinf(v)) v = 1e9f;
        hout[(size_t)row * 128 + c] = v;
    }
}

// ---------------- prep: Wm2 [128][64] fp32 -> Wm2T bf16 [64][128] ----------------
__global__ __launch_bounds__(256) void k_prep_w(const float* __restrict__ Wm2,
                                                short* __restrict__ Wm2T) {
    int i = blockIdx.x * blockDim.x + threadIdx.x;  // 8192 total
    if (i >= 64 * 128) return;
    int n = i & 63, k = i >> 6;
    Wm2T[n * 128 + k] = f2bf(Wm2[k * 64 + n]);
}

// ---------------- edge MLP readout: dst-sorted order, barrier-free persistent MFMA ----------------
// v2 — LOCAL OPTIMUM at ~54us, VGPR 84. Do not register-diet (v3: spills, 3x dur).
// Do not 2-tile (v4: compiler serializes the B-tile loads, occupancy drops, +6us).
__global__ __launch_bounds__(256) void k_edge_mlp3(const short* __restrict__ Pb,
                                                   const short* __restrict__ Qb,
                                                   const int* __restrict__ srcv,
                                                   const unsigned short* __restrict__ dstv,
                                                   const int* __restrict__ eidv,
                                                   const short* __restrict__ Wm2T,
                                                   const float* __restrict__ bm2,
                                                   const float* __restrict__ Wm3,
                                                   const float* __restrict__ bm3,
                                                   float* __restrict__ zout) {
    __shared__ short sW[64 * 128];  // 16 KiB
    int t = threadIdx.x;
    // stage Wm2T -> LDS with 16B-unit XOR swizzle: phys_unit = n*16 + (k16 ^ (n&15))
    for (int u = t; u < 1024; u += 256) {
        int n = u >> 4, k16 = u & 15;
        int phys = (n << 4) | (k16 ^ (n & 15));
        *(bf16x8*)(sW + phys * 8) = *(const bf16x8*)(Wm2T + n * 128 + k16 * 8);
    }
    int lane = t & 63;
    int lm = lane & 15, quad = lane >> 4;
    float bv[4], w30[4], w31[4];
#pragma unroll
    for (int nt = 0; nt < 4; nt++) {
        int n = nt * 16 + lm;
        bv[nt] = bm2[n]; w30[nt] = Wm3[2 * n]; w31[nt] = Wm3[2 * n + 1];
    }
    float b30 = bm3[0], b31 = bm3[1];
    __syncthreads();

    int gw = (blockIdx.x * blockDim.x + t) >> 6;
    int nw = (gridDim.x * blockDim.x) >> 6;

    for (int tile = gw; tile < E_ / 16; tile += nw) {
        int p0 = tile * 16;
        int sI = srcv[p0 + lm];
        int dI = (int)dstv[p0 + lm];
        const short* pr = Pb + (size_t)sI * 128 + quad * 8;
        const short* qr = Qb + (size_t)dI * 128 + quad * 8;
        // issue all 8 gathers up-front (latency hidden within wave)
        uint4 pu[4], qu[4];
#pragma unroll
        for (int kt = 0; kt < 4; kt++) {
            pu[kt] = *(const uint4*)(pr + kt * 32);
            qu[kt] = *(const uint4*)(qr + kt * 32);
        }
        bf16x8 aF[4];
#pragma unroll
        for (int kt = 0; kt < 4; kt++) {
            unsigned int pv[4] = {pu[kt].x, pu[kt].y, pu[kt].z, pu[kt].w};
            unsigned int qv[4] = {qu[kt].x, qu[kt].y, qu[kt].z, qu[kt].w};
            union { uint4 u; bf16x8 v; } cv;
            unsigned int rr[4];
#pragma unroll
            for (int j = 0; j < 4; j++) {
                float fl = fmaxf(bflo(pv[j]) + bflo(qv[j]), 0.f);
                float fh = fmaxf(bfhi(pv[j]) + bfhi(qv[j]), 0.f);
                rr[j] = (unsigned int)(unsigned short)f2bf(fl) |
                        ((unsigned int)(unsigned short)f2bf(fh) << 16);
            }
            cv.u.x = rr[0]; cv.u.y = rr[1]; cv.u.z = rr[2]; cv.u.w = rr[3];
            aF[kt] = cv.v;
        }
        float pz0[4] = {0.f, 0.f, 0.f, 0.f};
        float pz1[4] = {0.f, 0.f, 0.f, 0.f};
#pragma unroll
        for (int nt = 0; nt < 4; nt++) {
            floatx4 acc = (floatx4){0.f, 0.f, 0.f, 0.f};
#pragma unroll
            for (int kt = 0; kt < 4; kt++) {
                int phys = ((nt * 16 + lm) << 4) | (((kt << 2) | quad) ^ lm);
                bf16x8 bF = *(const bf16x8*)(sW + phys * 8);
                acc = __builtin_amdgcn_mfma_f32_16x16x32_bf16(aF[kt], bF, acc, 0, 0, 0);
            }
#pragma unroll
            for (int r = 0; r < 4; r++) {
                float u = fmaxf(acc[r] + bv[nt], 0.f);
                pz0[r] += u * w30[nt];
                pz1[r] += u * w31[nt];
            }
        }
#pragma unroll
        for (int off = 1; off < 16; off <<= 1) {
#pragma unroll
            for (int r = 0; r < 4; r++) {
                pz0[r] += __shfl_xor(pz0[r], off);
                pz1[r] += __shfl_xor(pz1[r], off);
            }
        }
        if (lm < 4) {
            int eid = eidv[p0 + quad * 4 + lm];
            float z0 = pz0[lm] + b30;
            float z1 = pz1[lm] + b31;
            if (isinf(z0)) z0 = 1e9f;
            if (isinf(z1)) z1 = 1e9f;
            *(float2*)(zout + (size_t)eid * 2) = make_float2(z0, z1);
        }
    }
}

extern "C" void kernel_launch(void* const* d_in, const int* in_sizes, int n_in,
                              void* d_out, int out_size, void* d_ws, size_t ws_size,
                              hipStream_t stream) {
    const float* h_in  = (const float*)d_in[0];
    const int*   src   = (const int*)d_in[2];
    const int*   dst   = (const int*)d_in[3];
    const float* W_emb = (const float*)d_in[4];
    const float* b_emb = (const float*)d_in[5];
    const float* Wg    = (const float*)d_in[6];
    const float* alg   = (const float*)d_in[7];
    const float* arg_  = (const float*)d_in[8];
    const float* bg    = (const float*)d_in[9];
    const float* gam   = (const float*)d_in[10];
    const float* bet   = (const float*)d_in[11];
    const float* W3    = (const float*)d_in[12];
    const float* al3   = (const float*)d_in[13];
    const float* ar3   = (const float*)d_in[14];
    const float* b3    = (const float*)d_in[15];
    const float* gam3  = (const float*)d_in[16];
    const float* bet3  = (const float*)d_in[17];
    const float* Wa    = (const float*)d_in[18];
    const float* ba    = (const float*)d_in[19];
    const float* Wm1   = (const float*)d_in[20];
    const float* bm1   = (const float*)d_in[21];
    const float* Wm2   = (const float*)d_in[22];
    const float* bm2   = (const float*)d_in[23];
    const float* Wm3   = (const float*)d_in[24];
    const float* bm3   = (const float*)d_in[25];

    float* zout = (float*)d_out;
    float* sout = zout + (size_t)E_ * 2;

    float* ws = (float*)d_ws;
    size_t o = 0;
    float* h_cur = ws + o; o += (size_t)N_ * 128;
    float* xbuf  = ws + o; o += (size_t)N_ * 128;
    float* featb = ws + o; o += (size_t)N_ * 128;   // reused: bf16 feat, coarse partials, bf16 P/Q
    float* el    = ws + o; o += (size_t)N_ * 8;
    float* er    = ws + o; o += (size_t)N_ * 8;
    float* colsum = ws + o; o += 128;
    float* colsq  = ws + o; o += 128;
    float* hc     = ws + o; o += 100 * 128;
    float* psum   = ws + o; o += (size_t)AGGB_ * 128;
    float* psq    = ws + o; o += (size_t)AGGB_ * 128;
    short* Wm2T = (short*)(ws + o); o += (64 * 128) / 2;
    short* WbT6 = (short*)(ws + o); o += (6 * 16384) / 2;
    short* WelT = (short*)(ws + o); o += (4 * 2048) / 2;
    short* WembT_hi = (short*)(ws + o); o += 16384 / 2;
    short* WembT_lo = (short*)(ws + o); o += 16384 / 2;
    short* WaT_hi   = (short*)(ws + o); o += 16384 / 2;
    short* WaT_lo   = (short*)(ws + o); o += 16384 / 2;
    int* counts = (int*)(ws + o); o += N_;
    int* rowptr = (int*)(ws + o); o += N_ + 4;
    int* cursor = (int*)(ws + o); o += N_;
    int* srcv   = (int*)(ws + o); o += E_;
    unsigned short* dstv = (unsigned short*)(ws + o); o += E_ / 2;
    int* eidv   = (int*)(ws + o); o += E_;
    int* bsum   = (int*)(ws + o); o += SNB_ + 4;

    short* featw = (short*)featb;  // bf16 per-layer projection

    // ---- CSR build (parallel scan; excl scratch reuses eidv pre-fill) ----
    hipMemsetAsync(counts, 0, N_ * sizeof(int), stream);
    k_count<<<1024, 256, 0, stream>>>(dst, counts);
    k_scanA<<<SNB_, 256, 0, stream>>>(counts, eidv, bsum);
    k_scanB<<<1, 256, 0, stream>>>(bsum);
    k_scanC<<<SNB_ + 1, 256, 0, stream>>>(eidv, bsum, rowptr, cursor);
    k_fill<<<1024, 256, 0, stream>>>(src, dst, cursor, srcv, dstv, eidv);
    k_prep_w<<<32, 256, 0, stream>>>(Wm2, Wm2T);
    k_prep_all<<<384, 256, 0, stream>>>(Wg, W3, Wm1, WbT6);
    k_prep_wela<<<32, 256, 0, stream>>>(Wg, alg, arg_, W3, al3, ar3, WelT);
    k_prep_hilo<<<128, 256, 0, stream>>>(W_emb, Wa, WembT_hi, WembT_lo, WaT_hi, WaT_lo);

    // ---- embedding (fp32-accurate via hi/lo MFMA) ----
    k_mfma_hilo<<<N_ / 64, 256, 0, stream>>>(h_in, WembT_hi, WembT_lo, b_emb, h_cur, 128);

    // ---- layer 0 (H=8) ----
    k_gemm_mfma<<<N_ / 64, 256, 0, stream>>>(h_cur, WbT6 + 0 * 16384, nullptr, featw,
                                             WelT + 0 * 2048, el, er, 8,
                                             nullptr, nullptr, nullptr, nullptr,
                                             nullptr, nullptr, nullptr, 0,
                                             nullptr, nullptr);
    hipMemsetAsync(colsum, 0, 256 * sizeof(float), stream);
    k_gat_agg<8><<<AGGB_, 256, 0, stream>>>(featw, el, er, rowptr, srcv, bg + 0 * 128, xbuf,
                                            psum, psq);
    k_stats_reduce<<<64, 256, 0, stream>>>(psum, psq, colsum, colsq);

    // ---- layer 1 (biGAT, H=8): gemm fused with layer-0 BN (writes h_cur) ----
    k_gemm_mfma<<<N_ / 64, 256, 0, stream>>>(nullptr, WbT6 + 1 * 16384, nullptr, featw,
                                             WelT + 1 * 2048, el, er, 8,
                                             xbuf, h_cur, colsum, colsq,
                                             gam + 0 * 128, bet + 0 * 128, h_cur, 1,
                                             nullptr, nullptr);
    k_mfma_hilo<<<N_ / 64, 256, 0, stream>>>(h_cur, WaT_hi, WaT_lo, ba, xbuf, 100);
    k_smax100<<<N_ / 4, 256, 0, stream>>>(xbuf, sout);
    hipMemsetAsync(colsum, 0, 256 * sizeof(float), stream);
    k_gat_agg<8><<<AGGB_, 256, 0, stream>>>(featw, el, er, rowptr, srcv, bg + 1 * 128, xbuf,
                                            psum, psq);
    k_stats_reduce<<<64, 256, 0, stream>>>(psum, psq, colsum, colsq);
    // layer-1 BN fused into BOTH consumers (coarse_mfma + combine); k_bn_apply deleted
    k_coarse_mfma<<<CPB_, 256, 0, stream>>>(sout, xbuf, h_cur, colsum, colsq,
                                            gam + 1 * 128, bet + 1 * 128, featb);
    k_coarse_reduce<<<50, 256, 0, stream>>>(featb, hc);
    k_combine<<<N_ / 16, 256, 0, stream>>>(sout, hc, xbuf, colsum, colsq,
                                           gam + 1 * 128, bet + 1 * 128, h_cur);

    // ---- layer 2 (H=8) ----
    k_gemm_mfma<<<N_ / 64, 256, 0, stream>>>(h_cur, WbT6 + 2 * 16384, nullptr, featw,
                                             WelT + 2 * 2048, el, er, 8,
                                             nullptr, nullptr, nullptr, nullptr,
                                             nullptr, nullptr, nullptr, 0,
                                             nullptr, nullptr);
    hipMemsetAsync(colsum, 0, 256 * sizeof(float), stream);
    k_gat_agg<8><<<AGGB_, 256, 0, stream>>>(featw, el, er, rowptr, srcv, bg + 2 * 128, xbuf,
                                            psum, psq);
    k_stats_reduce<<<64, 256, 0, stream>>>(psum, psq, colsum, colsq);

    // ---- layer 3 (H=1): gemm fused with layer-2 BN (writes h_cur) ----
    k_gemm_mfma<<<N_ / 64, 256, 0, stream>>>(nullptr, WbT6 + 3 * 16384, nullptr, featw,
                                             WelT + 3 * 2048, el, er, 1,
                                             xbuf, h_cur, colsum, colsq,
                                             gam + 2 * 128, bet + 2 * 128, h_cur, 1,
                                             nullptr, nullptr);
    hipMemsetAsync(colsum, 0, 256 * sizeof(float), stream);
    k_gat_agg<1><<<AGGB_, 256, 0, stream>>>(featw, el, er, rowptr, srcv, b3, xbuf,
                                            psum, psq);
    k_stats_reduce<<<64, 256, 0, stream>>>(psum, psq, colsum, colsq);

    // ---- edge MLP readout: ONE gemm (layer-3 BN fused) producing BOTH Pb and Qb ----
    short* Pb = (short*)featb;
    short* Qb = Pb + (size_t)N_ * 128;
    k_gemm_mfma<<<N_ / 64, 256, 0, stream>>>(nullptr, WbT6 + 4 * 16384, bm1, Pb,
                                             nullptr, nullptr, nullptr, 0,
                                             xbuf, h_cur, colsum, colsq,
                                             gam3, bet3, h_cur, 1,
                                             WbT6 + 5 * 16384, Qb);
    k_edge_mlp3<<<2048, 256, 0, stream>>>(Pb, Qb, srcv, dstv, eidv, Wm2T, bm2, Wm3, bm3, zout);
}